// Round 1
// baseline (1299.731 us; speedup 1.0000x reference)
//
#include <hip/hip_runtime.h>
#include <cstdint>
#include <cstddef>

#define N_NODES 50000
#define N_EDGES 500000
#define NG 512
#define HID 256
#define EPS 1e-5f

// ---------------- CSR build ----------------
__global__ void k_csr_count(const int* __restrict__ ei, int* __restrict__ cnt) {
  int e = blockIdx.x * 256 + threadIdx.x;
  if (e < N_EDGES) atomicAdd(&cnt[ei[N_EDGES + e]], 1);
}

__global__ void k_scan(const int* __restrict__ cnt, int* __restrict__ row_ptr) {
  __shared__ int ps[1024];
  const int CH = (N_NODES + 1023) / 1024;  // 49
  int tid = threadIdx.x;
  int b = tid * CH, e = min(b + CH, N_NODES);
  int s = 0;
  for (int i = b; i < e; i++) s += cnt[i];
  ps[tid] = s;
  __syncthreads();
  for (int o = 1; o < 1024; o <<= 1) {
    int add = (tid >= o) ? ps[tid - o] : 0;
    __syncthreads();
    ps[tid] += add;
    __syncthreads();
  }
  int run = (tid > 0) ? ps[tid - 1] : 0;
  for (int i = b; i < e; i++) { row_ptr[i] = run; run += cnt[i]; }
  if (tid == 1023) row_ptr[N_NODES] = ps[1023];
}

__global__ void k_csr_fill(const int* __restrict__ ei, const int* __restrict__ row_ptr,
                           int* __restrict__ fill, int* __restrict__ col_src) {
  int e = blockIdx.x * 256 + threadIdx.x;
  if (e >= N_EDGES) return;
  int s = ei[e], d = ei[N_EDGES + e];
  int pos = row_ptr[d] + atomicAdd(&fill[d], 1);
  col_src[pos] = s;
}

__global__ void k_dis(const int* __restrict__ row_ptr, float* __restrict__ dis) {
  int i = blockIdx.x * 256 + threadIdx.x;
  if (i < N_NODES) dis[i] = rsqrtf((float)(row_ptr[i + 1] - row_ptr[i]) + 1.0f);
}

// ---------------- GEMM: out[M,C] = A[M,K] @ W[K,C] (+bias) ----------------
// block = 256 threads = 4 waves; wave w owns rows w*16..w*16+15 of a 64-row tile;
// lane owns cols lane*CPT..; A tile staged in LDS, read as b128 broadcasts.
// flags: 1 = relu, 2 = accumulate into out
template <int K, int CPT>
__global__ __launch_bounds__(256) void k_gemm(const float* __restrict__ A,
                                              const float* __restrict__ W,
                                              const float* __restrict__ bias,
                                              float* __restrict__ out, int M, int flags) {
  constexpr int C = 64 * CPT;
  extern __shared__ float lds[];
  const int tid = threadIdx.x;
  const int brow = blockIdx.x * 64;
  for (int idx = tid * 4; idx < 64 * K; idx += 1024) {
    int r = idx / K, k = idx % K;
    int row = brow + r;
    float4 v = make_float4(0.f, 0.f, 0.f, 0.f);
    if (row < M) v = *reinterpret_cast<const float4*>(A + (size_t)row * K + k);
    *reinterpret_cast<float4*>(&lds[idx]) = v;
  }
  __syncthreads();
  const int lane = tid & 63;
  const int r0 = (tid >> 6) * 16;
  float acc[16][CPT];
#pragma unroll
  for (int r = 0; r < 16; r++)
#pragma unroll
    for (int c = 0; c < CPT; c++) acc[r][c] = 0.f;
  const float* Wp = W + lane * CPT;
  for (int k = 0; k < K; k += 4) {
    float w[4][CPT];
#pragma unroll
    for (int kk = 0; kk < 4; kk++) {
      if constexpr (CPT == 4) {
        float4 wv = *reinterpret_cast<const float4*>(Wp + (size_t)(k + kk) * C);
        w[kk][0] = wv.x; w[kk][1] = wv.y; w[kk][2] = wv.z; w[kk][3] = wv.w;
      } else {
        float2 wv = *reinterpret_cast<const float2*>(Wp + (size_t)(k + kk) * C);
        w[kk][0] = wv.x; w[kk][1] = wv.y;
      }
    }
#pragma unroll
    for (int r = 0; r < 16; r++) {
      float4 a = *reinterpret_cast<const float4*>(&lds[(r0 + r) * K + k]);
#pragma unroll
      for (int c = 0; c < CPT; c++) {
        acc[r][c] = fmaf(a.x, w[0][c], acc[r][c]);
        acc[r][c] = fmaf(a.y, w[1][c], acc[r][c]);
        acc[r][c] = fmaf(a.z, w[2][c], acc[r][c]);
        acc[r][c] = fmaf(a.w, w[3][c], acc[r][c]);
      }
    }
  }
  float bv[CPT];
#pragma unroll
  for (int c = 0; c < CPT; c++) bv[c] = bias ? bias[lane * CPT + c] : 0.f;
#pragma unroll
  for (int r = 0; r < 16; r++) {
    int row = brow + r0 + r;
    if (row >= M) continue;
    float* op = out + (size_t)row * C + lane * CPT;
    float v[CPT];
#pragma unroll
    for (int c = 0; c < CPT; c++) {
      v[c] = acc[r][c] + bv[c];
      if (flags & 1) v[c] = fmaxf(v[c], 0.f);
    }
    if (flags & 2) {
#pragma unroll
      for (int c = 0; c < CPT; c++) v[c] += op[c];
    }
    if constexpr (CPT == 4)
      *reinterpret_cast<float4*>(op) = make_float4(v[0], v[1], v[2], v[3]);
    else
      *reinterpret_cast<float2*>(op) = make_float2(v[0], v[1]);
  }
}

// ---------------- GCN aggregation (wave per node) ----------------
__global__ void k_gcn_agg(const float* __restrict__ xt, const float* __restrict__ dis,
                          const int* __restrict__ row_ptr, const int* __restrict__ col_src,
                          const float* __restrict__ b_gcn, float* __restrict__ out) {
  int node = blockIdx.x * 4 + (threadIdx.x >> 6);
  if (node >= N_NODES) return;
  int lane = threadIdx.x & 63;
  float di = dis[node];
  float4 x = *reinterpret_cast<const float4*>(xt + (size_t)node * HID + lane * 4);
  float w0 = di * di;
  float4 acc = make_float4(x.x * w0, x.y * w0, x.z * w0, x.w * w0);
  int b = row_ptr[node], e = row_ptr[node + 1];
  for (int i = b; i < e; i++) {
    int s = col_src[i];
    float nw = di * dis[s];
    float4 xv = *reinterpret_cast<const float4*>(xt + (size_t)s * HID + lane * 4);
    acc.x = fmaf(xv.x, nw, acc.x);
    acc.y = fmaf(xv.y, nw, acc.y);
    acc.z = fmaf(xv.z, nw, acc.z);
    acc.w = fmaf(xv.w, nw, acc.w);
  }
  float4 bb = *reinterpret_cast<const float4*>(b_gcn + lane * 4);
  acc.x += bb.x; acc.y += bb.y; acc.z += bb.z; acc.w += bb.w;
  *reinterpret_cast<float4*>(out + (size_t)node * HID + lane * 4) = acc;
}

// ---------------- GAT ----------------
__global__ void k_gat_al(const float* __restrict__ xt, const float* __restrict__ a_src,
                         const float* __restrict__ a_dst, float* __restrict__ alsrc,
                         float* __restrict__ aldst) {
  int node = blockIdx.x * 4 + (threadIdx.x >> 6);
  if (node >= N_NODES) return;
  int lane = threadIdx.x & 63;
  float4 v = *reinterpret_cast<const float4*>(xt + (size_t)node * HID + lane * 4);
  float4 as = *reinterpret_cast<const float4*>(a_src + lane * 4);
  float4 ad = *reinterpret_cast<const float4*>(a_dst + lane * 4);
  float ps = v.x * as.x + v.y * as.y + v.z * as.z + v.w * as.w;
  float pd = v.x * ad.x + v.y * ad.y + v.z * ad.z + v.w * ad.w;
  for (int o = 1; o < 8; o <<= 1) { ps += __shfl_xor(ps, o); pd += __shfl_xor(pd, o); }
  if ((lane & 7) == 0) {
    alsrc[node * 8 + (lane >> 3)] = ps;
    aldst[node * 8 + (lane >> 3)] = pd;
  }
}

__device__ __forceinline__ float leaky02(float x) { return x > 0.f ? x : 0.2f * x; }

__global__ void k_gat_stats(const float* __restrict__ alsrc, const float* __restrict__ aldst,
                            const int* __restrict__ row_ptr, const int* __restrict__ col_src,
                            float* __restrict__ m_nh, float* __restrict__ s_nh) {
  int t = blockIdx.x * 256 + threadIdx.x;  // t = node*8 + head
  if (t >= N_NODES * 8) return;
  int node = t >> 3, hh = t & 7;
  float ad = aldst[t];
  float m = leaky02(alsrc[t] + ad);  // self-loop logit
  float s = 1.0f;
  int b = row_ptr[node], e = row_ptr[node + 1];
  for (int i = b; i < e; i++) {
    int src = col_src[i];
    float l = leaky02(alsrc[src * 8 + hh] + ad);
    if (l > m) { s = s * __expf(m - l) + 1.0f; m = l; }
    else s += __expf(l - m);
  }
  m_nh[t] = m;
  s_nh[t] = s;
}

__global__ void k_gat_agg(const float* __restrict__ xt, const float* __restrict__ alsrc,
                          const float* __restrict__ aldst, const float* __restrict__ m_nh,
                          const float* __restrict__ s_nh, const int* __restrict__ row_ptr,
                          const int* __restrict__ col_src, const float* __restrict__ b_gat,
                          float* __restrict__ out) {
  int node = blockIdx.x * 4 + (threadIdx.x >> 6);
  if (node >= N_NODES) return;
  int lane = threadIdx.x & 63;
  int hh = lane >> 3;  // head of this lane's 4 dims
  float m = m_nh[node * 8 + hh];
  float inv_s = 1.0f / s_nh[node * 8 + hh];
  float ad = aldst[node * 8 + hh];
  float l0 = leaky02(alsrc[node * 8 + hh] + ad);
  float a0 = __expf(l0 - m) * inv_s;
  float4 x = *reinterpret_cast<const float4*>(xt + (size_t)node * HID + lane * 4);
  float4 acc = make_float4(x.x * a0, x.y * a0, x.z * a0, x.w * a0);
  int b = row_ptr[node], e = row_ptr[node + 1];
  for (int i = b; i < e; i++) {
    int src = col_src[i];
    float l = leaky02(alsrc[src * 8 + hh] + ad);
    float al = __expf(l - m) * inv_s;
    float4 xv = *reinterpret_cast<const float4*>(xt + (size_t)src * HID + lane * 4);
    acc.x = fmaf(xv.x, al, acc.x);
    acc.y = fmaf(xv.y, al, acc.y);
    acc.z = fmaf(xv.z, al, acc.z);
    acc.w = fmaf(xv.w, al, acc.w);
  }
  float4 bb = *reinterpret_cast<const float4*>(b_gat + lane * 4);
  acc.x += bb.x; acc.y += bb.y; acc.z += bb.z; acc.w += bb.w;
  *reinterpret_cast<float4*>(out + (size_t)node * HID + lane * 4) = acc;
}

// ---------------- SAGE mean aggregation ----------------
__global__ void k_sage_agg(const float* __restrict__ h, const int* __restrict__ row_ptr,
                           const int* __restrict__ col_src, float* __restrict__ out) {
  int node = blockIdx.x * 4 + (threadIdx.x >> 6);
  if (node >= N_NODES) return;
  int lane = threadIdx.x & 63;
  int b = row_ptr[node], e = row_ptr[node + 1];
  float inv = 1.0f / fmaxf((float)(e - b), 1.0f);
  float4 acc = make_float4(0.f, 0.f, 0.f, 0.f);
  for (int i = b; i < e; i++) {
    int s = col_src[i];
    float4 xv = *reinterpret_cast<const float4*>(h + (size_t)s * HID + lane * 4);
    acc.x += xv.x; acc.y += xv.y; acc.z += xv.z; acc.w += xv.w;
  }
  acc.x *= inv; acc.y *= inv; acc.z *= inv; acc.w *= inv;
  *reinterpret_cast<float4*>(out + (size_t)node * HID + lane * 4) = acc;
}

// ---------------- BatchNorm (batch stats) ----------------
__global__ void k_bn_stats(const float* __restrict__ x, float* __restrict__ stats) {
  int c = threadIdx.x;  // 256 threads = 256 cols
  float s = 0.f, q = 0.f;
  for (int r = blockIdx.x; r < N_NODES; r += gridDim.x) {
    float v = x[(size_t)r * HID + c];
    s += v;
    q = fmaf(v, v, q);
  }
  atomicAdd(&stats[c], s);
  atomicAdd(&stats[HID + c], q);
}

__global__ void k_bn_apply(const float* __restrict__ x, const float* __restrict__ stats,
                           const float* __restrict__ gamma, const float* __restrict__ beta,
                           float* __restrict__ h) {
  const float invN = 1.0f / (float)N_NODES;
  int total = N_NODES * 64;
  for (int i = blockIdx.x * 256 + threadIdx.x; i < total; i += gridDim.x * 256) {
    int c4 = (i & 63) * 4;
    float4 xv = *reinterpret_cast<const float4*>(x + (size_t)i * 4);
    float4 sm = *reinterpret_cast<const float4*>(stats + c4);
    float4 sq = *reinterpret_cast<const float4*>(stats + HID + c4);
    float4 gm = *reinterpret_cast<const float4*>(gamma + c4);
    float4 bt = *reinterpret_cast<const float4*>(beta + c4);
    float4 hv = *reinterpret_cast<const float4*>(h + (size_t)i * 4);
#define BN1(f)                                                    \
  {                                                               \
    float mu = sm.f * invN;                                       \
    float var = sq.f * invN - mu * mu;                            \
    float sc = gm.f * rsqrtf(var + EPS);                          \
    float v = (xv.f - mu) * sc + bt.f;                            \
    hv.f += fmaxf(v, 0.f);                                        \
  }
    BN1(x) BN1(y) BN1(z) BN1(w)
#undef BN1
    *reinterpret_cast<float4*>(h + (size_t)i * 4) = hv;
  }
}

// ---------------- gate: dot(relu_hidden, Wg2) + bg2 ----------------
__global__ void k_gate(const float* __restrict__ tg, const float* __restrict__ Wg2,
                       const float* __restrict__ bg2, float* __restrict__ gate) {
  int node = blockIdx.x * 4 + (threadIdx.x >> 6);
  if (node >= N_NODES) return;
  int lane = threadIdx.x & 63;
  float v = tg[(size_t)node * 128 + lane] * Wg2[lane] +
            tg[(size_t)node * 128 + 64 + lane] * Wg2[64 + lane];
  for (int o = 1; o < 64; o <<= 1) v += __shfl_xor(v, o);
  if (lane == 0) gate[node] = v + bg2[0];
}

// ---------------- graph segment starts (batch is sorted) ----------------
__global__ void k_gstart(const int* __restrict__ batch, int* __restrict__ gstart) {
  int g = blockIdx.x * 256 + threadIdx.x;
  if (g > NG) return;
  int lo = 0, hi = N_NODES;
  while (lo < hi) {
    int mid = (lo + hi) >> 1;
    if (batch[mid] < g) lo = mid + 1; else hi = mid;
  }
  gstart[g] = lo;
}

// ---------------- global attention pooling (block per graph) ----------------
__global__ void k_pool(const float* __restrict__ h, const float* __restrict__ gate,
                       const int* __restrict__ gstart, float* __restrict__ hg) {
  __shared__ float red[256];
  __shared__ float wbuf[256];
  int g = blockIdx.x, tid = threadIdx.x;
  int b = gstart[g], e = gstart[g + 1];
  float m = -1e30f;
  for (int r = b + tid; r < e; r += 256) m = fmaxf(m, gate[r]);
  red[tid] = m;
  __syncthreads();
  for (int o = 128; o > 0; o >>= 1) {
    if (tid < o) red[tid] = fmaxf(red[tid], red[tid + o]);
    __syncthreads();
  }
  m = red[0];
  __syncthreads();
  float s = 0.f;
  for (int r = b + tid; r < e; r += 256) s += __expf(gate[r] - m);
  red[tid] = s;
  __syncthreads();
  for (int o = 128; o > 0; o >>= 1) {
    if (tid < o) red[tid] += red[tid + o];
    __syncthreads();
  }
  float inv = 1.0f / fmaxf(red[0], 1e-16f);
  __syncthreads();
  float acc = 0.f;
  for (int cb = b; cb < e; cb += 256) {
    int r = cb + tid;
    wbuf[tid] = (r < e) ? __expf(gate[r] - m) : 0.f;
    __syncthreads();
    int n = min(256, e - cb);
    for (int j = 0; j < n; j++) acc = fmaf(h[(size_t)(cb + j) * HID + tid], wbuf[j], acc);
    __syncthreads();
  }
  hg[(size_t)g * HID + tid] = acc * inv;
}

// ---------------- MLP head: relu(LN(hg@W1+b1)) @ W2 + b2 ----------------
__global__ void k_mlp(const float* __restrict__ hg, const float* __restrict__ W1,
                      const float* __restrict__ b1, const float* __restrict__ lng,
                      const float* __restrict__ lnb, const float* __restrict__ W2,
                      const float* __restrict__ b2, float* __restrict__ out) {
  __shared__ float row[HID];
  __shared__ float z[HID];
  __shared__ float red[HID];
  int g = blockIdx.x, tid = threadIdx.x;
  row[tid] = hg[(size_t)g * HID + tid];
  __syncthreads();
  float acc = b1[tid];
  for (int k = 0; k < HID; k++) acc = fmaf(row[k], W1[(size_t)k * HID + tid], acc);
  red[tid] = acc;
  __syncthreads();
  for (int o = 128; o > 0; o >>= 1) {
    if (tid < o) red[tid] += red[tid + o];
    __syncthreads();
  }
  float mu = red[0] * (1.0f / HID);
  __syncthreads();
  red[tid] = acc * acc;
  __syncthreads();
  for (int o = 128; o > 0; o >>= 1) {
    if (tid < o) red[tid] += red[tid + o];
    __syncthreads();
  }
  float var = red[0] * (1.0f / HID) - mu * mu;
  float zz = (acc - mu) * rsqrtf(var + EPS) * lng[tid] + lnb[tid];
  z[tid] = fmaxf(zz, 0.f);
  __syncthreads();
  if (tid < 64) {
    float o = b2[tid];
    for (int k = 0; k < HID; k++) o = fmaf(z[k], W2[(size_t)k * 64 + tid], o);
    out[(size_t)g * 64 + tid] = o;
  }
}

// ---------------- launch ----------------
extern "C" void kernel_launch(void* const* d_in, const int* in_sizes, int n_in,
                              void* d_out, int out_size, void* d_ws, size_t ws_size,
                              hipStream_t stream) {
  const float* x     = (const float*)d_in[0];
  const float* W_emb = (const float*)d_in[1];
  const float* b_emb = (const float*)d_in[2];
  const float* W_gcn = (const float*)d_in[3];
  const float* b_gcn = (const float*)d_in[4];
  const float* W_gat = (const float*)d_in[5];
  const float* a_src = (const float*)d_in[6];
  const float* a_dst = (const float*)d_in[7];
  const float* b_gat = (const float*)d_in[8];
  const float* W_l   = (const float*)d_in[9];
  const float* b_l   = (const float*)d_in[10];
  const float* W_r   = (const float*)d_in[11];
  const float* bn_g  = (const float*)d_in[12];
  const float* bn_b  = (const float*)d_in[13];
  const float* Wg1   = (const float*)d_in[14];
  const float* bg1   = (const float*)d_in[15];
  const float* Wg2   = (const float*)d_in[16];
  const float* bg2   = (const float*)d_in[17];
  const float* Wm1   = (const float*)d_in[18];
  const float* bm1   = (const float*)d_in[19];
  const float* lnmg  = (const float*)d_in[20];
  const float* lnmb  = (const float*)d_in[21];
  const float* Wm2   = (const float*)d_in[22];
  const float* bm2   = (const float*)d_in[23];
  const float* Wv1   = (const float*)d_in[24];
  const float* bv1   = (const float*)d_in[25];
  const float* lnvg  = (const float*)d_in[26];
  const float* lnvb  = (const float*)d_in[27];
  const float* Wv2   = (const float*)d_in[28];
  const float* bv2   = (const float*)d_in[29];
  const int* ei      = (const int*)d_in[30];
  const int* batch   = (const int*)d_in[31];
  float* out = (float*)d_out;

  float* ws = (float*)d_ws;
  float* h     = ws;
  float* t0    = h + (size_t)N_NODES * HID;
  float* t1    = t0 + (size_t)N_NODES * HID;
  float* alsrc = t1 + (size_t)N_NODES * HID;
  float* aldst = alsrc + N_NODES * 8;
  float* m_nh  = aldst + N_NODES * 8;
  float* s_nh  = m_nh + N_NODES * 8;
  float* dis   = s_nh + N_NODES * 8;
  float* gate  = dis + N_NODES;
  float* hg    = gate + N_NODES;
  float* zbase = hg + NG * HID;        // zeroed region starts here
  float* bnst  = zbase;                // 3 layers * (sum[256] + ssq[256])
  int* row_cnt = (int*)(zbase + 3 * 512);
  int* fill    = row_cnt + N_NODES;
  int* row_ptr = fill + N_NODES;       // not zeroed (fully written)
  int* col_src = row_ptr + N_NODES + 1;
  int* gstart  = col_src + N_EDGES;

  size_t zbytes = (size_t)3 * 512 * 4 + 2 * (size_t)N_NODES * 4;
  hipMemsetAsync(zbase, 0, zbytes, stream);

  // CSR by dst
  k_csr_count<<<(N_EDGES + 255) / 256, 256, 0, stream>>>(ei, row_cnt);
  k_scan<<<1, 1024, 0, stream>>>(row_cnt, row_ptr);
  k_csr_fill<<<(N_EDGES + 255) / 256, 256, 0, stream>>>(ei, row_ptr, fill, col_src);
  k_dis<<<(N_NODES + 255) / 256, 256, 0, stream>>>(row_ptr, dis);

  const int GB = (N_NODES + 63) / 64;   // 782 gemm blocks
  const int AB = (N_NODES + 3) / 4;     // 12500 agg blocks (4 waves each)

  // embedding: h = x @ W_emb + b_emb
  k_gemm<128, 4><<<GB, 256, 64 * 128 * 4, stream>>>(x, W_emb, b_emb, h, N_NODES, 0);

  // --- GCN ---
  k_gemm<256, 4><<<GB, 256, 64 * 256 * 4, stream>>>(h, W_gcn, nullptr, t0, N_NODES, 0);
  k_gcn_agg<<<AB, 256, 0, stream>>>(t0, dis, row_ptr, col_src, b_gcn, t1);
  k_bn_stats<<<256, 256, 0, stream>>>(t1, bnst);
  k_bn_apply<<<1024, 256, 0, stream>>>(t1, bnst, bn_g, bn_b, h);

  // --- GAT ---
  k_gemm<256, 4><<<GB, 256, 64 * 256 * 4, stream>>>(h, W_gat, nullptr, t0, N_NODES, 0);
  k_gat_al<<<AB, 256, 0, stream>>>(t0, a_src, a_dst, alsrc, aldst);
  k_gat_stats<<<(N_NODES * 8 + 255) / 256, 256, 0, stream>>>(alsrc, aldst, row_ptr, col_src, m_nh, s_nh);
  k_gat_agg<<<AB, 256, 0, stream>>>(t0, alsrc, aldst, m_nh, s_nh, row_ptr, col_src, b_gat, t1);
  k_bn_stats<<<256, 256, 0, stream>>>(t1, bnst + 512);
  k_bn_apply<<<1024, 256, 0, stream>>>(t1, bnst + 512, bn_g + HID, bn_b + HID, h);

  // --- SAGE ---
  k_sage_agg<<<AB, 256, 0, stream>>>(h, row_ptr, col_src, t0);
  k_gemm<256, 4><<<GB, 256, 64 * 256 * 4, stream>>>(h, W_r, b_l, t1, N_NODES, 0);
  k_gemm<256, 4><<<GB, 256, 64 * 256 * 4, stream>>>(t0, W_l, nullptr, t1, N_NODES, 2);
  k_bn_stats<<<256, 256, 0, stream>>>(t1, bnst + 1024);
  k_bn_apply<<<1024, 256, 0, stream>>>(t1, bnst + 1024, bn_g + 2 * HID, bn_b + 2 * HID, h);

  // --- gate + pooling ---
  k_gemm<256, 2><<<GB, 256, 64 * 256 * 4, stream>>>(h, Wg1, bg1, t0, N_NODES, 1);  // relu
  k_gate<<<AB, 256, 0, stream>>>(t0, Wg2, bg2, gate);
  k_gstart<<<3, 256, 0, stream>>>(batch, gstart);
  k_pool<<<NG, 256, 0, stream>>>(h, gate, gstart, hg);

  // --- heads ---
  k_mlp<<<NG, 256, 0, stream>>>(hg, Wm1, bm1, lnmg, lnmb, Wm2, bm2, out);
  k_mlp<<<NG, 256, 0, stream>>>(hg, Wv1, bv1, lnvg, lnvb, Wv2, bv2, out + (size_t)NG * 64);
}

// Round 2
// 1082.644 us; speedup vs baseline: 1.2005x; 1.2005x over previous
//
#include <hip/hip_runtime.h>
#include <cstdint>
#include <cstddef>

#define N_NODES 50000
#define N_EDGES 500000
#define NG 512
#define HID 256
#define EPS 1e-5f

typedef __attribute__((ext_vector_type(8))) __bf16 bf16x8;
typedef __attribute__((ext_vector_type(4))) float f32x4;

__device__ __forceinline__ ushort f2bf(float f) {
  uint32_t u = __float_as_uint(f);
  uint32_t r = (u + 0x7fffu + ((u >> 16) & 1u)) >> 16;
  return (ushort)r;
}
__device__ __forceinline__ float bfu(ushort u) { return __uint_as_float(((uint32_t)u) << 16); }
__device__ __forceinline__ float4 bf4(ushort4 u) {
  return make_float4(bfu(u.x), bfu(u.y), bfu(u.z), bfu(u.w));
}

// ---------------- CSR build ----------------
__global__ void k_csr_count(const int* __restrict__ ei, int* __restrict__ cnt) {
  int e = blockIdx.x * 256 + threadIdx.x;
  if (e < N_EDGES) atomicAdd(&cnt[ei[N_EDGES + e]], 1);
}

__global__ void k_scan(const int* __restrict__ cnt, int* __restrict__ row_ptr) {
  __shared__ int ps[1024];
  const int CH = (N_NODES + 1023) / 1024;
  int tid = threadIdx.x;
  int b = tid * CH, e = min(b + CH, N_NODES);
  int s = 0;
  for (int i = b; i < e; i++) s += cnt[i];
  ps[tid] = s;
  __syncthreads();
  for (int o = 1; o < 1024; o <<= 1) {
    int add = (tid >= o) ? ps[tid - o] : 0;
    __syncthreads();
    ps[tid] += add;
    __syncthreads();
  }
  int run = (tid > 0) ? ps[tid - 1] : 0;
  for (int i = b; i < e; i++) { row_ptr[i] = run; run += cnt[i]; }
  if (tid == 1023) row_ptr[N_NODES] = ps[1023];
}

__global__ void k_csr_fill(const int* __restrict__ ei, const int* __restrict__ row_ptr,
                           int* __restrict__ fill, int* __restrict__ col_src) {
  int e = blockIdx.x * 256 + threadIdx.x;
  if (e >= N_EDGES) return;
  int s = ei[e], d = ei[N_EDGES + e];
  int pos = row_ptr[d] + atomicAdd(&fill[d], 1);
  col_src[pos] = s;
}

__global__ void k_dis(const int* __restrict__ row_ptr, float* __restrict__ dis) {
  int i = blockIdx.x * 256 + threadIdx.x;
  if (i < N_NODES) dis[i] = rsqrtf((float)(row_ptr[i + 1] - row_ptr[i]) + 1.0f);
}

// ---------------- conversions ----------------
__global__ void k_f2bf(const float* __restrict__ in, ushort* __restrict__ o, int n4) {
  int i = blockIdx.x * 256 + threadIdx.x;
  if (i >= n4) return;
  float4 v = reinterpret_cast<const float4*>(in)[i];
  reinterpret_cast<ushort4*>(o)[i] = make_ushort4(f2bf(v.x), f2bf(v.y), f2bf(v.z), f2bf(v.w));
}

// W [K,C] fp32 -> Wt [C,K] bf16
__global__ void k_wt(const float* __restrict__ W, ushort* __restrict__ Wt, int K, int C) {
  int i = blockIdx.x * 256 + threadIdx.x;
  if (i >= K * C) return;
  int c = i / K, k = i - c * K;
  Wt[i] = f2bf(W[k * C + c]);
}

// ---------------- MFMA GEMM ----------------
// out[M, NCT*16] = A1[M,K]@W1^T (+ A2[M,K]@W2^T) + bias; A row-major bf16,
// W given transposed [C,K] bf16. 256 thr = 4 waves; block covers 64 rows,
// wave w rows w*16..+15, all NCT col-tiles. No LDS, no barriers.
template <int K, int NCT>
__global__ __launch_bounds__(256) void k_mgemm(
    const ushort* __restrict__ A1, const ushort* __restrict__ W1,
    const ushort* __restrict__ A2, const ushort* __restrict__ W2,
    const float* __restrict__ bias, float* __restrict__ out,
    ushort* __restrict__ out_bf, int M, int relu) {
  constexpr int C = NCT * 16;
  constexpr int KS = K / 32;
  const int tid = threadIdx.x;
  const int lane = tid & 63;
  const int wid = tid >> 6;
  const int r16 = lane & 15;   // A-row / B-col / D-col within tile
  const int kg = lane >> 4;    // k-octet group
  const int base = blockIdx.x * 64 + wid * 16;
  int arow = base + r16;
  if (arow >= M) arow = M - 1;

  f32x4 acc[NCT];
#pragma unroll
  for (int c = 0; c < NCT; c++) acc[c] = (f32x4){0.f, 0.f, 0.f, 0.f};

  const int npass = A2 ? 2 : 1;
  for (int p = 0; p < npass; p++) {
    const ushort* __restrict__ A = p ? A2 : A1;
    const ushort* __restrict__ W = p ? W2 : W1;
    bf16x8 af[KS];
    const ushort* ap = A + (size_t)arow * K + kg * 8;
#pragma unroll
    for (int ks = 0; ks < KS; ks++)
      af[ks] = *reinterpret_cast<const bf16x8*>(ap + ks * 32);
#pragma unroll
    for (int c = 0; c < NCT; c++) {
      const ushort* wp = W + (size_t)(c * 16 + r16) * K + kg * 8;
#pragma unroll
      for (int ks = 0; ks < KS; ks++) {
        bf16x8 bfr = *reinterpret_cast<const bf16x8*>(wp + ks * 32);
        acc[c] = __builtin_amdgcn_mfma_f32_16x16x32_bf16(af[ks], bfr, acc[c], 0, 0, 0);
      }
    }
  }

#pragma unroll
  for (int c = 0; c < NCT; c++) {
    int col = c * 16 + r16;
    float bv = bias ? bias[col] : 0.f;
#pragma unroll
    for (int i = 0; i < 4; i++) {
      int row = base + kg * 4 + i;
      if (row < M) {
        float v = acc[c][i] + bv;
        if (relu) v = fmaxf(v, 0.f);
        if (out) out[(size_t)row * C + col] = v;
        if (out_bf) out_bf[(size_t)row * C + col] = f2bf(v);
      }
    }
  }
}

// ---------------- GCN aggregation (wave per node, bf16 gathers) ----------------
__global__ void k_gcn_agg(const ushort* __restrict__ xt, const float* __restrict__ dis,
                          const int* __restrict__ row_ptr, const int* __restrict__ col_src,
                          const float* __restrict__ b_gcn, float* __restrict__ out) {
  int node = blockIdx.x * 4 + (threadIdx.x >> 6);
  if (node >= N_NODES) return;
  int lane = threadIdx.x & 63;
  float di = dis[node];
  float4 x = bf4(*reinterpret_cast<const ushort4*>(xt + (size_t)node * HID + lane * 4));
  float w0 = di * di;
  float4 acc = make_float4(x.x * w0, x.y * w0, x.z * w0, x.w * w0);
  int b = row_ptr[node], e = row_ptr[node + 1];
  for (int i = b; i < e; i++) {
    int s = col_src[i];
    float nw = di * dis[s];
    float4 xv = bf4(*reinterpret_cast<const ushort4*>(xt + (size_t)s * HID + lane * 4));
    acc.x = fmaf(xv.x, nw, acc.x);
    acc.y = fmaf(xv.y, nw, acc.y);
    acc.z = fmaf(xv.z, nw, acc.z);
    acc.w = fmaf(xv.w, nw, acc.w);
  }
  float4 bb = *reinterpret_cast<const float4*>(b_gcn + lane * 4);
  acc.x += bb.x; acc.y += bb.y; acc.z += bb.z; acc.w += bb.w;
  *reinterpret_cast<float4*>(out + (size_t)node * HID + lane * 4) = acc;
}

// ---------------- GAT ----------------
__global__ void k_gat_al(const ushort* __restrict__ xt, const float* __restrict__ a_src,
                         const float* __restrict__ a_dst, float* __restrict__ alsrc,
                         float* __restrict__ aldst) {
  int node = blockIdx.x * 4 + (threadIdx.x >> 6);
  if (node >= N_NODES) return;
  int lane = threadIdx.x & 63;
  float4 v = bf4(*reinterpret_cast<const ushort4*>(xt + (size_t)node * HID + lane * 4));
  float4 as = *reinterpret_cast<const float4*>(a_src + lane * 4);
  float4 ad = *reinterpret_cast<const float4*>(a_dst + lane * 4);
  float ps = v.x * as.x + v.y * as.y + v.z * as.z + v.w * as.w;
  float pd = v.x * ad.x + v.y * ad.y + v.z * ad.z + v.w * ad.w;
  for (int o = 1; o < 8; o <<= 1) { ps += __shfl_xor(ps, o); pd += __shfl_xor(pd, o); }
  if ((lane & 7) == 0) {
    alsrc[node * 8 + (lane >> 3)] = ps;
    aldst[node * 8 + (lane >> 3)] = pd;
  }
}

__device__ __forceinline__ float leaky02(float x) { return x > 0.f ? x : 0.2f * x; }

__global__ void k_gat_stats(const float* __restrict__ alsrc, const float* __restrict__ aldst,
                            const int* __restrict__ row_ptr, const int* __restrict__ col_src,
                            float* __restrict__ m_nh, float* __restrict__ s_nh) {
  int t = blockIdx.x * 256 + threadIdx.x;  // t = node*8 + head
  if (t >= N_NODES * 8) return;
  int node = t >> 3, hh = t & 7;
  float ad = aldst[t];
  float m = leaky02(alsrc[t] + ad);  // self-loop logit
  float s = 1.0f;
  int b = row_ptr[node], e = row_ptr[node + 1];
  for (int i = b; i < e; i++) {
    int src = col_src[i];
    float l = leaky02(alsrc[src * 8 + hh] + ad);
    if (l > m) { s = s * __expf(m - l) + 1.0f; m = l; }
    else s += __expf(l - m);
  }
  m_nh[t] = m;
  s_nh[t] = s;
}

__global__ void k_gat_agg(const ushort* __restrict__ xt, const float* __restrict__ alsrc,
                          const float* __restrict__ aldst, const float* __restrict__ m_nh,
                          const float* __restrict__ s_nh, const int* __restrict__ row_ptr,
                          const int* __restrict__ col_src, const float* __restrict__ b_gat,
                          float* __restrict__ out) {
  int node = blockIdx.x * 4 + (threadIdx.x >> 6);
  if (node >= N_NODES) return;
  int lane = threadIdx.x & 63;
  int hh = lane >> 3;
  float m = m_nh[node * 8 + hh];
  float inv_s = 1.0f / s_nh[node * 8 + hh];
  float ad = aldst[node * 8 + hh];
  float l0 = leaky02(alsrc[node * 8 + hh] + ad);
  float a0 = __expf(l0 - m) * inv_s;
  float4 x = bf4(*reinterpret_cast<const ushort4*>(xt + (size_t)node * HID + lane * 4));
  float4 acc = make_float4(x.x * a0, x.y * a0, x.z * a0, x.w * a0);
  int b = row_ptr[node], e = row_ptr[node + 1];
  for (int i = b; i < e; i++) {
    int src = col_src[i];
    float l = leaky02(alsrc[src * 8 + hh] + ad);
    float al = __expf(l - m) * inv_s;
    float4 xv = bf4(*reinterpret_cast<const ushort4*>(xt + (size_t)src * HID + lane * 4));
    acc.x = fmaf(xv.x, al, acc.x);
    acc.y = fmaf(xv.y, al, acc.y);
    acc.z = fmaf(xv.z, al, acc.z);
    acc.w = fmaf(xv.w, al, acc.w);
  }
  float4 bb = *reinterpret_cast<const float4*>(b_gat + lane * 4);
  acc.x += bb.x; acc.y += bb.y; acc.z += bb.z; acc.w += bb.w;
  *reinterpret_cast<float4*>(out + (size_t)node * HID + lane * 4) = acc;
}

// ---------------- SAGE mean aggregation (bf16 in, bf16 out) ----------------
__global__ void k_sage_agg(const ushort* __restrict__ h, const int* __restrict__ row_ptr,
                           const int* __restrict__ col_src, ushort* __restrict__ out) {
  int node = blockIdx.x * 4 + (threadIdx.x >> 6);
  if (node >= N_NODES) return;
  int lane = threadIdx.x & 63;
  int b = row_ptr[node], e = row_ptr[node + 1];
  float inv = 1.0f / fmaxf((float)(e - b), 1.0f);
  float4 acc = make_float4(0.f, 0.f, 0.f, 0.f);
  for (int i = b; i < e; i++) {
    int s = col_src[i];
    float4 xv = bf4(*reinterpret_cast<const ushort4*>(h + (size_t)s * HID + lane * 4));
    acc.x += xv.x; acc.y += xv.y; acc.z += xv.z; acc.w += xv.w;
  }
  *reinterpret_cast<ushort4*>(out + (size_t)node * HID + lane * 4) =
      make_ushort4(f2bf(acc.x * inv), f2bf(acc.y * inv), f2bf(acc.z * inv), f2bf(acc.w * inv));
}

// ---------------- BatchNorm ----------------
__global__ void k_bn_stats(const float* __restrict__ x, float* __restrict__ stats) {
  int c = threadIdx.x;
  float s = 0.f, q = 0.f;
  for (int r = blockIdx.x; r < N_NODES; r += gridDim.x) {
    float v = x[(size_t)r * HID + c];
    s += v;
    q = fmaf(v, v, q);
  }
  atomicAdd(&stats[c], s);
  atomicAdd(&stats[HID + c], q);
}

// h += relu(bn(x)); also emit h_bf
__global__ void k_bn_apply(const float* __restrict__ x, const float* __restrict__ stats,
                           const float* __restrict__ gamma, const float* __restrict__ beta,
                           float* __restrict__ h, ushort* __restrict__ h_bf) {
  const float invN = 1.0f / (float)N_NODES;
  int total = N_NODES * 64;
  for (int i = blockIdx.x * 256 + threadIdx.x; i < total; i += gridDim.x * 256) {
    int c4 = (i & 63) * 4;
    float4 xv = *reinterpret_cast<const float4*>(x + (size_t)i * 4);
    float4 sm = *reinterpret_cast<const float4*>(stats + c4);
    float4 sq = *reinterpret_cast<const float4*>(stats + HID + c4);
    float4 gm = *reinterpret_cast<const float4*>(gamma + c4);
    float4 bt = *reinterpret_cast<const float4*>(beta + c4);
    float4 hv = *reinterpret_cast<const float4*>(h + (size_t)i * 4);
#define BN1(f)                                                    \
  {                                                               \
    float mu = sm.f * invN;                                       \
    float var = sq.f * invN - mu * mu;                            \
    float sc = gm.f * rsqrtf(var + EPS);                          \
    float v = (xv.f - mu) * sc + bt.f;                            \
    hv.f += fmaxf(v, 0.f);                                        \
  }
    BN1(x) BN1(y) BN1(z) BN1(w)
#undef BN1
    *reinterpret_cast<float4*>(h + (size_t)i * 4) = hv;
    *reinterpret_cast<ushort4*>(h_bf + (size_t)i * 4) =
        make_ushort4(f2bf(hv.x), f2bf(hv.y), f2bf(hv.z), f2bf(hv.w));
  }
}

// ---------------- gate: dot(relu_hidden, Wg2) + bg2 ----------------
__global__ void k_gate(const float* __restrict__ tg, const float* __restrict__ Wg2,
                       const float* __restrict__ bg2, float* __restrict__ gate) {
  int node = blockIdx.x * 4 + (threadIdx.x >> 6);
  if (node >= N_NODES) return;
  int lane = threadIdx.x & 63;
  float v = tg[(size_t)node * 128 + lane] * Wg2[lane] +
            tg[(size_t)node * 128 + 64 + lane] * Wg2[64 + lane];
  for (int o = 1; o < 64; o <<= 1) v += __shfl_xor(v, o);
  if (lane == 0) gate[node] = v + bg2[0];
}

// ---------------- graph segment starts ----------------
__global__ void k_gstart(const int* __restrict__ batch, int* __restrict__ gstart) {
  int g = blockIdx.x * 256 + threadIdx.x;
  if (g > NG) return;
  int lo = 0, hi = N_NODES;
  while (lo < hi) {
    int mid = (lo + hi) >> 1;
    if (batch[mid] < g) lo = mid + 1; else hi = mid;
  }
  gstart[g] = lo;
}

// ---------------- global attention pooling ----------------
__global__ void k_pool(const float* __restrict__ h, const float* __restrict__ gate,
                       const int* __restrict__ gstart, float* __restrict__ hg) {
  __shared__ float red[256];
  __shared__ float wbuf[256];
  int g = blockIdx.x, tid = threadIdx.x;
  int b = gstart[g], e = gstart[g + 1];
  float m = -1e30f;
  for (int r = b + tid; r < e; r += 256) m = fmaxf(m, gate[r]);
  red[tid] = m;
  __syncthreads();
  for (int o = 128; o > 0; o >>= 1) {
    if (tid < o) red[tid] = fmaxf(red[tid], red[tid + o]);
    __syncthreads();
  }
  m = red[0];
  __syncthreads();
  float s = 0.f;
  for (int r = b + tid; r < e; r += 256) s += __expf(gate[r] - m);
  red[tid] = s;
  __syncthreads();
  for (int o = 128; o > 0; o >>= 1) {
    if (tid < o) red[tid] += red[tid + o];
    __syncthreads();
  }
  float inv = 1.0f / fmaxf(red[0], 1e-16f);
  __syncthreads();
  float acc = 0.f;
  for (int cb = b; cb < e; cb += 256) {
    int r = cb + tid;
    wbuf[tid] = (r < e) ? __expf(gate[r] - m) : 0.f;
    __syncthreads();
    int n = min(256, e - cb);
    for (int j = 0; j < n; j++) acc = fmaf(h[(size_t)(cb + j) * HID + tid], wbuf[j], acc);
    __syncthreads();
  }
  hg[(size_t)g * HID + tid] = acc * inv;
}

// ---------------- MLP head ----------------
__global__ void k_mlp(const float* __restrict__ hg, const float* __restrict__ W1,
                      const float* __restrict__ b1, const float* __restrict__ lng,
                      const float* __restrict__ lnb, const float* __restrict__ W2,
                      const float* __restrict__ b2, float* __restrict__ out) {
  __shared__ float row[HID];
  __shared__ float z[HID];
  __shared__ float red[HID];
  int g = blockIdx.x, tid = threadIdx.x;
  row[tid] = hg[(size_t)g * HID + tid];
  __syncthreads();
  float acc = b1[tid];
  for (int k = 0; k < HID; k++) acc = fmaf(row[k], W1[(size_t)k * HID + tid], acc);
  red[tid] = acc;
  __syncthreads();
  for (int o = 128; o > 0; o >>= 1) {
    if (tid < o) red[tid] += red[tid + o];
    __syncthreads();
  }
  float mu = red[0] * (1.0f / HID);
  __syncthreads();
  red[tid] = acc * acc;
  __syncthreads();
  for (int o = 128; o > 0; o >>= 1) {
    if (tid < o) red[tid] += red[tid + o];
    __syncthreads();
  }
  float var = red[0] * (1.0f / HID) - mu * mu;
  float zz = (acc - mu) * rsqrtf(var + EPS) * lng[tid] + lnb[tid];
  z[tid] = fmaxf(zz, 0.f);
  __syncthreads();
  if (tid < 64) {
    float o = b2[tid];
    for (int k = 0; k < HID; k++) o = fmaf(z[k], W2[(size_t)k * 64 + tid], o);
    out[(size_t)g * 64 + tid] = o;
  }
}

// ---------------- launch ----------------
extern "C" void kernel_launch(void* const* d_in, const int* in_sizes, int n_in,
                              void* d_out, int out_size, void* d_ws, size_t ws_size,
                              hipStream_t stream) {
  const float* x     = (const float*)d_in[0];
  const float* W_emb = (const float*)d_in[1];
  const float* b_emb = (const float*)d_in[2];
  const float* W_gcn = (const float*)d_in[3];
  const float* b_gcn = (const float*)d_in[4];
  const float* W_gat = (const float*)d_in[5];
  const float* a_src = (const float*)d_in[6];
  const float* a_dst = (const float*)d_in[7];
  const float* b_gat = (const float*)d_in[8];
  const float* W_l   = (const float*)d_in[9];
  const float* b_l   = (const float*)d_in[10];
  const float* W_r   = (const float*)d_in[11];
  const float* bn_g  = (const float*)d_in[12];
  const float* bn_b  = (const float*)d_in[13];
  const float* Wg1   = (const float*)d_in[14];
  const float* bg1   = (const float*)d_in[15];
  const float* Wg2   = (const float*)d_in[16];
  const float* bg2   = (const float*)d_in[17];
  const float* Wm1   = (const float*)d_in[18];
  const float* bm1   = (const float*)d_in[19];
  const float* lnmg  = (const float*)d_in[20];
  const float* lnmb  = (const float*)d_in[21];
  const float* Wm2   = (const float*)d_in[22];
  const float* bm2   = (const float*)d_in[23];
  const float* Wv1   = (const float*)d_in[24];
  const float* bv1   = (const float*)d_in[25];
  const float* lnvg  = (const float*)d_in[26];
  const float* lnvb  = (const float*)d_in[27];
  const float* Wv2   = (const float*)d_in[28];
  const float* bv2   = (const float*)d_in[29];
  const int* ei      = (const int*)d_in[30];
  const int* batch   = (const int*)d_in[31];
  float* out = (float*)d_out;

  float* ws = (float*)d_ws;
  float* h     = ws;
  float* t1    = h + (size_t)N_NODES * HID;
  float* alsrc = t1 + (size_t)N_NODES * HID;
  float* aldst = alsrc + N_NODES * 8;
  float* m_nh  = aldst + N_NODES * 8;
  float* s_nh  = m_nh + N_NODES * 8;
  float* dis   = s_nh + N_NODES * 8;
  float* gate  = dis + N_NODES;
  float* hg    = gate + N_NODES;
  float* zbase = hg + NG * HID;        // zeroed region: bnst + row_cnt + fill
  float* bnst  = zbase;                // 3 * 512
  int* row_cnt = (int*)(zbase + 3 * 512);
  int* fill    = row_cnt + N_NODES;
  int* row_ptr = fill + N_NODES;
  int* col_src = row_ptr + N_NODES + 1;
  int* gstart  = col_src + N_EDGES;

  size_t off = (size_t)((char*)(gstart + NG + 1) - (char*)d_ws);
  off = (off + 15) & ~(size_t)15;
  ushort* h_bf   = (ushort*)((char*)d_ws + off);
  ushort* t0_bf  = h_bf + (size_t)N_NODES * HID;
  ushort* x_bf   = t0_bf;  // alias: x_bf consumed before t0_bf first written
  ushort* wemb_t = t0_bf + (size_t)N_NODES * HID;
  ushort* wgcn_t = wemb_t + 128 * 256;
  ushort* wgat_t = wgcn_t + 256 * 256;
  ushort* wr_t   = wgat_t + 256 * 256;
  ushort* wl_t   = wr_t + 256 * 256;
  ushort* wg1_t  = wl_t + 256 * 256;   // 128*256

  size_t zbytes = (size_t)3 * 512 * 4 + 2 * (size_t)N_NODES * 4;
  hipMemsetAsync(zbase, 0, zbytes, stream);

  // CSR by dst
  k_csr_count<<<(N_EDGES + 255) / 256, 256, 0, stream>>>(ei, row_cnt);
  k_scan<<<1, 1024, 0, stream>>>(row_cnt, row_ptr);
  k_csr_fill<<<(N_EDGES + 255) / 256, 256, 0, stream>>>(ei, row_ptr, fill, col_src);
  k_dis<<<(N_NODES + 255) / 256, 256, 0, stream>>>(row_ptr, dis);

  // weight transposes + x conversion
  k_wt<<<128, 256, 0, stream>>>(W_emb, wemb_t, 128, 256);
  k_wt<<<256, 256, 0, stream>>>(W_gcn, wgcn_t, 256, 256);
  k_wt<<<256, 256, 0, stream>>>(W_gat, wgat_t, 256, 256);
  k_wt<<<256, 256, 0, stream>>>(W_r, wr_t, 256, 256);
  k_wt<<<256, 256, 0, stream>>>(W_l, wl_t, 256, 256);
  k_wt<<<128, 256, 0, stream>>>(Wg1, wg1_t, 256, 128);
  k_f2bf<<<(N_NODES * 128 / 4 + 255) / 256, 256, 0, stream>>>(x, x_bf, N_NODES * 128 / 4);

  const int GB = (N_NODES + 63) / 64;   // 782
  const int AB = (N_NODES + 3) / 4;     // 12500

  // embedding: h = x @ W_emb + b_emb  (fp32 trunk + bf16 copy)
  k_mgemm<128, 16><<<GB, 256, 0, stream>>>(x_bf, wemb_t, nullptr, nullptr, b_emb, h, h_bf, N_NODES, 0);

  // --- GCN ---
  k_mgemm<256, 16><<<GB, 256, 0, stream>>>(h_bf, wgcn_t, nullptr, nullptr, nullptr, nullptr, t0_bf, N_NODES, 0);
  k_gcn_agg<<<AB, 256, 0, stream>>>(t0_bf, dis, row_ptr, col_src, b_gcn, t1);
  k_bn_stats<<<256, 256, 0, stream>>>(t1, bnst);
  k_bn_apply<<<1024, 256, 0, stream>>>(t1, bnst, bn_g, bn_b, h, h_bf);

  // --- GAT ---
  k_mgemm<256, 16><<<GB, 256, 0, stream>>>(h_bf, wgat_t, nullptr, nullptr, nullptr, nullptr, t0_bf, N_NODES, 0);
  k_gat_al<<<AB, 256, 0, stream>>>(t0_bf, a_src, a_dst, alsrc, aldst);
  k_gat_stats<<<(N_NODES * 8 + 255) / 256, 256, 0, stream>>>(alsrc, aldst, row_ptr, col_src, m_nh, s_nh);
  k_gat_agg<<<AB, 256, 0, stream>>>(t0_bf, alsrc, aldst, m_nh, s_nh, row_ptr, col_src, b_gat, t1);
  k_bn_stats<<<256, 256, 0, stream>>>(t1, bnst + 512);
  k_bn_apply<<<1024, 256, 0, stream>>>(t1, bnst + 512, bn_g + HID, bn_b + HID, h, h_bf);

  // --- SAGE: t1 = h@W_r + b_l + mean@W_l (dual-pass GEMM) ---
  k_sage_agg<<<AB, 256, 0, stream>>>(h_bf, row_ptr, col_src, t0_bf);
  k_mgemm<256, 16><<<GB, 256, 0, stream>>>(h_bf, wr_t, t0_bf, wl_t, b_l, t1, nullptr, N_NODES, 0);
  k_bn_stats<<<256, 256, 0, stream>>>(t1, bnst + 1024);
  k_bn_apply<<<1024, 256, 0, stream>>>(t1, bnst + 1024, bn_g + 2 * HID, bn_b + 2 * HID, h, h_bf);

  // --- gate + pooling ---
  k_mgemm<256, 8><<<GB, 256, 0, stream>>>(h_bf, wg1_t, nullptr, nullptr, bg1, t1, nullptr, N_NODES, 1);
  k_gate<<<AB, 256, 0, stream>>>(t1, Wg2, bg2, gate);
  k_gstart<<<3, 256, 0, stream>>>(batch, gstart);
  k_pool<<<NG, 256, 0, stream>>>(h, gate, gstart, hg);

  // --- heads ---
  k_mlp<<<NG, 256, 0, stream>>>(hg, Wm1, bm1, lnmg, lnmb, Wm2, bm2, out);
  k_mlp<<<NG, 256, 0, stream>>>(hg, Wv1, bv1, lnvg, lnvb, Wv2, bv2, out + (size_t)NG * 64);
}

// Round 3
// 888.162 us; speedup vs baseline: 1.4634x; 1.2190x over previous
//
#include <hip/hip_runtime.h>
#include <cstdint>
#include <cstddef>

#define N_NODES 50000
#define N_EDGES 500000
#define NG 512
#define HID 256
#define EPS 1e-5f

typedef __attribute__((ext_vector_type(8))) __bf16 bf16x8;
typedef __attribute__((ext_vector_type(4))) float f32x4;

__device__ __forceinline__ ushort f2bf(float f) {
  uint32_t u = __float_as_uint(f);
  uint32_t r = (u + 0x7fffu + ((u >> 16) & 1u)) >> 16;
  return (ushort)r;
}
__device__ __forceinline__ float bfu(ushort u) { return __uint_as_float(((uint32_t)u) << 16); }
__device__ __forceinline__ float4 bf4(ushort4 u) {
  return make_float4(bfu(u.x), bfu(u.y), bfu(u.z), bfu(u.w));
}

// ---------------- CSR build ----------------
__global__ void k_csr_count(const int* __restrict__ ei, int* __restrict__ cnt) {
  int e = blockIdx.x * 256 + threadIdx.x;
  if (e < N_EDGES) atomicAdd(&cnt[ei[N_EDGES + e]], 1);
}

__global__ void k_scan(const int* __restrict__ cnt, int* __restrict__ row_ptr) {
  __shared__ int ps[1024];
  const int CH = (N_NODES + 1023) / 1024;
  int tid = threadIdx.x;
  int b = tid * CH, e = min(b + CH, N_NODES);
  int s = 0;
  for (int i = b; i < e; i++) s += cnt[i];
  ps[tid] = s;
  __syncthreads();
  for (int o = 1; o < 1024; o <<= 1) {
    int add = (tid >= o) ? ps[tid - o] : 0;
    __syncthreads();
    ps[tid] += add;
    __syncthreads();
  }
  int run = (tid > 0) ? ps[tid - 1] : 0;
  for (int i = b; i < e; i++) { row_ptr[i] = run; run += cnt[i]; }
  if (tid == 1023) row_ptr[N_NODES] = ps[1023];
}

__global__ void k_csr_fill(const int* __restrict__ ei, const int* __restrict__ row_ptr,
                           int* __restrict__ fill, int* __restrict__ col_src) {
  int e = blockIdx.x * 256 + threadIdx.x;
  if (e >= N_EDGES) return;
  int s = ei[e], d = ei[N_EDGES + e];
  int pos = row_ptr[d] + atomicAdd(&fill[d], 1);
  col_src[pos] = s;
}

__global__ void k_dis(const int* __restrict__ row_ptr, float* __restrict__ dis) {
  int i = blockIdx.x * 256 + threadIdx.x;
  if (i < N_NODES) dis[i] = rsqrtf((float)(row_ptr[i + 1] - row_ptr[i]) + 1.0f);
}

// ---------------- conversions ----------------
__global__ void k_f2bf(const float* __restrict__ in, ushort* __restrict__ o, int n4) {
  int i = blockIdx.x * 256 + threadIdx.x;
  if (i >= n4) return;
  float4 v = reinterpret_cast<const float4*>(in)[i];
  reinterpret_cast<ushort4*>(o)[i] = make_ushort4(f2bf(v.x), f2bf(v.y), f2bf(v.z), f2bf(v.w));
}

// W [K,C] fp32 -> Wt [C,K] bf16
__global__ void k_wt(const float* __restrict__ W, ushort* __restrict__ Wt, int K, int C) {
  int i = blockIdx.x * 256 + threadIdx.x;
  if (i >= K * C) return;
  int c = i / K, k = i - c * K;
  Wt[i] = f2bf(W[k * C + c]);
}

// ---------------- MFMA GEMM, tiled ----------------
// out[M,C] = A1@W1t^T (+A2@W2t^T) + bias. A row-major bf16 [M,K]; Wt [C,K] bf16.
// Grid: (ceil(M/128), C/64). Block: 256 thr = 4 waves; wave owns 32 rows x 64 cols.
// W col-panel (64 x K bf16) staged in LDS with XOR chunk swizzle; A read direct.
template <int K, int C, bool DUAL>
__global__ __launch_bounds__(256) void k_mgemm(
    const ushort* __restrict__ A1, const ushort* __restrict__ W1t,
    const ushort* __restrict__ A2, const ushort* __restrict__ W2t,
    const float* __restrict__ bias, float* __restrict__ out,
    ushort* __restrict__ out_bf, int M, int relu) {
  constexpr int KS = K / 32;    // MFMA k-steps
  constexpr int CHK = K / 8;    // 16B chunks per col-row of panel
  __shared__ ushort wlds[64 * K];  // 32KB (K=256) / 16KB (K=128)
  const int tid = threadIdx.x;
  const int lane = tid & 63;
  const int wid = tid >> 6;
  const int r16 = lane & 15;
  const int kg = lane >> 4;
  const int c0 = blockIdx.y * 64;
  const int rbase = blockIdx.x * 128 + wid * 32;

  f32x4 acc[2][4];
#pragma unroll
  for (int rt = 0; rt < 2; rt++)
#pragma unroll
    for (int c = 0; c < 4; c++) acc[rt][c] = (f32x4){0.f, 0.f, 0.f, 0.f};

#pragma unroll
  for (int p = 0; p < (DUAL ? 2 : 1); p++) {
    const ushort* __restrict__ A = p ? A2 : A1;
    const ushort* __restrict__ Wt = p ? W2t : W1t;
    if (p) __syncthreads();  // drain reads of previous panel
    // stage 64 x K panel, chunk-swizzled: slot = c*CHK + (k16 ^ (c&7))
#pragma unroll
    for (int j = 0; j < (64 * CHK) / 256; j++) {
      int ci = j * 256 + tid;
      int c = ci / CHK, k16 = ci % CHK;
      int slot = c * CHK + (k16 ^ (c & 7));
      *reinterpret_cast<float4*>(&wlds[slot * 8]) =
          *reinterpret_cast<const float4*>(&Wt[(size_t)(c0 + c) * K + k16 * 8]);
    }
    __syncthreads();
#pragma unroll
    for (int rt = 0; rt < 2; rt++) {
      int arow = rbase + rt * 16 + r16;
      if (arow >= M) arow = M - 1;
      const ushort* ap = A + (size_t)arow * K + kg * 8;
      bf16x8 af[KS];
#pragma unroll
      for (int ks = 0; ks < KS; ks++)
        af[ks] = *reinterpret_cast<const bf16x8*>(ap + ks * 32);
#pragma unroll
      for (int ks = 0; ks < KS; ks++) {
#pragma unroll
        for (int c = 0; c < 4; c++) {
          int col = c * 16 + r16;
          int slot = col * CHK + ((ks * 4 + kg) ^ (r16 & 7));
          bf16x8 bfr = *reinterpret_cast<const bf16x8*>(&wlds[slot * 8]);
          acc[rt][c] = __builtin_amdgcn_mfma_f32_16x16x32_bf16(af[ks], bfr, acc[rt][c], 0, 0, 0);
        }
      }
    }
  }

#pragma unroll
  for (int rt = 0; rt < 2; rt++) {
#pragma unroll
    for (int c = 0; c < 4; c++) {
      int col = c0 + c * 16 + r16;
      float bv = bias ? bias[col] : 0.f;
#pragma unroll
      for (int i = 0; i < 4; i++) {
        int row = rbase + rt * 16 + kg * 4 + i;
        if (row < M) {
          float v = acc[rt][c][i] + bv;
          if (relu) v = fmaxf(v, 0.f);
          if (out) out[(size_t)row * C + col] = v;
          if (out_bf) out_bf[(size_t)row * C + col] = f2bf(v);
        }
      }
    }
  }
}

// ---------------- GCN aggregation (wave per node, bf16 gathers) ----------------
__global__ void k_gcn_agg(const ushort* __restrict__ xt, const float* __restrict__ dis,
                          const int* __restrict__ row_ptr, const int* __restrict__ col_src,
                          const float* __restrict__ b_gcn, float* __restrict__ out) {
  int node = blockIdx.x * 4 + (threadIdx.x >> 6);
  if (node >= N_NODES) return;
  int lane = threadIdx.x & 63;
  float di = dis[node];
  float4 x = bf4(*reinterpret_cast<const ushort4*>(xt + (size_t)node * HID + lane * 4));
  float w0 = di * di;
  float4 acc = make_float4(x.x * w0, x.y * w0, x.z * w0, x.w * w0);
  int b = row_ptr[node], e = row_ptr[node + 1];
  for (int i = b; i < e; i++) {
    int s = col_src[i];
    float nw = di * dis[s];
    float4 xv = bf4(*reinterpret_cast<const ushort4*>(xt + (size_t)s * HID + lane * 4));
    acc.x = fmaf(xv.x, nw, acc.x);
    acc.y = fmaf(xv.y, nw, acc.y);
    acc.z = fmaf(xv.z, nw, acc.z);
    acc.w = fmaf(xv.w, nw, acc.w);
  }
  float4 bb = *reinterpret_cast<const float4*>(b_gcn + lane * 4);
  acc.x += bb.x; acc.y += bb.y; acc.z += bb.z; acc.w += bb.w;
  *reinterpret_cast<float4*>(out + (size_t)node * HID + lane * 4) = acc;
}

// ---------------- GAT ----------------
__global__ void k_gat_al(const ushort* __restrict__ xt, const float* __restrict__ a_src,
                         const float* __restrict__ a_dst, float* __restrict__ alsrc,
                         float* __restrict__ aldst) {
  int node = blockIdx.x * 4 + (threadIdx.x >> 6);
  if (node >= N_NODES) return;
  int lane = threadIdx.x & 63;
  float4 v = bf4(*reinterpret_cast<const ushort4*>(xt + (size_t)node * HID + lane * 4));
  float4 as = *reinterpret_cast<const float4*>(a_src + lane * 4);
  float4 ad = *reinterpret_cast<const float4*>(a_dst + lane * 4);
  float ps = v.x * as.x + v.y * as.y + v.z * as.z + v.w * as.w;
  float pd = v.x * ad.x + v.y * ad.y + v.z * ad.z + v.w * ad.w;
  for (int o = 1; o < 8; o <<= 1) { ps += __shfl_xor(ps, o); pd += __shfl_xor(pd, o); }
  if ((lane & 7) == 0) {
    alsrc[node * 8 + (lane >> 3)] = ps;
    aldst[node * 8 + (lane >> 3)] = pd;
  }
}

__device__ __forceinline__ float leaky02(float x) { return x > 0.f ? x : 0.2f * x; }

__global__ void k_gat_stats(const float* __restrict__ alsrc, const float* __restrict__ aldst,
                            const int* __restrict__ row_ptr, const int* __restrict__ col_src,
                            float* __restrict__ m_nh, float* __restrict__ s_nh) {
  int t = blockIdx.x * 256 + threadIdx.x;  // t = node*8 + head
  if (t >= N_NODES * 8) return;
  int node = t >> 3, hh = t & 7;
  float ad = aldst[t];
  float m = leaky02(alsrc[t] + ad);  // self-loop logit
  float s = 1.0f;
  int b = row_ptr[node], e = row_ptr[node + 1];
  for (int i = b; i < e; i++) {
    int src = col_src[i];
    float l = leaky02(alsrc[src * 8 + hh] + ad);
    if (l > m) { s = s * __expf(m - l) + 1.0f; m = l; }
    else s += __expf(l - m);
  }
  m_nh[t] = m;
  s_nh[t] = s;
}

__global__ void k_gat_agg(const ushort* __restrict__ xt, const float* __restrict__ alsrc,
                          const float* __restrict__ aldst, const float* __restrict__ m_nh,
                          const float* __restrict__ s_nh, const int* __restrict__ row_ptr,
                          const int* __restrict__ col_src, const float* __restrict__ b_gat,
                          float* __restrict__ out) {
  int node = blockIdx.x * 4 + (threadIdx.x >> 6);
  if (node >= N_NODES) return;
  int lane = threadIdx.x & 63;
  int hh = lane >> 3;
  float m = m_nh[node * 8 + hh];
  float inv_s = 1.0f / s_nh[node * 8 + hh];
  float ad = aldst[node * 8 + hh];
  float l0 = leaky02(alsrc[node * 8 + hh] + ad);
  float a0 = __expf(l0 - m) * inv_s;
  float4 x = bf4(*reinterpret_cast<const ushort4*>(xt + (size_t)node * HID + lane * 4));
  float4 acc = make_float4(x.x * a0, x.y * a0, x.z * a0, x.w * a0);
  int b = row_ptr[node], e = row_ptr[node + 1];
  for (int i = b; i < e; i++) {
    int src = col_src[i];
    float l = leaky02(alsrc[src * 8 + hh] + ad);
    float al = __expf(l - m) * inv_s;
    float4 xv = bf4(*reinterpret_cast<const ushort4*>(xt + (size_t)src * HID + lane * 4));
    acc.x = fmaf(xv.x, al, acc.x);
    acc.y = fmaf(xv.y, al, acc.y);
    acc.z = fmaf(xv.z, al, acc.z);
    acc.w = fmaf(xv.w, al, acc.w);
  }
  float4 bb = *reinterpret_cast<const float4*>(b_gat + lane * 4);
  acc.x += bb.x; acc.y += bb.y; acc.z += bb.z; acc.w += bb.w;
  *reinterpret_cast<float4*>(out + (size_t)node * HID + lane * 4) = acc;
}

// ---------------- SAGE mean aggregation (bf16 in, bf16 out) ----------------
__global__ void k_sage_agg(const ushort* __restrict__ h, const int* __restrict__ row_ptr,
                           const int* __restrict__ col_src, ushort* __restrict__ out) {
  int node = blockIdx.x * 4 + (threadIdx.x >> 6);
  if (node >= N_NODES) return;
  int lane = threadIdx.x & 63;
  int b = row_ptr[node], e = row_ptr[node + 1];
  float inv = 1.0f / fmaxf((float)(e - b), 1.0f);
  float4 acc = make_float4(0.f, 0.f, 0.f, 0.f);
  for (int i = b; i < e; i++) {
    int s = col_src[i];
    float4 xv = bf4(*reinterpret_cast<const ushort4*>(h + (size_t)s * HID + lane * 4));
    acc.x += xv.x; acc.y += xv.y; acc.z += xv.z; acc.w += xv.w;
  }
  *reinterpret_cast<ushort4*>(out + (size_t)node * HID + lane * 4) =
      make_ushort4(f2bf(acc.x * inv), f2bf(acc.y * inv), f2bf(acc.z * inv), f2bf(acc.w * inv));
}

// ---------------- BatchNorm ----------------
__global__ void k_bn_stats(const float* __restrict__ x, float* __restrict__ stats) {
  int c = threadIdx.x;
  float s = 0.f, q = 0.f;
  for (int r = blockIdx.x; r < N_NODES; r += gridDim.x) {
    float v = x[(size_t)r * HID + c];
    s += v;
    q = fmaf(v, v, q);
  }
  atomicAdd(&stats[c], s);
  atomicAdd(&stats[HID + c], q);
}

// h += relu(bn(x)); also emit h_bf
__global__ void k_bn_apply(const float* __restrict__ x, const float* __restrict__ stats,
                           const float* __restrict__ gamma, const float* __restrict__ beta,
                           float* __restrict__ h, ushort* __restrict__ h_bf) {
  const float invN = 1.0f / (float)N_NODES;
  int total = N_NODES * 64;
  for (int i = blockIdx.x * 256 + threadIdx.x; i < total; i += gridDim.x * 256) {
    int c4 = (i & 63) * 4;
    float4 xv = *reinterpret_cast<const float4*>(x + (size_t)i * 4);
    float4 sm = *reinterpret_cast<const float4*>(stats + c4);
    float4 sq = *reinterpret_cast<const float4*>(stats + HID + c4);
    float4 gm = *reinterpret_cast<const float4*>(gamma + c4);
    float4 bt = *reinterpret_cast<const float4*>(beta + c4);
    float4 hv = *reinterpret_cast<const float4*>(h + (size_t)i * 4);
#define BN1(f)                                                    \
  {                                                               \
    float mu = sm.f * invN;                                       \
    float var = sq.f * invN - mu * mu;                            \
    float sc = gm.f * rsqrtf(var + EPS);                          \
    float v = (xv.f - mu) * sc + bt.f;                            \
    hv.f += fmaxf(v, 0.f);                                        \
  }
    BN1(x) BN1(y) BN1(z) BN1(w)
#undef BN1
    *reinterpret_cast<float4*>(h + (size_t)i * 4) = hv;
    *reinterpret_cast<ushort4*>(h_bf + (size_t)i * 4) =
        make_ushort4(f2bf(hv.x), f2bf(hv.y), f2bf(hv.z), f2bf(hv.w));
  }
}

// ---------------- gate: dot(relu_hidden, Wg2) + bg2 ----------------
__global__ void k_gate(const float* __restrict__ tg, const float* __restrict__ Wg2,
                       const float* __restrict__ bg2, float* __restrict__ gate) {
  int node = blockIdx.x * 4 + (threadIdx.x >> 6);
  if (node >= N_NODES) return;
  int lane = threadIdx.x & 63;
  float v = tg[(size_t)node * 128 + lane] * Wg2[lane] +
            tg[(size_t)node * 128 + 64 + lane] * Wg2[64 + lane];
  for (int o = 1; o < 64; o <<= 1) v += __shfl_xor(v, o);
  if (lane == 0) gate[node] = v + bg2[0];
}

// ---------------- graph segment starts ----------------
__global__ void k_gstart(const int* __restrict__ batch, int* __restrict__ gstart) {
  int g = blockIdx.x * 256 + threadIdx.x;
  if (g > NG) return;
  int lo = 0, hi = N_NODES;
  while (lo < hi) {
    int mid = (lo + hi) >> 1;
    if (batch[mid] < g) lo = mid + 1; else hi = mid;
  }
  gstart[g] = lo;
}

// ---------------- global attention pooling ----------------
__global__ void k_pool(const float* __restrict__ h, const float* __restrict__ gate,
                       const int* __restrict__ gstart, float* __restrict__ hg) {
  __shared__ float red[256];
  __shared__ float wbuf[256];
  int g = blockIdx.x, tid = threadIdx.x;
  int b = gstart[g], e = gstart[g + 1];
  float m = -1e30f;
  for (int r = b + tid; r < e; r += 256) m = fmaxf(m, gate[r]);
  red[tid] = m;
  __syncthreads();
  for (int o = 128; o > 0; o >>= 1) {
    if (tid < o) red[tid] = fmaxf(red[tid], red[tid + o]);
    __syncthreads();
  }
  m = red[0];
  __syncthreads();
  float s = 0.f;
  for (int r = b + tid; r < e; r += 256) s += __expf(gate[r] - m);
  red[tid] = s;
  __syncthreads();
  for (int o = 128; o > 0; o >>= 1) {
    if (tid < o) red[tid] += red[tid + o];
    __syncthreads();
  }
  float inv = 1.0f / fmaxf(red[0], 1e-16f);
  __syncthreads();
  float acc = 0.f;
  for (int cb = b; cb < e; cb += 256) {
    int r = cb + tid;
    wbuf[tid] = (r < e) ? __expf(gate[r] - m) : 0.f;
    __syncthreads();
    int n = min(256, e - cb);
    for (int j = 0; j < n; j++) acc = fmaf(h[(size_t)(cb + j) * HID + tid], wbuf[j], acc);
    __syncthreads();
  }
  hg[(size_t)g * HID + tid] = acc * inv;
}

// ---------------- MLP head ----------------
__global__ void k_mlp(const float* __restrict__ hg, const float* __restrict__ W1,
                      const float* __restrict__ b1, const float* __restrict__ lng,
                      const float* __restrict__ lnb, const float* __restrict__ W2,
                      const float* __restrict__ b2, float* __restrict__ out) {
  __shared__ float row[HID];
  __shared__ float z[HID];
  __shared__ float red[HID];
  int g = blockIdx.x, tid = threadIdx.x;
  row[tid] = hg[(size_t)g * HID + tid];
  __syncthreads();
  float acc = b1[tid];
  for (int k = 0; k < HID; k++) acc = fmaf(row[k], W1[(size_t)k * HID + tid], acc);
  red[tid] = acc;
  __syncthreads();
  for (int o = 128; o > 0; o >>= 1) {
    if (tid < o) red[tid] += red[tid + o];
    __syncthreads();
  }
  float mu = red[0] * (1.0f / HID);
  __syncthreads();
  red[tid] = acc * acc;
  __syncthreads();
  for (int o = 128; o > 0; o >>= 1) {
    if (tid < o) red[tid] += red[tid + o];
    __syncthreads();
  }
  float var = red[0] * (1.0f / HID) - mu * mu;
  float zz = (acc - mu) * rsqrtf(var + EPS) * lng[tid] + lnb[tid];
  z[tid] = fmaxf(zz, 0.f);
  __syncthreads();
  if (tid < 64) {
    float o = b2[tid];
    for (int k = 0; k < HID; k++) o = fmaf(z[k], W2[(size_t)k * 64 + tid], o);
    out[(size_t)g * 64 + tid] = o;
  }
}

// ---------------- launch ----------------
extern "C" void kernel_launch(void* const* d_in, const int* in_sizes, int n_in,
                              void* d_out, int out_size, void* d_ws, size_t ws_size,
                              hipStream_t stream) {
  const float* x     = (const float*)d_in[0];
  const float* W_emb = (const float*)d_in[1];
  const float* b_emb = (const float*)d_in[2];
  const float* W_gcn = (const float*)d_in[3];
  const float* b_gcn = (const float*)d_in[4];
  const float* W_gat = (const float*)d_in[5];
  const float* a_src = (const float*)d_in[6];
  const float* a_dst = (const float*)d_in[7];
  const float* b_gat = (const float*)d_in[8];
  const float* W_l   = (const float*)d_in[9];
  const float* b_l   = (const float*)d_in[10];
  const float* W_r   = (const float*)d_in[11];
  const float* bn_g  = (const float*)d_in[12];
  const float* bn_b  = (const float*)d_in[13];
  const float* Wg1   = (const float*)d_in[14];
  const float* bg1   = (const float*)d_in[15];
  const float* Wg2   = (const float*)d_in[16];
  const float* bg2   = (const float*)d_in[17];
  const float* Wm1   = (const float*)d_in[18];
  const float* bm1   = (const float*)d_in[19];
  const float* lnmg  = (const float*)d_in[20];
  const float* lnmb  = (const float*)d_in[21];
  const float* Wm2   = (const float*)d_in[22];
  const float* bm2   = (const float*)d_in[23];
  const float* Wv1   = (const float*)d_in[24];
  const float* bv1   = (const float*)d_in[25];
  const float* lnvg  = (const float*)d_in[26];
  const float* lnvb  = (const float*)d_in[27];
  const float* Wv2   = (const float*)d_in[28];
  const float* bv2   = (const float*)d_in[29];
  const int* ei      = (const int*)d_in[30];
  const int* batch   = (const int*)d_in[31];
  float* out = (float*)d_out;

  float* ws = (float*)d_ws;
  float* h     = ws;
  float* t1    = h + (size_t)N_NODES * HID;
  float* alsrc = t1 + (size_t)N_NODES * HID;
  float* aldst = alsrc + N_NODES * 8;
  float* m_nh  = aldst + N_NODES * 8;
  float* s_nh  = m_nh + N_NODES * 8;
  float* dis   = s_nh + N_NODES * 8;
  float* gate  = dis + N_NODES;
  float* hg    = gate + N_NODES;
  float* zbase = hg + NG * HID;        // zeroed region: bnst + row_cnt + fill
  float* bnst  = zbase;                // 3 * 512
  int* row_cnt = (int*)(zbase + 3 * 512);
  int* fill    = row_cnt + N_NODES;
  int* row_ptr = fill + N_NODES;
  int* col_src = row_ptr + N_NODES + 1;
  int* gstart  = col_src + N_EDGES;

  size_t off = (size_t)((char*)(gstart + NG + 1) - (char*)d_ws);
  off = (off + 15) & ~(size_t)15;
  ushort* h_bf   = (ushort*)((char*)d_ws + off);
  ushort* t0_bf  = h_bf + (size_t)N_NODES * HID;
  ushort* x_bf   = t0_bf;  // alias: x_bf consumed before t0_bf first written
  ushort* wemb_t = t0_bf + (size_t)N_NODES * HID;
  ushort* wgcn_t = wemb_t + 128 * 256;
  ushort* wgat_t = wgcn_t + 256 * 256;
  ushort* wr_t   = wgat_t + 256 * 256;
  ushort* wl_t   = wr_t + 256 * 256;
  ushort* wg1_t  = wl_t + 256 * 256;   // 128*256

  size_t zbytes = (size_t)3 * 512 * 4 + 2 * (size_t)N_NODES * 4;
  hipMemsetAsync(zbase, 0, zbytes, stream);

  // CSR by dst
  k_csr_count<<<(N_EDGES + 255) / 256, 256, 0, stream>>>(ei, row_cnt);
  k_scan<<<1, 1024, 0, stream>>>(row_cnt, row_ptr);
  k_csr_fill<<<(N_EDGES + 255) / 256, 256, 0, stream>>>(ei, row_ptr, fill, col_src);
  k_dis<<<(N_NODES + 255) / 256, 256, 0, stream>>>(row_ptr, dis);

  // weight transposes + x conversion
  k_wt<<<128, 256, 0, stream>>>(W_emb, wemb_t, 128, 256);
  k_wt<<<256, 256, 0, stream>>>(W_gcn, wgcn_t, 256, 256);
  k_wt<<<256, 256, 0, stream>>>(W_gat, wgat_t, 256, 256);
  k_wt<<<256, 256, 0, stream>>>(W_r, wr_t, 256, 256);
  k_wt<<<256, 256, 0, stream>>>(W_l, wl_t, 256, 256);
  k_wt<<<128, 256, 0, stream>>>(Wg1, wg1_t, 256, 128);
  k_f2bf<<<(N_NODES * 128 / 4 + 255) / 256, 256, 0, stream>>>(x, x_bf, N_NODES * 128 / 4);

  const int RB = (N_NODES + 127) / 128;  // 391 row-blocks
  const int AB = (N_NODES + 3) / 4;      // 12500 agg blocks

  // embedding: h = x @ W_emb + b_emb  (fp32 trunk + bf16 copy)
  k_mgemm<128, 256, false><<<dim3(RB, 4), 256, 0, stream>>>(
      x_bf, wemb_t, nullptr, nullptr, b_emb, h, h_bf, N_NODES, 0);

  // --- GCN ---
  k_mgemm<256, 256, false><<<dim3(RB, 4), 256, 0, stream>>>(
      h_bf, wgcn_t, nullptr, nullptr, nullptr, nullptr, t0_bf, N_NODES, 0);
  k_gcn_agg<<<AB, 256, 0, stream>>>(t0_bf, dis, row_ptr, col_src, b_gcn, t1);
  k_bn_stats<<<256, 256, 0, stream>>>(t1, bnst);
  k_bn_apply<<<1024, 256, 0, stream>>>(t1, bnst, bn_g, bn_b, h, h_bf);

  // --- GAT ---
  k_mgemm<256, 256, false><<<dim3(RB, 4), 256, 0, stream>>>(
      h_bf, wgat_t, nullptr, nullptr, nullptr, nullptr, t0_bf, N_NODES, 0);
  k_gat_al<<<AB, 256, 0, stream>>>(t0_bf, a_src, a_dst, alsrc, aldst);
  k_gat_stats<<<(N_NODES * 8 + 255) / 256, 256, 0, stream>>>(alsrc, aldst, row_ptr, col_src, m_nh, s_nh);
  k_gat_agg<<<AB, 256, 0, stream>>>(t0_bf, alsrc, aldst, m_nh, s_nh, row_ptr, col_src, b_gat, t1);
  k_bn_stats<<<256, 256, 0, stream>>>(t1, bnst + 512);
  k_bn_apply<<<1024, 256, 0, stream>>>(t1, bnst + 512, bn_g + HID, bn_b + HID, h, h_bf);

  // --- SAGE: t1 = h@W_r + b_l + mean@W_l (dual-pass, LDS re-stage) ---
  k_sage_agg<<<AB, 256, 0, stream>>>(h_bf, row_ptr, col_src, t0_bf);
  k_mgemm<256, 256, true><<<dim3(RB, 4), 256, 0, stream>>>(
      h_bf, wr_t, t0_bf, wl_t, b_l, t1, nullptr, N_NODES, 0);
  k_bn_stats<<<256, 256, 0, stream>>>(t1, bnst + 1024);
  k_bn_apply<<<1024, 256, 0, stream>>>(t1, bnst + 1024, bn_g + 2 * HID, bn_b + 2 * HID, h, h_bf);

  // --- gate + pooling ---
  k_mgemm<256, 128, false><<<dim3(RB, 2), 256, 0, stream>>>(
      h_bf, wg1_t, nullptr, nullptr, bg1, t1, nullptr, N_NODES, 1);
  k_gate<<<AB, 256, 0, stream>>>(t1, Wg2, bg2, gate);
  k_gstart<<<3, 256, 0, stream>>>(batch, gstart);
  k_pool<<<NG, 256, 0, stream>>>(h, gate, gstart, hg);

  // --- heads ---
  k_mlp<<<NG, 256, 0, stream>>>(hg, Wm1, bm1, lnmg, lnmb, Wm2, bm2, out);
  k_mlp<<<NG, 256, 0, stream>>>(hg, Wv1, bv1, lnvg, lnvb, Wv2, bv2, out + (size_t)NG * 64);
}

// Round 4
// 792.666 us; speedup vs baseline: 1.6397x; 1.1205x over previous
//
#include <hip/hip_runtime.h>
#include <cstdint>
#include <cstddef>

#define N_NODES 50000
#define N_EDGES 500000
#define NG 512
#define HID 256
#define EPS 1e-5f

typedef __attribute__((ext_vector_type(8))) __bf16 bf16x8;
typedef __attribute__((ext_vector_type(4))) float f32x4;

__device__ __forceinline__ ushort f2bf(float f) {
  uint32_t u = __float_as_uint(f);
  uint32_t r = (u + 0x7fffu + ((u >> 16) & 1u)) >> 16;
  return (ushort)r;
}
__device__ __forceinline__ float bfu(ushort u) { return __uint_as_float(((uint32_t)u) << 16); }
__device__ __forceinline__ float4 bf4(ushort4 u) {
  return make_float4(bfu(u.x), bfu(u.y), bfu(u.z), bfu(u.w));
}

// ---------------- CSR build ----------------
__global__ void k_csr_count(const int* __restrict__ ei, int* __restrict__ cnt) {
  int e = blockIdx.x * 256 + threadIdx.x;
  if (e < N_EDGES) atomicAdd(&cnt[ei[N_EDGES + e]], 1);
}

__global__ void k_scan(const int* __restrict__ cnt, int* __restrict__ row_ptr) {
  __shared__ int ps[1024];
  const int CH = (N_NODES + 1023) / 1024;
  int tid = threadIdx.x;
  int b = tid * CH, e = min(b + CH, N_NODES);
  int s = 0;
  for (int i = b; i < e; i++) s += cnt[i];
  ps[tid] = s;
  __syncthreads();
  for (int o = 1; o < 1024; o <<= 1) {
    int add = (tid >= o) ? ps[tid - o] : 0;
    __syncthreads();
    ps[tid] += add;
    __syncthreads();
  }
  int run = (tid > 0) ? ps[tid - 1] : 0;
  for (int i = b; i < e; i++) { row_ptr[i] = run; run += cnt[i]; }
  if (tid == 1023) row_ptr[N_NODES] = ps[1023];
}

__global__ void k_csr_fill(const int* __restrict__ ei, const int* __restrict__ row_ptr,
                           int* __restrict__ fill, int* __restrict__ col_src) {
  int e = blockIdx.x * 256 + threadIdx.x;
  if (e >= N_EDGES) return;
  int s = ei[e], d = ei[N_EDGES + e];
  int pos = row_ptr[d] + atomicAdd(&fill[d], 1);
  col_src[pos] = s;
}

__global__ void k_dis(const int* __restrict__ row_ptr, float* __restrict__ dis) {
  int i = blockIdx.x * 256 + threadIdx.x;
  if (i < N_NODES) dis[i] = rsqrtf((float)(row_ptr[i + 1] - row_ptr[i]) + 1.0f);
}

// ---------------- conversions ----------------
__global__ void k_f2bf(const float* __restrict__ in, ushort* __restrict__ o, int n4) {
  int i = blockIdx.x * 256 + threadIdx.x;
  if (i >= n4) return;
  float4 v = reinterpret_cast<const float4*>(in)[i];
  reinterpret_cast<ushort4*>(o)[i] = make_ushort4(f2bf(v.x), f2bf(v.y), f2bf(v.z), f2bf(v.w));
}

// W [K,C] fp32 -> Wt [C,K] bf16
__global__ void k_wt(const float* __restrict__ W, ushort* __restrict__ Wt, int K, int C) {
  int i = blockIdx.x * 256 + threadIdx.x;
  if (i >= K * C) return;
  int c = i / K, k = i - c * K;
  Wt[i] = f2bf(W[k * C + c]);
}

// ---------------- MFMA GEMM, tiled ----------------
// out[M,C] = A1@W1t^T (+A2@W2t^T) + bias. A row-major bf16 [M,K]; Wt [C,K] bf16.
// Grid: (C/64, ceil(M/128)). Block: 256 thr = 4 waves; wave owns 32 rows x 64 cols.
// W col-panel staged in LDS (XOR chunk swizzle); A frags hoisted across col loop;
// W frags hoisted across the 2 row-tiles (32 ds_read_b128 / wave instead of 64).
template <int K, int C, bool DUAL>
__global__ __launch_bounds__(256) void k_mgemm(
    const ushort* __restrict__ A1, const ushort* __restrict__ W1t,
    const ushort* __restrict__ A2, const ushort* __restrict__ W2t,
    const float* __restrict__ bias, float* __restrict__ out,
    ushort* __restrict__ out_bf, int M, int relu) {
  constexpr int KS = K / 32;    // MFMA k-steps
  constexpr int CHK = K / 8;    // 16B chunks per col-row of panel
  __shared__ ushort wlds[64 * K];  // 32KB (K=256) / 16KB (K=128)
  const int tid = threadIdx.x;
  const int lane = tid & 63;
  const int wid = tid >> 6;
  const int r16 = lane & 15;
  const int kg = lane >> 4;
  const int c0 = blockIdx.x * 64;
  const int rbase = blockIdx.y * 128 + wid * 32;

  f32x4 acc[2][4];
#pragma unroll
  for (int rt = 0; rt < 2; rt++)
#pragma unroll
    for (int c = 0; c < 4; c++) acc[rt][c] = (f32x4){0.f, 0.f, 0.f, 0.f};

#pragma unroll
  for (int p = 0; p < (DUAL ? 2 : 1); p++) {
    const ushort* __restrict__ A = p ? A2 : A1;
    const ushort* __restrict__ Wt = p ? W2t : W1t;
    if (p) __syncthreads();  // drain reads of previous panel
    // stage 64 x K panel, chunk-swizzled: slot = c*CHK + (k16 ^ (c&7))
#pragma unroll
    for (int jj = 0; jj < (64 * CHK) / 256; jj++) {
      int ci = jj * 256 + tid;
      int c = ci / CHK, k16 = ci % CHK;
      int slot = c * CHK + (k16 ^ (c & 7));
      *reinterpret_cast<float4*>(&wlds[slot * 8]) =
          *reinterpret_cast<const float4*>(&Wt[(size_t)(c0 + c) * K + k16 * 8]);
    }
    __syncthreads();
    // A fragments for both row-tiles (held across the col loop)
    bf16x8 af[2][KS];
#pragma unroll
    for (int rt = 0; rt < 2; rt++) {
      int arow = rbase + rt * 16 + r16;
      if (arow >= M) arow = M - 1;
      const ushort* ap = A + (size_t)arow * K + kg * 8;
#pragma unroll
      for (int ks = 0; ks < KS; ks++)
        af[rt][ks] = *reinterpret_cast<const bf16x8*>(ap + ks * 32);
    }
#pragma unroll
    for (int c = 0; c < 4; c++) {
      bf16x8 wf[KS];
      int colr = c * 16 + r16;
#pragma unroll
      for (int ks = 0; ks < KS; ks++) {
        int slot = colr * CHK + ((ks * 4 + kg) ^ (r16 & 7));
        wf[ks] = *reinterpret_cast<const bf16x8*>(&wlds[slot * 8]);
      }
#pragma unroll
      for (int ks = 0; ks < KS; ks++) {
        acc[0][c] = __builtin_amdgcn_mfma_f32_16x16x32_bf16(af[0][ks], wf[ks], acc[0][c], 0, 0, 0);
        acc[1][c] = __builtin_amdgcn_mfma_f32_16x16x32_bf16(af[1][ks], wf[ks], acc[1][c], 0, 0, 0);
      }
    }
  }

#pragma unroll
  for (int rt = 0; rt < 2; rt++) {
#pragma unroll
    for (int c = 0; c < 4; c++) {
      int col = c0 + c * 16 + r16;
      float bv = bias ? bias[col] : 0.f;
#pragma unroll
      for (int i = 0; i < 4; i++) {
        int row = rbase + rt * 16 + kg * 4 + i;
        if (row < M) {
          float v = acc[rt][c][i] + bv;
          if (relu) v = fmaxf(v, 0.f);
          if (out) out[(size_t)row * C + col] = v;
          if (out_bf) out_bf[(size_t)row * C + col] = f2bf(v);
        }
      }
    }
  }
}

// ---------------- GCN aggregation (wave per node, 4x unrolled gathers) ----------------
__global__ void k_gcn_agg(const ushort* __restrict__ xt, const float* __restrict__ dis,
                          const int* __restrict__ row_ptr, const int* __restrict__ col_src,
                          const float* __restrict__ b_gcn, float* __restrict__ out) {
  int node = blockIdx.x * 4 + (threadIdx.x >> 6);
  if (node >= N_NODES) return;
  int lane = threadIdx.x & 63;
  float di = dis[node];
  float4 x = bf4(*reinterpret_cast<const ushort4*>(xt + (size_t)node * HID + lane * 4));
  float w0 = di * di;
  float4 acc = make_float4(x.x * w0, x.y * w0, x.z * w0, x.w * w0);
  int b = row_ptr[node], e = row_ptr[node + 1];
  int i = b;
  for (; i + 4 <= e; i += 4) {
    int s0 = col_src[i], s1 = col_src[i + 1], s2 = col_src[i + 2], s3 = col_src[i + 3];
    ushort4 u0 = *reinterpret_cast<const ushort4*>(xt + (size_t)s0 * HID + lane * 4);
    ushort4 u1 = *reinterpret_cast<const ushort4*>(xt + (size_t)s1 * HID + lane * 4);
    ushort4 u2 = *reinterpret_cast<const ushort4*>(xt + (size_t)s2 * HID + lane * 4);
    ushort4 u3 = *reinterpret_cast<const ushort4*>(xt + (size_t)s3 * HID + lane * 4);
    float n0 = di * dis[s0], n1 = di * dis[s1], n2 = di * dis[s2], n3 = di * dis[s3];
    float4 v0 = bf4(u0), v1 = bf4(u1), v2 = bf4(u2), v3 = bf4(u3);
    acc.x = fmaf(v0.x, n0, acc.x); acc.y = fmaf(v0.y, n0, acc.y);
    acc.z = fmaf(v0.z, n0, acc.z); acc.w = fmaf(v0.w, n0, acc.w);
    acc.x = fmaf(v1.x, n1, acc.x); acc.y = fmaf(v1.y, n1, acc.y);
    acc.z = fmaf(v1.z, n1, acc.z); acc.w = fmaf(v1.w, n1, acc.w);
    acc.x = fmaf(v2.x, n2, acc.x); acc.y = fmaf(v2.y, n2, acc.y);
    acc.z = fmaf(v2.z, n2, acc.z); acc.w = fmaf(v2.w, n2, acc.w);
    acc.x = fmaf(v3.x, n3, acc.x); acc.y = fmaf(v3.y, n3, acc.y);
    acc.z = fmaf(v3.z, n3, acc.z); acc.w = fmaf(v3.w, n3, acc.w);
  }
  for (; i < e; i++) {
    int s = col_src[i];
    float nw = di * dis[s];
    float4 xv = bf4(*reinterpret_cast<const ushort4*>(xt + (size_t)s * HID + lane * 4));
    acc.x = fmaf(xv.x, nw, acc.x); acc.y = fmaf(xv.y, nw, acc.y);
    acc.z = fmaf(xv.z, nw, acc.z); acc.w = fmaf(xv.w, nw, acc.w);
  }
  float4 bb = *reinterpret_cast<const float4*>(b_gcn + lane * 4);
  acc.x += bb.x; acc.y += bb.y; acc.z += bb.z; acc.w += bb.w;
  *reinterpret_cast<float4*>(out + (size_t)node * HID + lane * 4) = acc;
}

// ---------------- GAT ----------------
__global__ void k_gat_al(const ushort* __restrict__ xt, const float* __restrict__ a_src,
                         const float* __restrict__ a_dst, float* __restrict__ alsrc,
                         float* __restrict__ aldst) {
  int node = blockIdx.x * 4 + (threadIdx.x >> 6);
  if (node >= N_NODES) return;
  int lane = threadIdx.x & 63;
  float4 v = bf4(*reinterpret_cast<const ushort4*>(xt + (size_t)node * HID + lane * 4));
  float4 as = *reinterpret_cast<const float4*>(a_src + lane * 4);
  float4 ad = *reinterpret_cast<const float4*>(a_dst + lane * 4);
  float ps = v.x * as.x + v.y * as.y + v.z * as.z + v.w * as.w;
  float pd = v.x * ad.x + v.y * ad.y + v.z * ad.z + v.w * ad.w;
  for (int o = 1; o < 8; o <<= 1) { ps += __shfl_xor(ps, o); pd += __shfl_xor(pd, o); }
  if ((lane & 7) == 0) {
    alsrc[node * 8 + (lane >> 3)] = ps;
    aldst[node * 8 + (lane >> 3)] = pd;
  }
}

__device__ __forceinline__ float leaky02(float x) { return x > 0.f ? x : 0.2f * x; }

// Fused: per-node-head online softmax stats (8 lanes per head) + weighted gather.
__global__ void k_gat_agg(const ushort* __restrict__ xt, const float* __restrict__ alsrc,
                          const float* __restrict__ aldst, const int* __restrict__ row_ptr,
                          const int* __restrict__ col_src, const float* __restrict__ b_gat,
                          float* __restrict__ out) {
  int node = blockIdx.x * 4 + (threadIdx.x >> 6);
  if (node >= N_NODES) return;
  int lane = threadIdx.x & 63;
  int hh = lane >> 3;   // head
  int j = lane & 7;     // sub-lane within head group
  float ad = aldst[node * 8 + hh];
  float l0 = leaky02(alsrc[node * 8 + hh] + ad);  // self-loop logit
  int b = row_ptr[node], e = row_ptr[node + 1];

  // --- stats: strided online max/sum per lane, then 8-lane merge ---
  float ml = (j == 0) ? l0 : -1e30f;
  float sl = (j == 0) ? 1.f : 0.f;
  for (int i = b + j; i < e; i += 8) {
    int src = col_src[i];
    float l = leaky02(alsrc[src * 8 + hh] + ad);
    if (l > ml) { sl = sl * __expf(ml - l) + 1.f; ml = l; }
    else sl += __expf(l - ml);
  }
#pragma unroll
  for (int o = 1; o < 8; o <<= 1) {
    float mo = __shfl_xor(ml, o);
    float so = __shfl_xor(sl, o);
    float mn = fmaxf(ml, mo);
    sl = sl * __expf(ml - mn) + so * __expf(mo - mn);
    ml = mn;
  }
  float inv_s = 1.0f / sl;

  // --- weighted aggregation ---
  float a0 = __expf(l0 - ml) * inv_s;
  float4 x = bf4(*reinterpret_cast<const ushort4*>(xt + (size_t)node * HID + lane * 4));
  float4 acc = make_float4(x.x * a0, x.y * a0, x.z * a0, x.w * a0);
  int i = b;
  for (; i + 4 <= e; i += 4) {
    int s0 = col_src[i], s1 = col_src[i + 1], s2 = col_src[i + 2], s3 = col_src[i + 3];
    float g0 = alsrc[s0 * 8 + hh], g1 = alsrc[s1 * 8 + hh];
    float g2 = alsrc[s2 * 8 + hh], g3 = alsrc[s3 * 8 + hh];
    ushort4 u0 = *reinterpret_cast<const ushort4*>(xt + (size_t)s0 * HID + lane * 4);
    ushort4 u1 = *reinterpret_cast<const ushort4*>(xt + (size_t)s1 * HID + lane * 4);
    ushort4 u2 = *reinterpret_cast<const ushort4*>(xt + (size_t)s2 * HID + lane * 4);
    ushort4 u3 = *reinterpret_cast<const ushort4*>(xt + (size_t)s3 * HID + lane * 4);
    float a1 = __expf(leaky02(g0 + ad) - ml) * inv_s;
    float a2 = __expf(leaky02(g1 + ad) - ml) * inv_s;
    float a3 = __expf(leaky02(g2 + ad) - ml) * inv_s;
    float a4 = __expf(leaky02(g3 + ad) - ml) * inv_s;
    float4 v0 = bf4(u0), v1 = bf4(u1), v2 = bf4(u2), v3 = bf4(u3);
    acc.x = fmaf(v0.x, a1, acc.x); acc.y = fmaf(v0.y, a1, acc.y);
    acc.z = fmaf(v0.z, a1, acc.z); acc.w = fmaf(v0.w, a1, acc.w);
    acc.x = fmaf(v1.x, a2, acc.x); acc.y = fmaf(v1.y, a2, acc.y);
    acc.z = fmaf(v1.z, a2, acc.z); acc.w = fmaf(v1.w, a2, acc.w);
    acc.x = fmaf(v2.x, a3, acc.x); acc.y = fmaf(v2.y, a3, acc.y);
    acc.z = fmaf(v2.z, a3, acc.z); acc.w = fmaf(v2.w, a3, acc.w);
    acc.x = fmaf(v3.x, a4, acc.x); acc.y = fmaf(v3.y, a4, acc.y);
    acc.z = fmaf(v3.z, a4, acc.z); acc.w = fmaf(v3.w, a4, acc.w);
  }
  for (; i < e; i++) {
    int src = col_src[i];
    float l = leaky02(alsrc[src * 8 + hh] + ad);
    float al = __expf(l - ml) * inv_s;
    float4 xv = bf4(*reinterpret_cast<const ushort4*>(xt + (size_t)src * HID + lane * 4));
    acc.x = fmaf(xv.x, al, acc.x); acc.y = fmaf(xv.y, al, acc.y);
    acc.z = fmaf(xv.z, al, acc.z); acc.w = fmaf(xv.w, al, acc.w);
  }
  float4 bb = *reinterpret_cast<const float4*>(b_gat + lane * 4);
  acc.x += bb.x; acc.y += bb.y; acc.z += bb.z; acc.w += bb.w;
  *reinterpret_cast<float4*>(out + (size_t)node * HID + lane * 4) = acc;
}

// ---------------- SAGE mean aggregation (bf16 in, bf16 out, 4x unrolled) ----------------
__global__ void k_sage_agg(const ushort* __restrict__ h, const int* __restrict__ row_ptr,
                           const int* __restrict__ col_src, ushort* __restrict__ out) {
  int node = blockIdx.x * 4 + (threadIdx.x >> 6);
  if (node >= N_NODES) return;
  int lane = threadIdx.x & 63;
  int b = row_ptr[node], e = row_ptr[node + 1];
  float inv = 1.0f / fmaxf((float)(e - b), 1.0f);
  float4 acc = make_float4(0.f, 0.f, 0.f, 0.f);
  int i = b;
  for (; i + 4 <= e; i += 4) {
    int s0 = col_src[i], s1 = col_src[i + 1], s2 = col_src[i + 2], s3 = col_src[i + 3];
    ushort4 u0 = *reinterpret_cast<const ushort4*>(h + (size_t)s0 * HID + lane * 4);
    ushort4 u1 = *reinterpret_cast<const ushort4*>(h + (size_t)s1 * HID + lane * 4);
    ushort4 u2 = *reinterpret_cast<const ushort4*>(h + (size_t)s2 * HID + lane * 4);
    ushort4 u3 = *reinterpret_cast<const ushort4*>(h + (size_t)s3 * HID + lane * 4);
    float4 v0 = bf4(u0), v1 = bf4(u1), v2 = bf4(u2), v3 = bf4(u3);
    acc.x += v0.x + v1.x + v2.x + v3.x;
    acc.y += v0.y + v1.y + v2.y + v3.y;
    acc.z += v0.z + v1.z + v2.z + v3.z;
    acc.w += v0.w + v1.w + v2.w + v3.w;
  }
  for (; i < e; i++) {
    int s = col_src[i];
    float4 xv = bf4(*reinterpret_cast<const ushort4*>(h + (size_t)s * HID + lane * 4));
    acc.x += xv.x; acc.y += xv.y; acc.z += xv.z; acc.w += xv.w;
  }
  *reinterpret_cast<ushort4*>(out + (size_t)node * HID + lane * 4) =
      make_ushort4(f2bf(acc.x * inv), f2bf(acc.y * inv), f2bf(acc.z * inv), f2bf(acc.w * inv));
}

// ---------------- BatchNorm ----------------
__global__ void k_bn_stats(const float* __restrict__ x, float* __restrict__ stats) {
  int c = threadIdx.x;
  float s = 0.f, q = 0.f;
  for (int r = blockIdx.x; r < N_NODES; r += gridDim.x) {
    float v = x[(size_t)r * HID + c];
    s += v;
    q = fmaf(v, v, q);
  }
  atomicAdd(&stats[c], s);
  atomicAdd(&stats[HID + c], q);
}

// h += relu(bn(x)); also emit h_bf
__global__ void k_bn_apply(const float* __restrict__ x, const float* __restrict__ stats,
                           const float* __restrict__ gamma, const float* __restrict__ beta,
                           float* __restrict__ h, ushort* __restrict__ h_bf) {
  const float invN = 1.0f / (float)N_NODES;
  int total = N_NODES * 64;
  for (int i = blockIdx.x * 256 + threadIdx.x; i < total; i += gridDim.x * 256) {
    int c4 = (i & 63) * 4;
    float4 xv = *reinterpret_cast<const float4*>(x + (size_t)i * 4);
    float4 sm = *reinterpret_cast<const float4*>(stats + c4);
    float4 sq = *reinterpret_cast<const float4*>(stats + HID + c4);
    float4 gm = *reinterpret_cast<const float4*>(gamma + c4);
    float4 bt = *reinterpret_cast<const float4*>(beta + c4);
    float4 hv = *reinterpret_cast<const float4*>(h + (size_t)i * 4);
#define BN1(f)                                                    \
  {                                                               \
    float mu = sm.f * invN;                                       \
    float var = sq.f * invN - mu * mu;                            \
    float sc = gm.f * rsqrtf(var + EPS);                          \
    float v = (xv.f - mu) * sc + bt.f;                            \
    hv.f += fmaxf(v, 0.f);                                        \
  }
    BN1(x) BN1(y) BN1(z) BN1(w)
#undef BN1
    *reinterpret_cast<float4*>(h + (size_t)i * 4) = hv;
    *reinterpret_cast<ushort4*>(h_bf + (size_t)i * 4) =
        make_ushort4(f2bf(hv.x), f2bf(hv.y), f2bf(hv.z), f2bf(hv.w));
  }
}

// ---------------- gate: dot(relu_hidden, Wg2) + bg2 ----------------
__global__ void k_gate(const float* __restrict__ tg, const float* __restrict__ Wg2,
                       const float* __restrict__ bg2, float* __restrict__ gate) {
  int node = blockIdx.x * 4 + (threadIdx.x >> 6);
  if (node >= N_NODES) return;
  int lane = threadIdx.x & 63;
  float v = tg[(size_t)node * 128 + lane] * Wg2[lane] +
            tg[(size_t)node * 128 + 64 + lane] * Wg2[64 + lane];
  for (int o = 1; o < 64; o <<= 1) v += __shfl_xor(v, o);
  if (lane == 0) gate[node] = v + bg2[0];
}

// ---------------- graph segment starts ----------------
__global__ void k_gstart(const int* __restrict__ batch, int* __restrict__ gstart) {
  int g = blockIdx.x * 256 + threadIdx.x;
  if (g > NG) return;
  int lo = 0, hi = N_NODES;
  while (lo < hi) {
    int mid = (lo + hi) >> 1;
    if (batch[mid] < g) lo = mid + 1; else hi = mid;
  }
  gstart[g] = lo;
}

// ---------------- global attention pooling ----------------
__global__ void k_pool(const float* __restrict__ h, const float* __restrict__ gate,
                       const int* __restrict__ gstart, float* __restrict__ hg) {
  __shared__ float red[256];
  __shared__ float wbuf[256];
  int g = blockIdx.x, tid = threadIdx.x;
  int b = gstart[g], e = gstart[g + 1];
  float m = -1e30f;
  for (int r = b + tid; r < e; r += 256) m = fmaxf(m, gate[r]);
  red[tid] = m;
  __syncthreads();
  for (int o = 128; o > 0; o >>= 1) {
    if (tid < o) red[tid] = fmaxf(red[tid], red[tid + o]);
    __syncthreads();
  }
  m = red[0];
  __syncthreads();
  float s = 0.f;
  for (int r = b + tid; r < e; r += 256) s += __expf(gate[r] - m);
  red[tid] = s;
  __syncthreads();
  for (int o = 128; o > 0; o >>= 1) {
    if (tid < o) red[tid] += red[tid + o];
    __syncthreads();
  }
  float inv = 1.0f / fmaxf(red[0], 1e-16f);
  __syncthreads();
  float acc = 0.f;
  for (int cb = b; cb < e; cb += 256) {
    int r = cb + tid;
    wbuf[tid] = (r < e) ? __expf(gate[r] - m) : 0.f;
    __syncthreads();
    int n = min(256, e - cb);
    for (int j = 0; j < n; j++) acc = fmaf(h[(size_t)(cb + j) * HID + tid], wbuf[j], acc);
    __syncthreads();
  }
  hg[(size_t)g * HID + tid] = acc * inv;
}

// ---------------- MLP head ----------------
__global__ void k_mlp(const float* __restrict__ hg, const float* __restrict__ W1,
                      const float* __restrict__ b1, const float* __restrict__ lng,
                      const float* __restrict__ lnb, const float* __restrict__ W2,
                      const float* __restrict__ b2, float* __restrict__ out) {
  __shared__ float row[HID];
  __shared__ float z[HID];
  __shared__ float red[HID];
  int g = blockIdx.x, tid = threadIdx.x;
  row[tid] = hg[(size_t)g * HID + tid];
  __syncthreads();
  float acc = b1[tid];
  for (int k = 0; k < HID; k++) acc = fmaf(row[k], W1[(size_t)k * HID + tid], acc);
  red[tid] = acc;
  __syncthreads();
  for (int o = 128; o > 0; o >>= 1) {
    if (tid < o) red[tid] += red[tid + o];
    __syncthreads();
  }
  float mu = red[0] * (1.0f / HID);
  __syncthreads();
  red[tid] = acc * acc;
  __syncthreads();
  for (int o = 128; o > 0; o >>= 1) {
    if (tid < o) red[tid] += red[tid + o];
    __syncthreads();
  }
  float var = red[0] * (1.0f / HID) - mu * mu;
  float zz = (acc - mu) * rsqrtf(var + EPS) * lng[tid] + lnb[tid];
  z[tid] = fmaxf(zz, 0.f);
  __syncthreads();
  if (tid < 64) {
    float o = b2[tid];
    for (int k = 0; k < HID; k++) o = fmaf(z[k], W2[(size_t)k * 64 + tid], o);
    out[(size_t)g * 64 + tid] = o;
  }
}

// ---------------- launch ----------------
extern "C" void kernel_launch(void* const* d_in, const int* in_sizes, int n_in,
                              void* d_out, int out_size, void* d_ws, size_t ws_size,
                              hipStream_t stream) {
  const float* x     = (const float*)d_in[0];
  const float* W_emb = (const float*)d_in[1];
  const float* b_emb = (const float*)d_in[2];
  const float* W_gcn = (const float*)d_in[3];
  const float* b_gcn = (const float*)d_in[4];
  const float* W_gat = (const float*)d_in[5];
  const float* a_src = (const float*)d_in[6];
  const float* a_dst = (const float*)d_in[7];
  const float* b_gat = (const float*)d_in[8];
  const float* W_l   = (const float*)d_in[9];
  const float* b_l   = (const float*)d_in[10];
  const float* W_r   = (const float*)d_in[11];
  const float* bn_g  = (const float*)d_in[12];
  const float* bn_b  = (const float*)d_in[13];
  const float* Wg1   = (const float*)d_in[14];
  const float* bg1   = (const float*)d_in[15];
  const float* Wg2   = (const float*)d_in[16];
  const float* bg2   = (const float*)d_in[17];
  const float* Wm1   = (const float*)d_in[18];
  const float* bm1   = (const float*)d_in[19];
  const float* lnmg  = (const float*)d_in[20];
  const float* lnmb  = (const float*)d_in[21];
  const float* Wm2   = (const float*)d_in[22];
  const float* bm2   = (const float*)d_in[23];
  const float* Wv1   = (const float*)d_in[24];
  const float* bv1   = (const float*)d_in[25];
  const float* lnvg  = (const float*)d_in[26];
  const float* lnvb  = (const float*)d_in[27];
  const float* Wv2   = (const float*)d_in[28];
  const float* bv2   = (const float*)d_in[29];
  const int* ei      = (const int*)d_in[30];
  const int* batch   = (const int*)d_in[31];
  float* out = (float*)d_out;

  float* ws = (float*)d_ws;
  float* h     = ws;
  float* t1    = h + (size_t)N_NODES * HID;
  float* alsrc = t1 + (size_t)N_NODES * HID;
  float* aldst = alsrc + N_NODES * 8;
  float* m_nh  = aldst + N_NODES * 8;   // (unused, kept for layout)
  float* s_nh  = m_nh + N_NODES * 8;    // (unused, kept for layout)
  float* dis   = s_nh + N_NODES * 8;
  float* gate  = dis + N_NODES;
  float* hg    = gate + N_NODES;
  float* zbase = hg + NG * HID;        // zeroed region: bnst + row_cnt + fill
  float* bnst  = zbase;                // 3 * 512
  int* row_cnt = (int*)(zbase + 3 * 512);
  int* fill    = row_cnt + N_NODES;
  int* row_ptr = fill + N_NODES;
  int* col_src = row_ptr + N_NODES + 1;
  int* gstart  = col_src + N_EDGES;

  size_t off = (size_t)((char*)(gstart + NG + 1) - (char*)d_ws);
  off = (off + 15) & ~(size_t)15;
  ushort* h_bf   = (ushort*)((char*)d_ws + off);
  ushort* t0_bf  = h_bf + (size_t)N_NODES * HID;
  ushort* x_bf   = t0_bf;  // alias: x_bf consumed before t0_bf first written
  ushort* wemb_t = t0_bf + (size_t)N_NODES * HID;
  ushort* wgcn_t = wemb_t + 128 * 256;
  ushort* wgat_t = wgcn_t + 256 * 256;
  ushort* wr_t   = wgat_t + 256 * 256;
  ushort* wl_t   = wr_t + 256 * 256;
  ushort* wg1_t  = wl_t + 256 * 256;   // 128*256

  size_t zbytes = (size_t)3 * 512 * 4 + 2 * (size_t)N_NODES * 4;
  hipMemsetAsync(zbase, 0, zbytes, stream);

  // CSR by dst
  k_csr_count<<<(N_EDGES + 255) / 256, 256, 0, stream>>>(ei, row_cnt);
  k_scan<<<1, 1024, 0, stream>>>(row_cnt, row_ptr);
  k_csr_fill<<<(N_EDGES + 255) / 256, 256, 0, stream>>>(ei, row_ptr, fill, col_src);
  k_dis<<<(N_NODES + 255) / 256, 256, 0, stream>>>(row_ptr, dis);

  // weight transposes + x conversion
  k_wt<<<128, 256, 0, stream>>>(W_emb, wemb_t, 128, 256);
  k_wt<<<256, 256, 0, stream>>>(W_gcn, wgcn_t, 256, 256);
  k_wt<<<256, 256, 0, stream>>>(W_gat, wgat_t, 256, 256);
  k_wt<<<256, 256, 0, stream>>>(W_r, wr_t, 256, 256);
  k_wt<<<256, 256, 0, stream>>>(W_l, wl_t, 256, 256);
  k_wt<<<128, 256, 0, stream>>>(Wg1, wg1_t, 256, 128);
  k_f2bf<<<(N_NODES * 128 / 4 + 255) / 256, 256, 0, stream>>>(x, x_bf, N_NODES * 128 / 4);

  const int RB = (N_NODES + 127) / 128;  // 391 row-blocks
  const int AB = (N_NODES + 3) / 4;      // 12500 agg blocks

  // embedding: h = x @ W_emb + b_emb  (fp32 trunk + bf16 copy)
  k_mgemm<128, 256, false><<<dim3(4, RB), 256, 0, stream>>>(
      x_bf, wemb_t, nullptr, nullptr, b_emb, h, h_bf, N_NODES, 0);

  // --- GCN ---
  k_mgemm<256, 256, false><<<dim3(4, RB), 256, 0, stream>>>(
      h_bf, wgcn_t, nullptr, nullptr, nullptr, nullptr, t0_bf, N_NODES, 0);
  k_gcn_agg<<<AB, 256, 0, stream>>>(t0_bf, dis, row_ptr, col_src, b_gcn, t1);
  k_bn_stats<<<256, 256, 0, stream>>>(t1, bnst);
  k_bn_apply<<<1024, 256, 0, stream>>>(t1, bnst, bn_g, bn_b, h, h_bf);

  // --- GAT (stats fused into agg) ---
  k_mgemm<256, 256, false><<<dim3(4, RB), 256, 0, stream>>>(
      h_bf, wgat_t, nullptr, nullptr, nullptr, nullptr, t0_bf, N_NODES, 0);
  k_gat_al<<<AB, 256, 0, stream>>>(t0_bf, a_src, a_dst, alsrc, aldst);
  k_gat_agg<<<AB, 256, 0, stream>>>(t0_bf, alsrc, aldst, row_ptr, col_src, b_gat, t1);
  k_bn_stats<<<256, 256, 0, stream>>>(t1, bnst + 512);
  k_bn_apply<<<1024, 256, 0, stream>>>(t1, bnst + 512, bn_g + HID, bn_b + HID, h, h_bf);

  // --- SAGE: t1 = h@W_r + b_l + mean@W_l (dual-pass, LDS re-stage) ---
  k_sage_agg<<<AB, 256, 0, stream>>>(h_bf, row_ptr, col_src, t0_bf);
  k_mgemm<256, 256, true><<<dim3(4, RB), 256, 0, stream>>>(
      h_bf, wr_t, t0_bf, wl_t, b_l, t1, nullptr, N_NODES, 0);
  k_bn_stats<<<256, 256, 0, stream>>>(t1, bnst + 1024);
  k_bn_apply<<<1024, 256, 0, stream>>>(t1, bnst + 1024, bn_g + 2 * HID, bn_b + 2 * HID, h, h_bf);

  // --- gate + pooling ---
  k_mgemm<256, 128, false><<<dim3(2, RB), 256, 0, stream>>>(
      h_bf, wg1_t, nullptr, nullptr, bg1, t1, nullptr, N_NODES, 1);
  k_gate<<<AB, 256, 0, stream>>>(t1, Wg2, bg2, gate);
  k_gstart<<<3, 256, 0, stream>>>(batch, gstart);
  k_pool<<<NG, 256, 0, stream>>>(h, gate, gstart, hg);

  // --- heads ---
  k_mlp<<<NG, 256, 0, stream>>>(hg, Wm1, bm1, lnmg, lnmb, Wm2, bm2, out);
  k_mlp<<<NG, 256, 0, stream>>>(hg, Wv1, bv1, lnvg, lnvb, Wv2, bv2, out + (size_t)NG * 64);
}

// Round 5
// 733.210 us; speedup vs baseline: 1.7727x; 1.0811x over previous
//
#include <hip/hip_runtime.h>
#include <cstdint>
#include <cstddef>

#define N_NODES 50000
#define N_EDGES 500000
#define NG 512
#define HID 256
#define EPS 1e-5f
#define SCB 49  // scan blocks: ceil(50000/1024)

typedef __attribute__((ext_vector_type(8))) __bf16 bf16x8;
typedef __attribute__((ext_vector_type(4))) float f32x4;

__device__ __forceinline__ ushort f2bf(float f) {
  uint32_t u = __float_as_uint(f);
  uint32_t r = (u + 0x7fffu + ((u >> 16) & 1u)) >> 16;
  return (ushort)r;
}
__device__ __forceinline__ float bfu(ushort u) { return __uint_as_float(((uint32_t)u) << 16); }
__device__ __forceinline__ float4 bf4(ushort4 u) {
  return make_float4(bfu(u.x), bfu(u.y), bfu(u.z), bfu(u.w));
}

// ---------------- CSR build ----------------
__global__ void k_csr_count(const int* __restrict__ ei, int* __restrict__ cnt) {
  int e = blockIdx.x * 256 + threadIdx.x;
  if (e < N_EDGES) atomicAdd(&cnt[ei[N_EDGES + e]], 1);
}

// hierarchical scan: 49-block partials -> 1-wave scan -> 49-block scatter (+dis)
__global__ void k_scan_part(const int* __restrict__ cnt, int* __restrict__ psum) {
  __shared__ int red[256];
  int tid = threadIdx.x;
  int i0 = blockIdx.x * 1024 + tid * 4;
  int s = 0;
  if (i0 + 4 <= N_NODES) {
    int4 v = *reinterpret_cast<const int4*>(cnt + i0);
    s = v.x + v.y + v.z + v.w;
  } else {
    for (int k = 0; k < 4; k++)
      if (i0 + k < N_NODES) s += cnt[i0 + k];
  }
  red[tid] = s;
  __syncthreads();
  for (int o = 128; o > 0; o >>= 1) {
    if (tid < o) red[tid] += red[tid + o];
    __syncthreads();
  }
  if (tid == 0) psum[blockIdx.x] = red[0];
}

__global__ void k_scan_top(const int* __restrict__ psum, int* __restrict__ boff,
                           int* __restrict__ row_ptr) {
  int t = threadIdx.x;  // 64
  int v = (t < SCB) ? psum[t] : 0;
  int own = v;
  for (int o = 1; o < 64; o <<= 1) {
    int u = __shfl_up(v, o);
    if (t >= o) v += u;
  }
  if (t < SCB) boff[t] = v - own;
  if (t == 63) row_ptr[N_NODES] = v;
}

__global__ void k_scan_out(const int* __restrict__ cnt, const int* __restrict__ boff,
                           int* __restrict__ row_ptr, float* __restrict__ dis) {
  __shared__ int ps[256];
  int tid = threadIdx.x;
  int i0 = blockIdx.x * 1024 + tid * 4;
  int v[4];
#pragma unroll
  for (int k = 0; k < 4; k++) v[k] = (i0 + k < N_NODES) ? cnt[i0 + k] : 0;
  int s = v[0] + v[1] + v[2] + v[3];
  ps[tid] = s;
  __syncthreads();
  for (int o = 1; o < 256; o <<= 1) {
    int add = (tid >= o) ? ps[tid - o] : 0;
    __syncthreads();
    ps[tid] += add;
    __syncthreads();
  }
  int run = boff[blockIdx.x] + ((tid > 0) ? ps[tid - 1] : 0);
#pragma unroll
  for (int k = 0; k < 4; k++) {
    if (i0 + k < N_NODES) {
      row_ptr[i0 + k] = run;
      dis[i0 + k] = rsqrtf((float)v[k] + 1.0f);
      run += v[k];
    }
  }
}

__global__ void k_csr_fill(const int* __restrict__ ei, const int* __restrict__ row_ptr,
                           int* __restrict__ fill, int* __restrict__ col_src) {
  int e = blockIdx.x * 256 + threadIdx.x;
  if (e >= N_EDGES) return;
  int s = ei[e], d = ei[N_EDGES + e];
  int pos = row_ptr[d] + atomicAdd(&fill[d], 1);
  col_src[pos] = s;
}

// ---------------- conversions ----------------
__global__ void k_f2bf(const float* __restrict__ in, ushort* __restrict__ o, int n4) {
  int i = blockIdx.x * 256 + threadIdx.x;
  if (i >= n4) return;
  float4 v = reinterpret_cast<const float4*>(in)[i];
  reinterpret_cast<ushort4*>(o)[i] = make_ushort4(f2bf(v.x), f2bf(v.y), f2bf(v.z), f2bf(v.w));
}

// W [K,C] fp32 -> Wt [C,K] bf16
__global__ void k_wt(const float* __restrict__ W, ushort* __restrict__ Wt, int K, int C) {
  int i = blockIdx.x * 256 + threadIdx.x;
  if (i >= K * C) return;
  int c = i / K, k = i - c * K;
  Wt[i] = f2bf(W[k * C + c]);
}

// ---------------- MFMA GEMM, tiled, multi-panel A-reuse ----------------
// out[M,C] = A1@W1t^T (+A2@W2t^T) + bias. A row-major bf16 [M,K]; Wt [C,K] bf16.
// Grid: (C/64/CPAN, ceil(M/128)). Block: 4 waves; wave owns 32 rows x 64 cols,
// looping CPAN col-panels with A fragments held in registers (non-DUAL).
template <int K, int C, int CPAN, bool DUAL>
__global__ __launch_bounds__(256) void k_mgemm(
    const ushort* __restrict__ A1, const ushort* __restrict__ W1t,
    const ushort* __restrict__ A2, const ushort* __restrict__ W2t,
    const float* __restrict__ bias, float* __restrict__ out,
    ushort* __restrict__ out_bf, int M, int relu) {
  constexpr int KS = K / 32;   // MFMA k-steps
  constexpr int CHK = K / 8;   // 16B chunks per panel row
  constexpr int NP = DUAL ? 2 : 1;
  __shared__ ushort wlds[64 * K];
  const int tid = threadIdx.x;
  const int lane = tid & 63;
  const int wid = tid >> 6;
  const int r16 = lane & 15;
  const int kg = lane >> 4;
  const int rbase = blockIdx.y * 128 + wid * 32;

  int arow[2];
#pragma unroll
  for (int rt = 0; rt < 2; rt++) {
    arow[rt] = rbase + rt * 16 + r16;
    if (arow[rt] >= M) arow[rt] = M - 1;
  }

  // non-DUAL: preload A frags once, reuse across panels
  bf16x8 af[2][KS];
  if constexpr (!DUAL) {
#pragma unroll
    for (int rt = 0; rt < 2; rt++) {
      const ushort* ap = A1 + (size_t)arow[rt] * K + kg * 8;
#pragma unroll
      for (int ks = 0; ks < KS; ks++)
        af[rt][ks] = *reinterpret_cast<const bf16x8*>(ap + ks * 32);
    }
  }

#pragma unroll
  for (int cp = 0; cp < CPAN; cp++) {
    const int c0 = (blockIdx.x * CPAN + cp) * 64;
    f32x4 acc[2][4];
#pragma unroll
    for (int rt = 0; rt < 2; rt++)
#pragma unroll
      for (int c = 0; c < 4; c++) acc[rt][c] = (f32x4){0.f, 0.f, 0.f, 0.f};

#pragma unroll
    for (int p = 0; p < NP; p++) {
      const ushort* __restrict__ Wt = p ? W2t : W1t;
      if (cp || p) __syncthreads();  // drain reads of previous panel
      // stage 64 x K panel, chunk-swizzled: slot = c*CHK + (k16 ^ (c&7))
#pragma unroll
      for (int jj = 0; jj < (64 * CHK) / 256; jj++) {
        int ci = jj * 256 + tid;
        int c = ci / CHK, k16 = ci % CHK;
        int slot = c * CHK + (k16 ^ (c & 7));
        *reinterpret_cast<float4*>(&wlds[slot * 8]) =
            *reinterpret_cast<const float4*>(&Wt[(size_t)(c0 + c) * K + k16 * 8]);
      }
      __syncthreads();
      if constexpr (DUAL) {
        const ushort* __restrict__ A = p ? A2 : A1;
#pragma unroll
        for (int rt = 0; rt < 2; rt++) {
          const ushort* ap = A + (size_t)arow[rt] * K + kg * 8;
#pragma unroll
          for (int ks = 0; ks < KS; ks++)
            af[rt][ks] = *reinterpret_cast<const bf16x8*>(ap + ks * 32);
        }
      }
#pragma unroll
      for (int c = 0; c < 4; c++) {
        bf16x8 wf[KS];
        int colr = c * 16 + r16;
#pragma unroll
        for (int ks = 0; ks < KS; ks++) {
          int slot = colr * CHK + ((ks * 4 + kg) ^ (r16 & 7));
          wf[ks] = *reinterpret_cast<const bf16x8*>(&wlds[slot * 8]);
        }
#pragma unroll
        for (int ks = 0; ks < KS; ks++) {
          acc[0][c] = __builtin_amdgcn_mfma_f32_16x16x32_bf16(af[0][ks], wf[ks], acc[0][c], 0, 0, 0);
          acc[1][c] = __builtin_amdgcn_mfma_f32_16x16x32_bf16(af[1][ks], wf[ks], acc[1][c], 0, 0, 0);
        }
      }
    }

#pragma unroll
    for (int rt = 0; rt < 2; rt++) {
#pragma unroll
      for (int c = 0; c < 4; c++) {
        int col = c0 + c * 16 + r16;
        float bv = bias ? bias[col] : 0.f;
#pragma unroll
        for (int i = 0; i < 4; i++) {
          int row = rbase + rt * 16 + kg * 4 + i;
          if (row < M) {
            float v = acc[rt][c][i] + bv;
            if (relu) v = fmaxf(v, 0.f);
            if (out) out[(size_t)row * C + col] = v;
            if (out_bf) out_bf[(size_t)row * C + col] = f2bf(v);
          }
        }
      }
    }
  }
}

// ---------------- GCN aggregation (wave per node, 4x unrolled gathers) ----------------
__global__ void k_gcn_agg(const ushort* __restrict__ xt, const float* __restrict__ dis,
                          const int* __restrict__ row_ptr, const int* __restrict__ col_src,
                          const float* __restrict__ b_gcn, float* __restrict__ out) {
  int node = blockIdx.x * 4 + (threadIdx.x >> 6);
  if (node >= N_NODES) return;
  int lane = threadIdx.x & 63;
  float di = dis[node];
  float4 x = bf4(*reinterpret_cast<const ushort4*>(xt + (size_t)node * HID + lane * 4));
  float w0 = di * di;
  float4 acc = make_float4(x.x * w0, x.y * w0, x.z * w0, x.w * w0);
  int b = row_ptr[node], e = row_ptr[node + 1];
  int i = b;
  for (; i + 4 <= e; i += 4) {
    int s0 = col_src[i], s1 = col_src[i + 1], s2 = col_src[i + 2], s3 = col_src[i + 3];
    ushort4 u0 = *reinterpret_cast<const ushort4*>(xt + (size_t)s0 * HID + lane * 4);
    ushort4 u1 = *reinterpret_cast<const ushort4*>(xt + (size_t)s1 * HID + lane * 4);
    ushort4 u2 = *reinterpret_cast<const ushort4*>(xt + (size_t)s2 * HID + lane * 4);
    ushort4 u3 = *reinterpret_cast<const ushort4*>(xt + (size_t)s3 * HID + lane * 4);
    float n0 = di * dis[s0], n1 = di * dis[s1], n2 = di * dis[s2], n3 = di * dis[s3];
    float4 v0 = bf4(u0), v1 = bf4(u1), v2 = bf4(u2), v3 = bf4(u3);
    acc.x = fmaf(v0.x, n0, acc.x); acc.y = fmaf(v0.y, n0, acc.y);
    acc.z = fmaf(v0.z, n0, acc.z); acc.w = fmaf(v0.w, n0, acc.w);
    acc.x = fmaf(v1.x, n1, acc.x); acc.y = fmaf(v1.y, n1, acc.y);
    acc.z = fmaf(v1.z, n1, acc.z); acc.w = fmaf(v1.w, n1, acc.w);
    acc.x = fmaf(v2.x, n2, acc.x); acc.y = fmaf(v2.y, n2, acc.y);
    acc.z = fmaf(v2.z, n2, acc.z); acc.w = fmaf(v2.w, n2, acc.w);
    acc.x = fmaf(v3.x, n3, acc.x); acc.y = fmaf(v3.y, n3, acc.y);
    acc.z = fmaf(v3.z, n3, acc.z); acc.w = fmaf(v3.w, n3, acc.w);
  }
  for (; i < e; i++) {
    int s = col_src[i];
    float nw = di * dis[s];
    float4 xv = bf4(*reinterpret_cast<const ushort4*>(xt + (size_t)s * HID + lane * 4));
    acc.x = fmaf(xv.x, nw, acc.x); acc.y = fmaf(xv.y, nw, acc.y);
    acc.z = fmaf(xv.z, nw, acc.z); acc.w = fmaf(xv.w, nw, acc.w);
  }
  float4 bb = *reinterpret_cast<const float4*>(b_gcn + lane * 4);
  acc.x += bb.x; acc.y += bb.y; acc.z += bb.z; acc.w += bb.w;
  *reinterpret_cast<float4*>(out + (size_t)node * HID + lane * 4) = acc;
}

// ---------------- GAT ----------------
__global__ void k_gat_al(const ushort* __restrict__ xt, const float* __restrict__ a_src,
                         const float* __restrict__ a_dst, float* __restrict__ alsrc,
                         float* __restrict__ aldst) {
  int node = blockIdx.x * 4 + (threadIdx.x >> 6);
  if (node >= N_NODES) return;
  int lane = threadIdx.x & 63;
  float4 v = bf4(*reinterpret_cast<const ushort4*>(xt + (size_t)node * HID + lane * 4));
  float4 as = *reinterpret_cast<const float4*>(a_src + lane * 4);
  float4 ad = *reinterpret_cast<const float4*>(a_dst + lane * 4);
  float ps = v.x * as.x + v.y * as.y + v.z * as.z + v.w * as.w;
  float pd = v.x * ad.x + v.y * ad.y + v.z * ad.z + v.w * ad.w;
  for (int o = 1; o < 8; o <<= 1) { ps += __shfl_xor(ps, o); pd += __shfl_xor(pd, o); }
  if ((lane & 7) == 0) {
    alsrc[node * 8 + (lane >> 3)] = ps;
    aldst[node * 8 + (lane >> 3)] = pd;
  }
}

__device__ __forceinline__ float leaky02(float x) { return x > 0.f ? x : 0.2f * x; }

// Single-pass GAT: exp without max-shift (logits O(1)); denominator accumulated
// in the same loop (all 8 lanes of a head group compute identical alpha).
__global__ void k_gat_agg(const ushort* __restrict__ xt, const float* __restrict__ alsrc,
                          const float* __restrict__ aldst, const int* __restrict__ row_ptr,
                          const int* __restrict__ col_src, const float* __restrict__ b_gat,
                          float* __restrict__ out) {
  int node = blockIdx.x * 4 + (threadIdx.x >> 6);
  if (node >= N_NODES) return;
  int lane = threadIdx.x & 63;
  int hh = lane >> 3;
  float ad = aldst[node * 8 + hh];
  float e0 = __expf(leaky02(alsrc[node * 8 + hh] + ad));  // self-loop
  float4 x = bf4(*reinterpret_cast<const ushort4*>(xt + (size_t)node * HID + lane * 4));
  float4 acc = make_float4(x.x * e0, x.y * e0, x.z * e0, x.w * e0);
  float s = e0;
  int b = row_ptr[node], e = row_ptr[node + 1];
  int i = b;
  for (; i + 4 <= e; i += 4) {
    int s0 = col_src[i], s1 = col_src[i + 1], s2 = col_src[i + 2], s3 = col_src[i + 3];
    float g0 = alsrc[s0 * 8 + hh], g1 = alsrc[s1 * 8 + hh];
    float g2 = alsrc[s2 * 8 + hh], g3 = alsrc[s3 * 8 + hh];
    ushort4 u0 = *reinterpret_cast<const ushort4*>(xt + (size_t)s0 * HID + lane * 4);
    ushort4 u1 = *reinterpret_cast<const ushort4*>(xt + (size_t)s1 * HID + lane * 4);
    ushort4 u2 = *reinterpret_cast<const ushort4*>(xt + (size_t)s2 * HID + lane * 4);
    ushort4 u3 = *reinterpret_cast<const ushort4*>(xt + (size_t)s3 * HID + lane * 4);
    float a1 = __expf(leaky02(g0 + ad));
    float a2 = __expf(leaky02(g1 + ad));
    float a3 = __expf(leaky02(g2 + ad));
    float a4 = __expf(leaky02(g3 + ad));
    s += a1 + a2 + a3 + a4;
    float4 v0 = bf4(u0), v1 = bf4(u1), v2 = bf4(u2), v3 = bf4(u3);
    acc.x = fmaf(v0.x, a1, acc.x); acc.y = fmaf(v0.y, a1, acc.y);
    acc.z = fmaf(v0.z, a1, acc.z); acc.w = fmaf(v0.w, a1, acc.w);
    acc.x = fmaf(v1.x, a2, acc.x); acc.y = fmaf(v1.y, a2, acc.y);
    acc.z = fmaf(v1.z, a2, acc.z); acc.w = fmaf(v1.w, a2, acc.w);
    acc.x = fmaf(v2.x, a3, acc.x); acc.y = fmaf(v2.y, a3, acc.y);
    acc.z = fmaf(v2.z, a3, acc.z); acc.w = fmaf(v2.w, a3, acc.w);
    acc.x = fmaf(v3.x, a4, acc.x); acc.y = fmaf(v3.y, a4, acc.y);
    acc.z = fmaf(v3.z, a4, acc.z); acc.w = fmaf(v3.w, a4, acc.w);
  }
  for (; i < e; i++) {
    int src = col_src[i];
    float al = __expf(leaky02(alsrc[src * 8 + hh] + ad));
    s += al;
    float4 xv = bf4(*reinterpret_cast<const ushort4*>(xt + (size_t)src * HID + lane * 4));
    acc.x = fmaf(xv.x, al, acc.x); acc.y = fmaf(xv.y, al, acc.y);
    acc.z = fmaf(xv.z, al, acc.z); acc.w = fmaf(xv.w, al, acc.w);
  }
  float inv_s = 1.0f / s;
  float4 bb = *reinterpret_cast<const float4*>(b_gat + lane * 4);
  acc.x = fmaf(acc.x, inv_s, bb.x);
  acc.y = fmaf(acc.y, inv_s, bb.y);
  acc.z = fmaf(acc.z, inv_s, bb.z);
  acc.w = fmaf(acc.w, inv_s, bb.w);
  *reinterpret_cast<float4*>(out + (size_t)node * HID + lane * 4) = acc;
}

// ---------------- SAGE mean aggregation (bf16 in, bf16 out, 4x unrolled) ----------------
__global__ void k_sage_agg(const ushort* __restrict__ h, const int* __restrict__ row_ptr,
                           const int* __restrict__ col_src, ushort* __restrict__ out) {
  int node = blockIdx.x * 4 + (threadIdx.x >> 6);
  if (node >= N_NODES) return;
  int lane = threadIdx.x & 63;
  int b = row_ptr[node], e = row_ptr[node + 1];
  float inv = 1.0f / fmaxf((float)(e - b), 1.0f);
  float4 acc = make_float4(0.f, 0.f, 0.f, 0.f);
  int i = b;
  for (; i + 4 <= e; i += 4) {
    int s0 = col_src[i], s1 = col_src[i + 1], s2 = col_src[i + 2], s3 = col_src[i + 3];
    ushort4 u0 = *reinterpret_cast<const ushort4*>(h + (size_t)s0 * HID + lane * 4);
    ushort4 u1 = *reinterpret_cast<const ushort4*>(h + (size_t)s1 * HID + lane * 4);
    ushort4 u2 = *reinterpret_cast<const ushort4*>(h + (size_t)s2 * HID + lane * 4);
    ushort4 u3 = *reinterpret_cast<const ushort4*>(h + (size_t)s3 * HID + lane * 4);
    float4 v0 = bf4(u0), v1 = bf4(u1), v2 = bf4(u2), v3 = bf4(u3);
    acc.x += v0.x + v1.x + v2.x + v3.x;
    acc.y += v0.y + v1.y + v2.y + v3.y;
    acc.z += v0.z + v1.z + v2.z + v3.z;
    acc.w += v0.w + v1.w + v2.w + v3.w;
  }
  for (; i < e; i++) {
    int s = col_src[i];
    float4 xv = bf4(*reinterpret_cast<const ushort4*>(h + (size_t)s * HID + lane * 4));
    acc.x += xv.x; acc.y += xv.y; acc.z += xv.z; acc.w += xv.w;
  }
  *reinterpret_cast<ushort4*>(out + (size_t)node * HID + lane * 4) =
      make_ushort4(f2bf(acc.x * inv), f2bf(acc.y * inv), f2bf(acc.z * inv), f2bf(acc.w * inv));
}

// ---------------- BatchNorm ----------------
__global__ void k_bn_stats(const float* __restrict__ x, float* __restrict__ stats) {
  int c = threadIdx.x;
  float s = 0.f, q = 0.f;
  for (int r = blockIdx.x; r < N_NODES; r += gridDim.x) {
    float v = x[(size_t)r * HID + c];
    s += v;
    q = fmaf(v, v, q);
  }
  atomicAdd(&stats[c], s);
  atomicAdd(&stats[HID + c], q);
}

// h += relu(bn(x)); also emit h_bf
__global__ void k_bn_apply(const float* __restrict__ x, const float* __restrict__ stats,
                           const float* __restrict__ gamma, const float* __restrict__ beta,
                           float* __restrict__ h, ushort* __restrict__ h_bf) {
  const float invN = 1.0f / (float)N_NODES;
  int total = N_NODES * 64;
  for (int i = blockIdx.x * 256 + threadIdx.x; i < total; i += gridDim.x * 256) {
    int c4 = (i & 63) * 4;
    float4 xv = *reinterpret_cast<const float4*>(x + (size_t)i * 4);
    float4 sm = *reinterpret_cast<const float4*>(stats + c4);
    float4 sq = *reinterpret_cast<const float4*>(stats + HID + c4);
    float4 gm = *reinterpret_cast<const float4*>(gamma + c4);
    float4 bt = *reinterpret_cast<const float4*>(beta + c4);
    float4 hv = *reinterpret_cast<const float4*>(h + (size_t)i * 4);
#define BN1(f)                                                    \
  {                                                               \
    float mu = sm.f * invN;                                       \
    float var = sq.f * invN - mu * mu;                            \
    float sc = gm.f * rsqrtf(var + EPS);                          \
    float v = (xv.f - mu) * sc + bt.f;                            \
    hv.f += fmaxf(v, 0.f);                                        \
  }
    BN1(x) BN1(y) BN1(z) BN1(w)
#undef BN1
    *reinterpret_cast<float4*>(h + (size_t)i * 4) = hv;
    *reinterpret_cast<ushort4*>(h_bf + (size_t)i * 4) =
        make_ushort4(f2bf(hv.x), f2bf(hv.y), f2bf(hv.z), f2bf(hv.w));
  }
}

// ---------------- gate: dot(relu_hidden, Wg2) + bg2 ----------------
__global__ void k_gate(const float* __restrict__ tg, const float* __restrict__ Wg2,
                       const float* __restrict__ bg2, float* __restrict__ gate) {
  int node = blockIdx.x * 4 + (threadIdx.x >> 6);
  if (node >= N_NODES) return;
  int lane = threadIdx.x & 63;
  float v = tg[(size_t)node * 128 + lane] * Wg2[lane] +
            tg[(size_t)node * 128 + 64 + lane] * Wg2[64 + lane];
  for (int o = 1; o < 64; o <<= 1) v += __shfl_xor(v, o);
  if (lane == 0) gate[node] = v + bg2[0];
}

// ---------------- graph segment starts ----------------
__global__ void k_gstart(const int* __restrict__ batch, int* __restrict__ gstart) {
  int g = blockIdx.x * 256 + threadIdx.x;
  if (g > NG) return;
  int lo = 0, hi = N_NODES;
  while (lo < hi) {
    int mid = (lo + hi) >> 1;
    if (batch[mid] < g) lo = mid + 1; else hi = mid;
  }
  gstart[g] = lo;
}

// ---------------- global attention pooling ----------------
__global__ void k_pool(const float* __restrict__ h, const float* __restrict__ gate,
                       const int* __restrict__ gstart, float* __restrict__ hg) {
  __shared__ float red[256];
  __shared__ float wbuf[256];
  int g = blockIdx.x, tid = threadIdx.x;
  int b = gstart[g], e = gstart[g + 1];
  float m = -1e30f;
  for (int r = b + tid; r < e; r += 256) m = fmaxf(m, gate[r]);
  red[tid] = m;
  __syncthreads();
  for (int o = 128; o > 0; o >>= 1) {
    if (tid < o) red[tid] = fmaxf(red[tid], red[tid + o]);
    __syncthreads();
  }
  m = red[0];
  __syncthreads();
  float s = 0.f;
  for (int r = b + tid; r < e; r += 256) s += __expf(gate[r] - m);
  red[tid] = s;
  __syncthreads();
  for (int o = 128; o > 0; o >>= 1) {
    if (tid < o) red[tid] += red[tid + o];
    __syncthreads();
  }
  float inv = 1.0f / fmaxf(red[0], 1e-16f);
  __syncthreads();
  float acc = 0.f;
  for (int cb = b; cb < e; cb += 256) {
    int r = cb + tid;
    wbuf[tid] = (r < e) ? __expf(gate[r] - m) : 0.f;
    __syncthreads();
    int n = min(256, e - cb);
    for (int j = 0; j < n; j++) acc = fmaf(h[(size_t)(cb + j) * HID + tid], wbuf[j], acc);
    __syncthreads();
  }
  hg[(size_t)g * HID + tid] = acc * inv;
}

// ---------------- MLP head ----------------
__global__ void k_mlp(const float* __restrict__ hg, const float* __restrict__ W1,
                      const float* __restrict__ b1, const float* __restrict__ lng,
                      const float* __restrict__ lnb, const float* __restrict__ W2,
                      const float* __restrict__ b2, float* __restrict__ out) {
  __shared__ float row[HID];
  __shared__ float z[HID];
  __shared__ float red[HID];
  int g = blockIdx.x, tid = threadIdx.x;
  row[tid] = hg[(size_t)g * HID + tid];
  __syncthreads();
  float acc = b1[tid];
  for (int k = 0; k < HID; k++) acc = fmaf(row[k], W1[(size_t)k * HID + tid], acc);
  red[tid] = acc;
  __syncthreads();
  for (int o = 128; o > 0; o >>= 1) {
    if (tid < o) red[tid] += red[tid + o];
    __syncthreads();
  }
  float mu = red[0] * (1.0f / HID);
  __syncthreads();
  red[tid] = acc * acc;
  __syncthreads();
  for (int o = 128; o > 0; o >>= 1) {
    if (tid < o) red[tid] += red[tid + o];
    __syncthreads();
  }
  float var = red[0] * (1.0f / HID) - mu * mu;
  float zz = (acc - mu) * rsqrtf(var + EPS) * lng[tid] + lnb[tid];
  z[tid] = fmaxf(zz, 0.f);
  __syncthreads();
  if (tid < 64) {
    float o = b2[tid];
    for (int k = 0; k < HID; k++) o = fmaf(z[k], W2[(size_t)k * 64 + tid], o);
    out[(size_t)g * 64 + tid] = o;
  }
}

// ---------------- launch ----------------
extern "C" void kernel_launch(void* const* d_in, const int* in_sizes, int n_in,
                              void* d_out, int out_size, void* d_ws, size_t ws_size,
                              hipStream_t stream) {
  const float* x     = (const float*)d_in[0];
  const float* W_emb = (const float*)d_in[1];
  const float* b_emb = (const float*)d_in[2];
  const float* W_gcn = (const float*)d_in[3];
  const float* b_gcn = (const float*)d_in[4];
  const float* W_gat = (const float*)d_in[5];
  const float* a_src = (const float*)d_in[6];
  const float* a_dst = (const float*)d_in[7];
  const float* b_gat = (const float*)d_in[8];
  const float* W_l   = (const float*)d_in[9];
  const float* b_l   = (const float*)d_in[10];
  const float* W_r   = (const float*)d_in[11];
  const float* bn_g  = (const float*)d_in[12];
  const float* bn_b  = (const float*)d_in[13];
  const float* Wg1   = (const float*)d_in[14];
  const float* bg1   = (const float*)d_in[15];
  const float* Wg2   = (const float*)d_in[16];
  const float* bg2   = (const float*)d_in[17];
  const float* Wm1   = (const float*)d_in[18];
  const float* bm1   = (const float*)d_in[19];
  const float* lnmg  = (const float*)d_in[20];
  const float* lnmb  = (const float*)d_in[21];
  const float* Wm2   = (const float*)d_in[22];
  const float* bm2   = (const float*)d_in[23];
  const float* Wv1   = (const float*)d_in[24];
  const float* bv1   = (const float*)d_in[25];
  const float* lnvg  = (const float*)d_in[26];
  const float* lnvb  = (const float*)d_in[27];
  const float* Wv2   = (const float*)d_in[28];
  const float* bv2   = (const float*)d_in[29];
  const int* ei      = (const int*)d_in[30];
  const int* batch   = (const int*)d_in[31];
  float* out = (float*)d_out;

  float* ws = (float*)d_ws;
  float* h     = ws;
  float* t1    = h + (size_t)N_NODES * HID;
  float* alsrc = t1 + (size_t)N_NODES * HID;
  float* aldst = alsrc + N_NODES * 8;
  float* dis   = aldst + N_NODES * 8;
  float* gate  = dis + N_NODES;
  float* hg    = gate + N_NODES;
  float* zbase = hg + NG * HID;        // zeroed region: bnst + row_cnt + fill
  float* bnst  = zbase;                // 3 * 512
  int* row_cnt = (int*)(zbase + 3 * 512);
  int* fill    = row_cnt + N_NODES;
  int* row_ptr = fill + N_NODES;
  int* col_src = row_ptr + N_NODES + 1;
  int* gstart  = col_src + N_EDGES;
  int* psum    = gstart + NG + 1;      // SCB partials
  int* boff    = psum + 64;            // SCB offsets

  size_t off = (size_t)((char*)(boff + 64) - (char*)d_ws);
  off = (off + 15) & ~(size_t)15;
  ushort* h_bf   = (ushort*)((char*)d_ws + off);
  ushort* t0_bf  = h_bf + (size_t)N_NODES * HID;
  ushort* x_bf   = t0_bf;  // alias: x_bf consumed before t0_bf first written
  ushort* wemb_t = t0_bf + (size_t)N_NODES * HID;
  ushort* wgcn_t = wemb_t + 128 * 256;
  ushort* wgat_t = wgcn_t + 256 * 256;
  ushort* wr_t   = wgat_t + 256 * 256;
  ushort* wl_t   = wr_t + 256 * 256;
  ushort* wg1_t  = wl_t + 256 * 256;   // 128*256

  size_t zbytes = (size_t)3 * 512 * 4 + 2 * (size_t)N_NODES * 4;
  hipMemsetAsync(zbase, 0, zbytes, stream);

  // CSR by dst (hierarchical scan + fused dis)
  k_csr_count<<<(N_EDGES + 255) / 256, 256, 0, stream>>>(ei, row_cnt);
  k_scan_part<<<SCB, 256, 0, stream>>>(row_cnt, psum);
  k_scan_top<<<1, 64, 0, stream>>>(psum, boff, row_ptr);
  k_scan_out<<<SCB, 256, 0, stream>>>(row_cnt, boff, row_ptr, dis);
  k_csr_fill<<<(N_EDGES + 255) / 256, 256, 0, stream>>>(ei, row_ptr, fill, col_src);

  // weight transposes + x conversion
  k_wt<<<128, 256, 0, stream>>>(W_emb, wemb_t, 128, 256);
  k_wt<<<256, 256, 0, stream>>>(W_gcn, wgcn_t, 256, 256);
  k_wt<<<256, 256, 0, stream>>>(W_gat, wgat_t, 256, 256);
  k_wt<<<256, 256, 0, stream>>>(W_r, wr_t, 256, 256);
  k_wt<<<256, 256, 0, stream>>>(W_l, wl_t, 256, 256);
  k_wt<<<128, 256, 0, stream>>>(Wg1, wg1_t, 256, 128);
  k_f2bf<<<(N_NODES * 128 / 4 + 255) / 256, 256, 0, stream>>>(x, x_bf, N_NODES * 128 / 4);

  const int RB = (N_NODES + 127) / 128;  // 391 row-blocks
  const int AB = (N_NODES + 3) / 4;      // 12500 agg blocks

  // embedding: h = x @ W_emb + b_emb  (fp32 trunk + bf16 copy)
  k_mgemm<128, 256, 2, false><<<dim3(2, RB), 256, 0, stream>>>(
      x_bf, wemb_t, nullptr, nullptr, b_emb, h, h_bf, N_NODES, 0);

  // --- GCN ---
  k_mgemm<256, 256, 2, false><<<dim3(2, RB), 256, 0, stream>>>(
      h_bf, wgcn_t, nullptr, nullptr, nullptr, nullptr, t0_bf, N_NODES, 0);
  k_gcn_agg<<<AB, 256, 0, stream>>>(t0_bf, dis, row_ptr, col_src, b_gcn, t1);
  k_bn_stats<<<256, 256, 0, stream>>>(t1, bnst);
  k_bn_apply<<<1024, 256, 0, stream>>>(t1, bnst, bn_g, bn_b, h, h_bf);

  // --- GAT (single-pass softmax fused into agg) ---
  k_mgemm<256, 256, 2, false><<<dim3(2, RB), 256, 0, stream>>>(
      h_bf, wgat_t, nullptr, nullptr, nullptr, nullptr, t0_bf, N_NODES, 0);
  k_gat_al<<<AB, 256, 0, stream>>>(t0_bf, a_src, a_dst, alsrc, aldst);
  k_gat_agg<<<AB, 256, 0, stream>>>(t0_bf, alsrc, aldst, row_ptr, col_src, b_gat, t1);
  k_bn_stats<<<256, 256, 0, stream>>>(t1, bnst + 512);
  k_bn_apply<<<1024, 256, 0, stream>>>(t1, bnst + 512, bn_g + HID, bn_b + HID, h, h_bf);

  // --- SAGE: t1 = h@W_r + b_l + mean@W_l (dual-pass, LDS re-stage) ---
  k_sage_agg<<<AB, 256, 0, stream>>>(h_bf, row_ptr, col_src, t0_bf);
  k_mgemm<256, 256, 2, true><<<dim3(2, RB), 256, 0, stream>>>(
      h_bf, wr_t, t0_bf, wl_t, b_l, t1, nullptr, N_NODES, 0);
  k_bn_stats<<<256, 256, 0, stream>>>(t1, bnst + 1024);
  k_bn_apply<<<1024, 256, 0, stream>>>(t1, bnst + 1024, bn_g + 2 * HID, bn_b + 2 * HID, h, h_bf);

  // --- gate + pooling ---
  k_mgemm<256, 128, 2, false><<<dim3(1, RB), 256, 0, stream>>>(
      h_bf, wg1_t, nullptr, nullptr, bg1, t1, nullptr, N_NODES, 1);
  k_gate<<<AB, 256, 0, stream>>>(t1, Wg2, bg2, gate);
  k_gstart<<<3, 256, 0, stream>>>(batch, gstart);
  k_pool<<<NG, 256, 0, stream>>>(h, gate, gstart, hg);

  // --- heads ---
  k_mlp<<<NG, 256, 0, stream>>>(hg, Wm1, bm1, lnmg, lnmb, Wm2, bm2, out);
  k_mlp<<<NG, 256, 0, stream>>>(hg, Wv1, bv1, lnvg, lnvb, Wv2, bv2, out + (size_t)NG * 64);
}

// Round 6
// 672.409 us; speedup vs baseline: 1.9329x; 1.0904x over previous
//
#include <hip/hip_runtime.h>
#include <cstdint>
#include <cstddef>

#define N_NODES 50000
#define N_EDGES 500000
#define NG 512
#define HID 256
#define EPS 1e-5f
#define SCB 49  // scan blocks: ceil(50000/1024)

typedef __attribute__((ext_vector_type(8))) __bf16 bf16x8;
typedef __attribute__((ext_vector_type(8))) ushort u16x8;
typedef __attribute__((ext_vector_type(4))) float f32x4;

__device__ __forceinline__ ushort f2bf(float f) {
  uint32_t u = __float_as_uint(f);
  uint32_t r = (u + 0x7fffu + ((u >> 16) & 1u)) >> 16;
  return (ushort)r;
}
__device__ __forceinline__ float bfu(ushort u) { return __uint_as_float(((uint32_t)u) << 16); }
__device__ __forceinline__ float4 bf4(ushort4 u) {
  return make_float4(bfu(u.x), bfu(u.y), bfu(u.z), bfu(u.w));
}

// ---------------- CSR build ----------------
__global__ void k_csr_count(const int* __restrict__ ei, int* __restrict__ cnt) {
  int e = blockIdx.x * 256 + threadIdx.x;
  if (e < N_EDGES) atomicAdd(&cnt[ei[N_EDGES + e]], 1);
}

__global__ void k_scan_part(const int* __restrict__ cnt, int* __restrict__ psum) {
  __shared__ int red[256];
  int tid = threadIdx.x;
  int i0 = blockIdx.x * 1024 + tid * 4;
  int s = 0;
  if (i0 + 4 <= N_NODES) {
    int4 v = *reinterpret_cast<const int4*>(cnt + i0);
    s = v.x + v.y + v.z + v.w;
  } else {
    for (int k = 0; k < 4; k++)
      if (i0 + k < N_NODES) s += cnt[i0 + k];
  }
  red[tid] = s;
  __syncthreads();
  for (int o = 128; o > 0; o >>= 1) {
    if (tid < o) red[tid] += red[tid + o];
    __syncthreads();
  }
  if (tid == 0) psum[blockIdx.x] = red[0];
}

__global__ void k_scan_top(const int* __restrict__ psum, int* __restrict__ boff,
                           int* __restrict__ row_ptr) {
  int t = threadIdx.x;  // 64
  int v = (t < SCB) ? psum[t] : 0;
  int own = v;
  for (int o = 1; o < 64; o <<= 1) {
    int u = __shfl_up(v, o);
    if (t >= o) v += u;
  }
  if (t < SCB) boff[t] = v - own;
  if (t == 63) row_ptr[N_NODES] = v;
}

__global__ void k_scan_out(const int* __restrict__ cnt, const int* __restrict__ boff,
                           int* __restrict__ row_ptr, float* __restrict__ dis) {
  __shared__ int ps[256];
  int tid = threadIdx.x;
  int i0 = blockIdx.x * 1024 + tid * 4;
  int v[4];
#pragma unroll
  for (int k = 0; k < 4; k++) v[k] = (i0 + k < N_NODES) ? cnt[i0 + k] : 0;
  int s = v[0] + v[1] + v[2] + v[3];
  ps[tid] = s;
  __syncthreads();
  for (int o = 1; o < 256; o <<= 1) {
    int add = (tid >= o) ? ps[tid - o] : 0;
    __syncthreads();
    ps[tid] += add;
    __syncthreads();
  }
  int run = boff[blockIdx.x] + ((tid > 0) ? ps[tid - 1] : 0);
#pragma unroll
  for (int k = 0; k < 4; k++) {
    if (i0 + k < N_NODES) {
      row_ptr[i0 + k] = run;
      dis[i0 + k] = rsqrtf((float)v[k] + 1.0f);
      run += v[k];
    }
  }
}

__global__ void k_csr_fill(const int* __restrict__ ei, const int* __restrict__ row_ptr,
                           int* __restrict__ fill, int* __restrict__ col_src) {
  int e = blockIdx.x * 256 + threadIdx.x;
  if (e >= N_EDGES) return;
  int s = ei[e], d = ei[N_EDGES + e];
  int pos = row_ptr[d] + atomicAdd(&fill[d], 1);
  col_src[pos] = s;
}

// ---------------- batched weight transpose: W[K,C] fp32 -> Wt[C,K] bf16 ----------------
struct WtArgs {
  const float* src[6];
  ushort* dst[6];
  int K[6];
  int C[6];
  int off[6];  // block offset of each job
};

__global__ void k_wt_all(WtArgs a) {
  int b = blockIdx.x;
  int ji = 0;
#pragma unroll
  for (int t = 1; t < 6; t++)
    if (b >= a.off[t]) ji = t;
  int K = a.K[ji], C = a.C[ji];
  int i = (b - a.off[ji]) * 256 + threadIdx.x;
  int c = i / K, k = i - c * K;
  a.dst[ji][i] = f2bf(a.src[ji][k * C + c]);
}

// ---------------- MFMA GEMM: 64-row blocks, full-C in-block panel loop ----------------
// out[M,C] = A1@W1t^T (+A2@W2t^T) + bias. Wt [C,K] bf16. Grid: ceil(M/64).
// Block: 4 waves; wave owns 16 rows x 64 cols per panel, loops NPAN=C/64 panels.
// A fragments (both, if DUAL) held in registers across all panels -> A read ONCE.
// GATE mode: epilogue computes gate[row] = relu(.)@gw + gb (no C store).
template <int K, int C, bool DUAL, bool AFP32, bool GATE>
__global__ __launch_bounds__(256) void k_mgemm(
    const void* __restrict__ A1v, const ushort* __restrict__ W1t,
    const ushort* __restrict__ A2, const ushort* __restrict__ W2t,
    const float* __restrict__ bias, float* __restrict__ out,
    ushort* __restrict__ out_bf, const float* __restrict__ gw,
    const float* __restrict__ gb, float* __restrict__ gate, int M, int relu) {
  constexpr int KS = K / 32;    // MFMA k-steps
  constexpr int CHK = K / 8;    // 16B chunks per panel row
  constexpr int NPAN = C / 64;  // column panels
  __shared__ ushort wlds[64 * K];
  const int tid = threadIdx.x;
  const int lane = tid & 63;
  const int wid = tid >> 6;
  const int r16 = lane & 15;
  const int kg = lane >> 4;
  const int rbase = blockIdx.x * 64 + wid * 16;

  int arow = rbase + r16;
  if (arow >= M) arow = M - 1;

  // A fragments, loaded once
  bf16x8 af[KS], af2[KS];
  if constexpr (AFP32) {
    const float* ap = (const float*)A1v + (size_t)arow * K + kg * 8;
#pragma unroll
    for (int ks = 0; ks < KS; ks++) {
      float4 lo = *reinterpret_cast<const float4*>(ap + ks * 32);
      float4 hi = *reinterpret_cast<const float4*>(ap + ks * 32 + 4);
      union { u16x8 u; bf16x8 b; } cv;
      cv.u = (u16x8){f2bf(lo.x), f2bf(lo.y), f2bf(lo.z), f2bf(lo.w),
                     f2bf(hi.x), f2bf(hi.y), f2bf(hi.z), f2bf(hi.w)};
      af[ks] = cv.b;
    }
  } else {
    const ushort* ap = (const ushort*)A1v + (size_t)arow * K + kg * 8;
#pragma unroll
    for (int ks = 0; ks < KS; ks++)
      af[ks] = *reinterpret_cast<const bf16x8*>(ap + ks * 32);
  }
  if constexpr (DUAL) {
    const ushort* ap = A2 + (size_t)arow * K + kg * 8;
#pragma unroll
    for (int ks = 0; ks < KS; ks++)
      af2[ks] = *reinterpret_cast<const bf16x8*>(ap + ks * 32);
  }

  float greg[4] = {0.f, 0.f, 0.f, 0.f};  // GATE row partials

#define STAGE(WT)                                                              \
  {                                                                            \
    _Pragma("unroll") for (int jj = 0; jj < (64 * CHK) / 256; jj++) {          \
      int ci = jj * 256 + tid;                                                 \
      int c = ci / CHK, k16 = ci % CHK;                                        \
      int slot = c * CHK + (k16 ^ (c & 7));                                    \
      *reinterpret_cast<float4*>(&wlds[slot * 8]) =                            \
          *reinterpret_cast<const float4*>(&(WT)[(size_t)(c0 + c) * K + k16 * 8]); \
    }                                                                          \
  }

#define COMPUTE(AF)                                                            \
  {                                                                            \
    _Pragma("unroll") for (int ct = 0; ct < 4; ct++) {                         \
      bf16x8 wf[KS];                                                           \
      int colr = ct * 16 + r16;                                                \
      _Pragma("unroll") for (int ks = 0; ks < KS; ks++) {                      \
        int slot = colr * CHK + ((ks * 4 + kg) ^ (r16 & 7));                   \
        wf[ks] = *reinterpret_cast<const bf16x8*>(&wlds[slot * 8]);            \
      }                                                                        \
      _Pragma("unroll") for (int ks = 0; ks < KS; ks++)                        \
        acc[ct] = __builtin_amdgcn_mfma_f32_16x16x32_bf16((AF)[ks], wf[ks],    \
                                                          acc[ct], 0, 0, 0);   \
    }                                                                          \
  }

#pragma unroll
  for (int pan = 0; pan < NPAN; pan++) {
    const int c0 = pan * 64;
    f32x4 acc[4];
#pragma unroll
    for (int ct = 0; ct < 4; ct++) acc[ct] = (f32x4){0.f, 0.f, 0.f, 0.f};

    if (pan) __syncthreads();  // drain reads of previous panel
    STAGE(W1t);
    __syncthreads();
    COMPUTE(af);
    if constexpr (DUAL) {
      __syncthreads();
      STAGE(W2t);
      __syncthreads();
      COMPUTE(af2);
    }

    if constexpr (GATE) {
#pragma unroll
      for (int ct = 0; ct < 4; ct++) {
        int col = c0 + ct * 16 + r16;
        float bv = bias[col];
        float wv = gw[col];
#pragma unroll
        for (int i = 0; i < 4; i++) {
          float v = fmaxf(acc[ct][i] + bv, 0.f);
          greg[i] = fmaf(v, wv, greg[i]);
        }
      }
    } else {
#pragma unroll
      for (int ct = 0; ct < 4; ct++) {
        int col = c0 + ct * 16 + r16;
        float bv = bias ? bias[col] : 0.f;
#pragma unroll
        for (int i = 0; i < 4; i++) {
          int row = rbase + kg * 4 + i;
          if (row < M) {
            float v = acc[ct][i] + bv;
            if (relu) v = fmaxf(v, 0.f);
            if (out) out[(size_t)row * C + col] = v;
            if (out_bf) out_bf[(size_t)row * C + col] = f2bf(v);
          }
        }
      }
    }
  }

  if constexpr (GATE) {
#pragma unroll
    for (int i = 0; i < 4; i++) {
#pragma unroll
      for (int o = 1; o < 16; o <<= 1) greg[i] += __shfl_xor(greg[i], o);
    }
    if (r16 == 0) {
      float b0 = gb[0];
#pragma unroll
      for (int i = 0; i < 4; i++) {
        int row = rbase + kg * 4 + i;
        if (row < M) gate[row] = greg[i] + b0;
      }
    }
  }
#undef STAGE
#undef COMPUTE
}

// ---------------- GCN aggregation (wave per node, 4x unrolled gathers) ----------------
__global__ void k_gcn_agg(const ushort* __restrict__ xt, const float* __restrict__ dis,
                          const int* __restrict__ row_ptr, const int* __restrict__ col_src,
                          const float* __restrict__ b_gcn, float* __restrict__ out) {
  int node = blockIdx.x * 4 + (threadIdx.x >> 6);
  if (node >= N_NODES) return;
  int lane = threadIdx.x & 63;
  float di = dis[node];
  float4 x = bf4(*reinterpret_cast<const ushort4*>(xt + (size_t)node * HID + lane * 4));
  float w0 = di * di;
  float4 acc = make_float4(x.x * w0, x.y * w0, x.z * w0, x.w * w0);
  int b = row_ptr[node], e = row_ptr[node + 1];
  int i = b;
  for (; i + 4 <= e; i += 4) {
    int s0 = col_src[i], s1 = col_src[i + 1], s2 = col_src[i + 2], s3 = col_src[i + 3];
    ushort4 u0 = *reinterpret_cast<const ushort4*>(xt + (size_t)s0 * HID + lane * 4);
    ushort4 u1 = *reinterpret_cast<const ushort4*>(xt + (size_t)s1 * HID + lane * 4);
    ushort4 u2 = *reinterpret_cast<const ushort4*>(xt + (size_t)s2 * HID + lane * 4);
    ushort4 u3 = *reinterpret_cast<const ushort4*>(xt + (size_t)s3 * HID + lane * 4);
    float n0 = di * dis[s0], n1 = di * dis[s1], n2 = di * dis[s2], n3 = di * dis[s3];
    float4 v0 = bf4(u0), v1 = bf4(u1), v2 = bf4(u2), v3 = bf4(u3);
    acc.x = fmaf(v0.x, n0, acc.x); acc.y = fmaf(v0.y, n0, acc.y);
    acc.z = fmaf(v0.z, n0, acc.z); acc.w = fmaf(v0.w, n0, acc.w);
    acc.x = fmaf(v1.x, n1, acc.x); acc.y = fmaf(v1.y, n1, acc.y);
    acc.z = fmaf(v1.z, n1, acc.z); acc.w = fmaf(v1.w, n1, acc.w);
    acc.x = fmaf(v2.x, n2, acc.x); acc.y = fmaf(v2.y, n2, acc.y);
    acc.z = fmaf(v2.z, n2, acc.z); acc.w = fmaf(v2.w, n2, acc.w);
    acc.x = fmaf(v3.x, n3, acc.x); acc.y = fmaf(v3.y, n3, acc.y);
    acc.z = fmaf(v3.z, n3, acc.z); acc.w = fmaf(v3.w, n3, acc.w);
  }
  for (; i < e; i++) {
    int s = col_src[i];
    float nw = di * dis[s];
    float4 xv = bf4(*reinterpret_cast<const ushort4*>(xt + (size_t)s * HID + lane * 4));
    acc.x = fmaf(xv.x, nw, acc.x); acc.y = fmaf(xv.y, nw, acc.y);
    acc.z = fmaf(xv.z, nw, acc.z); acc.w = fmaf(xv.w, nw, acc.w);
  }
  float4 bb = *reinterpret_cast<const float4*>(b_gcn + lane * 4);
  acc.x += bb.x; acc.y += bb.y; acc.z += bb.z; acc.w += bb.w;
  *reinterpret_cast<float4*>(out + (size_t)node * HID + lane * 4) = acc;
}

// ---------------- GAT ----------------
__global__ void k_gat_al(const ushort* __restrict__ xt, const float* __restrict__ a_src,
                         const float* __restrict__ a_dst, float* __restrict__ alsrc,
                         float* __restrict__ aldst) {
  int node = blockIdx.x * 4 + (threadIdx.x >> 6);
  if (node >= N_NODES) return;
  int lane = threadIdx.x & 63;
  float4 v = bf4(*reinterpret_cast<const ushort4*>(xt + (size_t)node * HID + lane * 4));
  float4 as = *reinterpret_cast<const float4*>(a_src + lane * 4);
  float4 ad = *reinterpret_cast<const float4*>(a_dst + lane * 4);
  float ps = v.x * as.x + v.y * as.y + v.z * as.z + v.w * as.w;
  float pd = v.x * ad.x + v.y * ad.y + v.z * ad.z + v.w * ad.w;
  for (int o = 1; o < 8; o <<= 1) { ps += __shfl_xor(ps, o); pd += __shfl_xor(pd, o); }
  if ((lane & 7) == 0) {
    alsrc[node * 8 + (lane >> 3)] = ps;
    aldst[node * 8 + (lane >> 3)] = pd;
  }
}

__device__ __forceinline__ float leaky02(float x) { return x > 0.f ? x : 0.2f * x; }

// Single-pass GAT: exp without max-shift (logits O(1)); denominator accumulated
// in the same loop (all 8 lanes of a head group compute identical alpha).
__global__ void k_gat_agg(const ushort* __restrict__ xt, const float* __restrict__ alsrc,
                          const float* __restrict__ aldst, const int* __restrict__ row_ptr,
                          const int* __restrict__ col_src, const float* __restrict__ b_gat,
                          float* __restrict__ out) {
  int node = blockIdx.x * 4 + (threadIdx.x >> 6);
  if (node >= N_NODES) return;
  int lane = threadIdx.x & 63;
  int hh = lane >> 3;
  float ad = aldst[node * 8 + hh];
  float e0 = __expf(leaky02(alsrc[node * 8 + hh] + ad));  // self-loop
  float4 x = bf4(*reinterpret_cast<const ushort4*>(xt + (size_t)node * HID + lane * 4));
  float4 acc = make_float4(x.x * e0, x.y * e0, x.z * e0, x.w * e0);
  float s = e0;
  int b = row_ptr[node], e = row_ptr[node + 1];
  int i = b;
  for (; i + 4 <= e; i += 4) {
    int s0 = col_src[i], s1 = col_src[i + 1], s2 = col_src[i + 2], s3 = col_src[i + 3];
    float g0 = alsrc[s0 * 8 + hh], g1 = alsrc[s1 * 8 + hh];
    float g2 = alsrc[s2 * 8 + hh], g3 = alsrc[s3 * 8 + hh];
    ushort4 u0 = *reinterpret_cast<const ushort4*>(xt + (size_t)s0 * HID + lane * 4);
    ushort4 u1 = *reinterpret_cast<const ushort4*>(xt + (size_t)s1 * HID + lane * 4);
    ushort4 u2 = *reinterpret_cast<const ushort4*>(xt + (size_t)s2 * HID + lane * 4);
    ushort4 u3 = *reinterpret_cast<const ushort4*>(xt + (size_t)s3 * HID + lane * 4);
    float a1 = __expf(leaky02(g0 + ad));
    float a2 = __expf(leaky02(g1 + ad));
    float a3 = __expf(leaky02(g2 + ad));
    float a4 = __expf(leaky02(g3 + ad));
    s += a1 + a2 + a3 + a4;
    float4 v0 = bf4(u0), v1 = bf4(u1), v2 = bf4(u2), v3 = bf4(u3);
    acc.x = fmaf(v0.x, a1, acc.x); acc.y = fmaf(v0.y, a1, acc.y);
    acc.z = fmaf(v0.z, a1, acc.z); acc.w = fmaf(v0.w, a1, acc.w);
    acc.x = fmaf(v1.x, a2, acc.x); acc.y = fmaf(v1.y, a2, acc.y);
    acc.z = fmaf(v1.z, a2, acc.z); acc.w = fmaf(v1.w, a2, acc.w);
    acc.x = fmaf(v2.x, a3, acc.x); acc.y = fmaf(v2.y, a3, acc.y);
    acc.z = fmaf(v2.z, a3, acc.z); acc.w = fmaf(v2.w, a3, acc.w);
    acc.x = fmaf(v3.x, a4, acc.x); acc.y = fmaf(v3.y, a4, acc.y);
    acc.z = fmaf(v3.z, a4, acc.z); acc.w = fmaf(v3.w, a4, acc.w);
  }
  for (; i < e; i++) {
    int src = col_src[i];
    float al = __expf(leaky02(alsrc[src * 8 + hh] + ad));
    s += al;
    float4 xv = bf4(*reinterpret_cast<const ushort4*>(xt + (size_t)src * HID + lane * 4));
    acc.x = fmaf(xv.x, al, acc.x); acc.y = fmaf(xv.y, al, acc.y);
    acc.z = fmaf(xv.z, al, acc.z); acc.w = fmaf(xv.w, al, acc.w);
  }
  float inv_s = 1.0f / s;
  float4 bb = *reinterpret_cast<const float4*>(b_gat + lane * 4);
  acc.x = fmaf(acc.x, inv_s, bb.x);
  acc.y = fmaf(acc.y, inv_s, bb.y);
  acc.z = fmaf(acc.z, inv_s, bb.z);
  acc.w = fmaf(acc.w, inv_s, bb.w);
  *reinterpret_cast<float4*>(out + (size_t)node * HID + lane * 4) = acc;
}

// ---------------- SAGE mean aggregation (bf16 in, bf16 out, 4x unrolled) ----------------
__global__ void k_sage_agg(const ushort* __restrict__ h, const int* __restrict__ row_ptr,
                           const int* __restrict__ col_src, ushort* __restrict__ out) {
  int node = blockIdx.x * 4 + (threadIdx.x >> 6);
  if (node >= N_NODES) return;
  int lane = threadIdx.x & 63;
  int b = row_ptr[node], e = row_ptr[node + 1];
  float inv = 1.0f / fmaxf((float)(e - b), 1.0f);
  float4 acc = make_float4(0.f, 0.f, 0.f, 0.f);
  int i = b;
  for (; i + 4 <= e; i += 4) {
    int s0 = col_src[i], s1 = col_src[i + 1], s2 = col_src[i + 2], s3 = col_src[i + 3];
    ushort4 u0 = *reinterpret_cast<const ushort4*>(h + (size_t)s0 * HID + lane * 4);
    ushort4 u1 = *reinterpret_cast<const ushort4*>(h + (size_t)s1 * HID + lane * 4);
    ushort4 u2 = *reinterpret_cast<const ushort4*>(h + (size_t)s2 * HID + lane * 4);
    ushort4 u3 = *reinterpret_cast<const ushort4*>(h + (size_t)s3 * HID + lane * 4);
    float4 v0 = bf4(u0), v1 = bf4(u1), v2 = bf4(u2), v3 = bf4(u3);
    acc.x += v0.x + v1.x + v2.x + v3.x;
    acc.y += v0.y + v1.y + v2.y + v3.y;
    acc.z += v0.z + v1.z + v2.z + v3.z;
    acc.w += v0.w + v1.w + v2.w + v3.w;
  }
  for (; i < e; i++) {
    int s = col_src[i];
    float4 xv = bf4(*reinterpret_cast<const ushort4*>(h + (size_t)s * HID + lane * 4));
    acc.x += xv.x; acc.y += xv.y; acc.z += xv.z; acc.w += xv.w;
  }
  *reinterpret_cast<ushort4*>(out + (size_t)node * HID + lane * 4) =
      make_ushort4(f2bf(acc.x * inv), f2bf(acc.y * inv), f2bf(acc.z * inv), f2bf(acc.w * inv));
}

// ---------------- BatchNorm ----------------
__global__ void k_bn_stats(const float* __restrict__ x, float* __restrict__ stats) {
  int c = threadIdx.x;
  float s = 0.f, q = 0.f;
  for (int r = blockIdx.x; r < N_NODES; r += gridDim.x) {
    float v = x[(size_t)r * HID + c];
    s += v;
    q = fmaf(v, v, q);
  }
  atomicAdd(&stats[c], s);
  atomicAdd(&stats[HID + c], q);
}

// h += relu(bn(x)); also emit h_bf
__global__ void k_bn_apply(const float* __restrict__ x, const float* __restrict__ stats,
                           const float* __restrict__ gamma, const float* __restrict__ beta,
                           float* __restrict__ h, ushort* __restrict__ h_bf) {
  const float invN = 1.0f / (float)N_NODES;
  int total = N_NODES * 64;
  for (int i = blockIdx.x * 256 + threadIdx.x; i < total; i += gridDim.x * 256) {
    int c4 = (i & 63) * 4;
    float4 xv = *reinterpret_cast<const float4*>(x + (size_t)i * 4);
    float4 sm = *reinterpret_cast<const float4*>(stats + c4);
    float4 sq = *reinterpret_cast<const float4*>(stats + HID + c4);
    float4 gm = *reinterpret_cast<const float4*>(gamma + c4);
    float4 bt = *reinterpret_cast<const float4*>(beta + c4);
    float4 hv = *reinterpret_cast<const float4*>(h + (size_t)i * 4);
#define BN1(f)                                                    \
  {                                                               \
    float mu = sm.f * invN;                                       \
    float var = sq.f * invN - mu * mu;                            \
    float sc = gm.f * rsqrtf(var + EPS);                          \
    float v = (xv.f - mu) * sc + bt.f;                            \
    hv.f += fmaxf(v, 0.f);                                        \
  }
    BN1(x) BN1(y) BN1(z) BN1(w)
#undef BN1
    *reinterpret_cast<float4*>(h + (size_t)i * 4) = hv;
    *reinterpret_cast<ushort4*>(h_bf + (size_t)i * 4) =
        make_ushort4(f2bf(hv.x), f2bf(hv.y), f2bf(hv.z), f2bf(hv.w));
  }
}

// ---------------- graph segment starts ----------------
__global__ void k_gstart(const int* __restrict__ batch, int* __restrict__ gstart) {
  int g = blockIdx.x * 256 + threadIdx.x;
  if (g > NG) return;
  int lo = 0, hi = N_NODES;
  while (lo < hi) {
    int mid = (lo + hi) >> 1;
    if (batch[mid] < g) lo = mid + 1; else hi = mid;
  }
  gstart[g] = lo;
}

// ---------------- global attention pooling ----------------
__global__ void k_pool(const float* __restrict__ h, const float* __restrict__ gate,
                       const int* __restrict__ gstart, float* __restrict__ hg) {
  __shared__ float red[256];
  __shared__ float wbuf[256];
  int g = blockIdx.x, tid = threadIdx.x;
  int b = gstart[g], e = gstart[g + 1];
  float m = -1e30f;
  for (int r = b + tid; r < e; r += 256) m = fmaxf(m, gate[r]);
  red[tid] = m;
  __syncthreads();
  for (int o = 128; o > 0; o >>= 1) {
    if (tid < o) red[tid] = fmaxf(red[tid], red[tid + o]);
    __syncthreads();
  }
  m = red[0];
  __syncthreads();
  float s = 0.f;
  for (int r = b + tid; r < e; r += 256) s += __expf(gate[r] - m);
  red[tid] = s;
  __syncthreads();
  for (int o = 128; o > 0; o >>= 1) {
    if (tid < o) red[tid] += red[tid + o];
    __syncthreads();
  }
  float inv = 1.0f / fmaxf(red[0], 1e-16f);
  __syncthreads();
  float acc = 0.f;
  for (int cb = b; cb < e; cb += 256) {
    int r = cb + tid;
    wbuf[tid] = (r < e) ? __expf(gate[r] - m) : 0.f;
    __syncthreads();
    int n = min(256, e - cb);
    for (int j = 0; j < n; j++) acc = fmaf(h[(size_t)(cb + j) * HID + tid], wbuf[j], acc);
    __syncthreads();
  }
  hg[(size_t)g * HID + tid] = acc * inv;
}

// ---------------- MLP head ----------------
__global__ void k_mlp(const float* __restrict__ hg, const float* __restrict__ W1,
                      const float* __restrict__ b1, const float* __restrict__ lng,
                      const float* __restrict__ lnb, const float* __restrict__ W2,
                      const float* __restrict__ b2, float* __restrict__ out) {
  __shared__ float row[HID];
  __shared__ float z[HID];
  __shared__ float red[HID];
  int g = blockIdx.x, tid = threadIdx.x;
  row[tid] = hg[(size_t)g * HID + tid];
  __syncthreads();
  float acc = b1[tid];
  for (int k = 0; k < HID; k++) acc = fmaf(row[k], W1[(size_t)k * HID + tid], acc);
  red[tid] = acc;
  __syncthreads();
  for (int o = 128; o > 0; o >>= 1) {
    if (tid < o) red[tid] += red[tid + o];
    __syncthreads();
  }
  float mu = red[0] * (1.0f / HID);
  __syncthreads();
  red[tid] = acc * acc;
  __syncthreads();
  for (int o = 128; o > 0; o >>= 1) {
    if (tid < o) red[tid] += red[tid + o];
    __syncthreads();
  }
  float var = red[0] * (1.0f / HID) - mu * mu;
  float zz = (acc - mu) * rsqrtf(var + EPS) * lng[tid] + lnb[tid];
  z[tid] = fmaxf(zz, 0.f);
  __syncthreads();
  if (tid < 64) {
    float o = b2[tid];
    for (int k = 0; k < HID; k++) o = fmaf(z[k], W2[(size_t)k * 64 + tid], o);
    out[(size_t)g * 64 + tid] = o;
  }
}

// ---------------- launch ----------------
extern "C" void kernel_launch(void* const* d_in, const int* in_sizes, int n_in,
                              void* d_out, int out_size, void* d_ws, size_t ws_size,
                              hipStream_t stream) {
  const float* x     = (const float*)d_in[0];
  const float* W_emb = (const float*)d_in[1];
  const float* b_emb = (const float*)d_in[2];
  const float* W_gcn = (const float*)d_in[3];
  const float* b_gcn = (const float*)d_in[4];
  const float* W_gat = (const float*)d_in[5];
  const float* a_src = (const float*)d_in[6];
  const float* a_dst = (const float*)d_in[7];
  const float* b_gat = (const float*)d_in[8];
  const float* W_l   = (const float*)d_in[9];
  const float* b_l   = (const float*)d_in[10];
  const float* W_r   = (const float*)d_in[11];
  const float* bn_g  = (const float*)d_in[12];
  const float* bn_b  = (const float*)d_in[13];
  const float* Wg1   = (const float*)d_in[14];
  const float* bg1   = (const float*)d_in[15];
  const float* Wg2   = (const float*)d_in[16];
  const float* bg2   = (const float*)d_in[17];
  const float* Wm1   = (const float*)d_in[18];
  const float* bm1   = (const float*)d_in[19];
  const float* lnmg  = (const float*)d_in[20];
  const float* lnmb  = (const float*)d_in[21];
  const float* Wm2   = (const float*)d_in[22];
  const float* bm2   = (const float*)d_in[23];
  const float* Wv1   = (const float*)d_in[24];
  const float* bv1   = (const float*)d_in[25];
  const float* lnvg  = (const float*)d_in[26];
  const float* lnvb  = (const float*)d_in[27];
  const float* Wv2   = (const float*)d_in[28];
  const float* bv2   = (const float*)d_in[29];
  const int* ei      = (const int*)d_in[30];
  const int* batch   = (const int*)d_in[31];
  float* out = (float*)d_out;

  float* ws = (float*)d_ws;
  float* h     = ws;
  float* t1    = h + (size_t)N_NODES * HID;
  float* alsrc = t1 + (size_t)N_NODES * HID;
  float* aldst = alsrc + N_NODES * 8;
  float* dis   = aldst + N_NODES * 8;
  float* gate  = dis + N_NODES;
  float* hg    = gate + N_NODES;
  float* zbase = hg + NG * HID;        // zeroed region: bnst + row_cnt + fill
  float* bnst  = zbase;                // 3 * 512
  int* row_cnt = (int*)(zbase + 3 * 512);
  int* fill    = row_cnt + N_NODES;
  int* row_ptr = fill + N_NODES;
  int* col_src = row_ptr + N_NODES + 1;
  int* gstart  = col_src + N_EDGES;
  int* psum    = gstart + NG + 1;
  int* boff    = psum + 64;

  size_t off = (size_t)((char*)(boff + 64) - (char*)d_ws);
  off = (off + 15) & ~(size_t)15;
  ushort* h_bf   = (ushort*)((char*)d_ws + off);
  ushort* t0_bf  = h_bf + (size_t)N_NODES * HID;
  ushort* wemb_t = t0_bf + (size_t)N_NODES * HID;
  ushort* wgcn_t = wemb_t + 128 * 256;
  ushort* wgat_t = wgcn_t + 256 * 256;
  ushort* wr_t   = wgat_t + 256 * 256;
  ushort* wl_t   = wr_t + 256 * 256;
  ushort* wg1_t  = wl_t + 256 * 256;   // 256*128

  size_t zbytes = (size_t)3 * 512 * 4 + 2 * (size_t)N_NODES * 4;
  hipMemsetAsync(zbase, 0, zbytes, stream);

  // CSR by dst (hierarchical scan + fused dis)
  k_csr_count<<<(N_EDGES + 255) / 256, 256, 0, stream>>>(ei, row_cnt);
  k_scan_part<<<SCB, 256, 0, stream>>>(row_cnt, psum);
  k_scan_top<<<1, 64, 0, stream>>>(psum, boff, row_ptr);
  k_scan_out<<<SCB, 256, 0, stream>>>(row_cnt, boff, row_ptr, dis);
  k_csr_fill<<<(N_EDGES + 255) / 256, 256, 0, stream>>>(ei, row_ptr, fill, col_src);

  // all weight transposes in one launch
  WtArgs wa;
  wa.src[0] = W_emb; wa.dst[0] = wemb_t; wa.K[0] = 128; wa.C[0] = 256; wa.off[0] = 0;
  wa.src[1] = W_gcn; wa.dst[1] = wgcn_t; wa.K[1] = 256; wa.C[1] = 256; wa.off[1] = 128;
  wa.src[2] = W_gat; wa.dst[2] = wgat_t; wa.K[2] = 256; wa.C[2] = 256; wa.off[2] = 384;
  wa.src[3] = W_r;   wa.dst[3] = wr_t;   wa.K[3] = 256; wa.C[3] = 256; wa.off[3] = 640;
  wa.src[4] = W_l;   wa.dst[4] = wl_t;   wa.K[4] = 256; wa.C[4] = 256; wa.off[4] = 896;
  wa.src[5] = Wg1;   wa.dst[5] = wg1_t;  wa.K[5] = 256; wa.C[5] = 128; wa.off[5] = 1152;
  k_wt_all<<<1280, 256, 0, stream>>>(wa);

  const int RB = (N_NODES + 63) / 64;   // 782 gemm blocks
  const int AB = (N_NODES + 3) / 4;     // 12500 agg blocks

  // embedding: h = x @ W_emb + b_emb  (fp32 A converted on load; fp32 + bf16 out)
  k_mgemm<128, 256, false, true, false><<<RB, 256, 0, stream>>>(
      x, wemb_t, nullptr, nullptr, b_emb, h, h_bf, nullptr, nullptr, nullptr, N_NODES, 0);

  // --- GCN ---
  k_mgemm<256, 256, false, false, false><<<RB, 256, 0, stream>>>(
      h_bf, wgcn_t, nullptr, nullptr, nullptr, nullptr, t0_bf, nullptr, nullptr, nullptr, N_NODES, 0);
  k_gcn_agg<<<AB, 256, 0, stream>>>(t0_bf, dis, row_ptr, col_src, b_gcn, t1);
  k_bn_stats<<<256, 256, 0, stream>>>(t1, bnst);
  k_bn_apply<<<1024, 256, 0, stream>>>(t1, bnst, bn_g, bn_b, h, h_bf);

  // --- GAT (single-pass softmax fused into agg) ---
  k_mgemm<256, 256, false, false, false><<<RB, 256, 0, stream>>>(
      h_bf, wgat_t, nullptr, nullptr, nullptr, nullptr, t0_bf, nullptr, nullptr, nullptr, N_NODES, 0);
  k_gat_al<<<AB, 256, 0, stream>>>(t0_bf, a_src, a_dst, alsrc, aldst);
  k_gat_agg<<<AB, 256, 0, stream>>>(t0_bf, alsrc, aldst, row_ptr, col_src, b_gat, t1);
  k_bn_stats<<<256, 256, 0, stream>>>(t1, bnst + 512);
  k_bn_apply<<<1024, 256, 0, stream>>>(t1, bnst + 512, bn_g + HID, bn_b + HID, h, h_bf);

  // --- SAGE: t1 = h@W_r + b_l + mean@W_l (dual, both A-frag sets in regs) ---
  k_sage_agg<<<AB, 256, 0, stream>>>(h_bf, row_ptr, col_src, t0_bf);
  k_mgemm<256, 256, true, false, false><<<RB, 256, 0, stream>>>(
      h_bf, wr_t, t0_bf, wl_t, b_l, t1, nullptr, nullptr, nullptr, nullptr, N_NODES, 0);
  k_bn_stats<<<256, 256, 0, stream>>>(t1, bnst + 1024);
  k_bn_apply<<<1024, 256, 0, stream>>>(t1, bnst + 1024, bn_g + 2 * HID, bn_b + 2 * HID, h, h_bf);

  // --- gate (fully fused GEMM epilogue) + pooling ---
  k_mgemm<256, 128, false, false, true><<<RB, 256, 0, stream>>>(
      h_bf, wg1_t, nullptr, nullptr, bg1, nullptr, nullptr, Wg2, bg2, gate, N_NODES, 1);
  k_gstart<<<3, 256, 0, stream>>>(batch, gstart);
  k_pool<<<NG, 256, 0, stream>>>(h, gate, gstart, hg);

  // --- heads ---
  k_mlp<<<NG, 256, 0, stream>>>(hg, Wm1, bm1, lnmg, lnmb, Wm2, bm2, out);
  k_mlp<<<NG, 256, 0, stream>>>(hg, Wv1, bv1, lnvg, lnvb, Wv2, bv2, out + (size_t)NG * 64);
}

// Round 7
// 654.332 us; speedup vs baseline: 1.9863x; 1.0276x over previous
//
#include <hip/hip_runtime.h>
#include <cstdint>
#include <cstddef>

#define N_NODES 50000
#define N_EDGES 500000
#define NG 512
#define HID 256
#define EPS 1e-5f
#define SCB 49  // scan blocks: ceil(50000/1024)

typedef __attribute__((ext_vector_type(8))) __bf16 bf16x8;
typedef __attribute__((ext_vector_type(8))) ushort u16x8;
typedef __attribute__((ext_vector_type(4))) float f32x4;

__device__ __forceinline__ ushort f2bf(float f) {
  uint32_t u = __float_as_uint(f);
  uint32_t r = (u + 0x7fffu + ((u >> 16) & 1u)) >> 16;
  return (ushort)r;
}
__device__ __forceinline__ float bfu(ushort u) { return __uint_as_float(((uint32_t)u) << 16); }
__device__ __forceinline__ float4 bf4(ushort4 u) {
  return make_float4(bfu(u.x), bfu(u.y), bfu(u.z), bfu(u.w));
}

// ---------------- CSR build ----------------
__global__ void k_csr_count(const int* __restrict__ ei, int* __restrict__ cnt) {
  int e = blockIdx.x * 256 + threadIdx.x;
  if (e < N_EDGES) atomicAdd(&cnt[ei[N_EDGES + e]], 1);
}

__global__ void k_scan_part(const int* __restrict__ cnt, int* __restrict__ psum) {
  __shared__ int red[256];
  int tid = threadIdx.x;
  int i0 = blockIdx.x * 1024 + tid * 4;
  int s = 0;
  if (i0 + 4 <= N_NODES) {
    int4 v = *reinterpret_cast<const int4*>(cnt + i0);
    s = v.x + v.y + v.z + v.w;
  } else {
    for (int k = 0; k < 4; k++)
      if (i0 + k < N_NODES) s += cnt[i0 + k];
  }
  red[tid] = s;
  __syncthreads();
  for (int o = 128; o > 0; o >>= 1) {
    if (tid < o) red[tid] += red[tid + o];
    __syncthreads();
  }
  if (tid == 0) psum[blockIdx.x] = red[0];
}

__global__ void k_scan_top(const int* __restrict__ psum, int* __restrict__ boff,
                           int* __restrict__ row_ptr) {
  int t = threadIdx.x;  // 64
  int v = (t < SCB) ? psum[t] : 0;
  int own = v;
  for (int o = 1; o < 64; o <<= 1) {
    int u = __shfl_up(v, o);
    if (t >= o) v += u;
  }
  if (t < SCB) boff[t] = v - own;
  if (t == 63) row_ptr[N_NODES] = v;
}

__global__ void k_scan_out(const int* __restrict__ cnt, const int* __restrict__ boff,
                           int* __restrict__ row_ptr, float* __restrict__ dis) {
  __shared__ int ps[256];
  int tid = threadIdx.x;
  int i0 = blockIdx.x * 1024 + tid * 4;
  int v[4];
#pragma unroll
  for (int k = 0; k < 4; k++) v[k] = (i0 + k < N_NODES) ? cnt[i0 + k] : 0;
  int s = v[0] + v[1] + v[2] + v[3];
  ps[tid] = s;
  __syncthreads();
  for (int o = 1; o < 256; o <<= 1) {
    int add = (tid >= o) ? ps[tid - o] : 0;
    __syncthreads();
    ps[tid] += add;
    __syncthreads();
  }
  int run = boff[blockIdx.x] + ((tid > 0) ? ps[tid - 1] : 0);
#pragma unroll
  for (int k = 0; k < 4; k++) {
    if (i0 + k < N_NODES) {
      row_ptr[i0 + k] = run;
      dis[i0 + k] = rsqrtf((float)v[k] + 1.0f);
      run += v[k];
    }
  }
}

__global__ void k_csr_fill(const int* __restrict__ ei, const int* __restrict__ row_ptr,
                           int* __restrict__ fill, int* __restrict__ col_src) {
  int e = blockIdx.x * 256 + threadIdx.x;
  if (e >= N_EDGES) return;
  int s = ei[e], d = ei[N_EDGES + e];
  int pos = row_ptr[d] + atomicAdd(&fill[d], 1);
  col_src[pos] = s;
}

// ---------------- batched weight transpose: W[K,C] fp32 -> Wt[C,K] bf16 ----------------
struct WtArgs {
  const float* src[6];
  ushort* dst[6];
  int K[6];
  int C[6];
  int off[6];
};

__global__ void k_wt_all(WtArgs a) {
  int b = blockIdx.x;
  int ji = 0;
#pragma unroll
  for (int t = 1; t < 6; t++)
    if (b >= a.off[t]) ji = t;
  int K = a.K[ji], C = a.C[ji];
  int i = (b - a.off[ji]) * 256 + threadIdx.x;
  int c = i / K, k = i - c * K;
  a.dst[ji][i] = f2bf(a.src[ji][k * C + c]);
}

// ---------------- MFMA GEMM: 64-row blocks, full-C in-block panel loop ----------------
template <int K, int C, bool DUAL, bool AFP32, bool GATE>
__global__ __launch_bounds__(256) void k_mgemm(
    const void* __restrict__ A1v, const ushort* __restrict__ W1t,
    const ushort* __restrict__ A2, const ushort* __restrict__ W2t,
    const float* __restrict__ bias, float* __restrict__ out,
    ushort* __restrict__ out_bf, const float* __restrict__ gw,
    const float* __restrict__ gb, float* __restrict__ gate, int M, int relu) {
  constexpr int KS = K / 32;
  constexpr int CHK = K / 8;
  constexpr int NPAN = C / 64;
  __shared__ ushort wlds[64 * K];
  const int tid = threadIdx.x;
  const int lane = tid & 63;
  const int wid = tid >> 6;
  const int r16 = lane & 15;
  const int kg = lane >> 4;
  const int rbase = blockIdx.x * 64 + wid * 16;

  int arow = rbase + r16;
  if (arow >= M) arow = M - 1;

  bf16x8 af[KS], af2[KS];
  if constexpr (AFP32) {
    const float* ap = (const float*)A1v + (size_t)arow * K + kg * 8;
#pragma unroll
    for (int ks = 0; ks < KS; ks++) {
      float4 lo = *reinterpret_cast<const float4*>(ap + ks * 32);
      float4 hi = *reinterpret_cast<const float4*>(ap + ks * 32 + 4);
      union { u16x8 u; bf16x8 b; } cv;
      cv.u = (u16x8){f2bf(lo.x), f2bf(lo.y), f2bf(lo.z), f2bf(lo.w),
                     f2bf(hi.x), f2bf(hi.y), f2bf(hi.z), f2bf(hi.w)};
      af[ks] = cv.b;
    }
  } else {
    const ushort* ap = (const ushort*)A1v + (size_t)arow * K + kg * 8;
#pragma unroll
    for (int ks = 0; ks < KS; ks++)
      af[ks] = *reinterpret_cast<const bf16x8*>(ap + ks * 32);
  }
  if constexpr (DUAL) {
    const ushort* ap = A2 + (size_t)arow * K + kg * 8;
#pragma unroll
    for (int ks = 0; ks < KS; ks++)
      af2[ks] = *reinterpret_cast<const bf16x8*>(ap + ks * 32);
  }

  float greg[4] = {0.f, 0.f, 0.f, 0.f};

#define STAGE(WT)                                                              \
  {                                                                            \
    _Pragma("unroll") for (int jj = 0; jj < (64 * CHK) / 256; jj++) {          \
      int ci = jj * 256 + tid;                                                 \
      int c = ci / CHK, k16 = ci % CHK;                                        \
      int slot = c * CHK + (k16 ^ (c & 7));                                    \
      *reinterpret_cast<float4*>(&wlds[slot * 8]) =                            \
          *reinterpret_cast<const float4*>(&(WT)[(size_t)(c0 + c) * K + k16 * 8]); \
    }                                                                          \
  }

#define COMPUTE(AF)                                                            \
  {                                                                            \
    _Pragma("unroll") for (int ct = 0; ct < 4; ct++) {                         \
      bf16x8 wf[KS];                                                           \
      int colr = ct * 16 + r16;                                                \
      _Pragma("unroll") for (int ks = 0; ks < KS; ks++) {                      \
        int slot = colr * CHK + ((ks * 4 + kg) ^ (r16 & 7));                   \
        wf[ks] = *reinterpret_cast<const bf16x8*>(&wlds[slot * 8]);            \
      }                                                                        \
      _Pragma("unroll") for (int ks = 0; ks < KS; ks++)                        \
        acc[ct] = __builtin_amdgcn_mfma_f32_16x16x32_bf16((AF)[ks], wf[ks],    \
                                                          acc[ct], 0, 0, 0);   \
    }                                                                          \
  }

#pragma unroll
  for (int pan = 0; pan < NPAN; pan++) {
    const int c0 = pan * 64;
    f32x4 acc[4];
#pragma unroll
    for (int ct = 0; ct < 4; ct++) acc[ct] = (f32x4){0.f, 0.f, 0.f, 0.f};

    if (pan) __syncthreads();
    STAGE(W1t);
    __syncthreads();
    COMPUTE(af);
    if constexpr (DUAL) {
      __syncthreads();
      STAGE(W2t);
      __syncthreads();
      COMPUTE(af2);
    }

    if constexpr (GATE) {
#pragma unroll
      for (int ct = 0; ct < 4; ct++) {
        int col = c0 + ct * 16 + r16;
        float bv = bias[col];
        float wv = gw[col];
#pragma unroll
        for (int i = 0; i < 4; i++) {
          float v = fmaxf(acc[ct][i] + bv, 0.f);
          greg[i] = fmaf(v, wv, greg[i]);
        }
      }
    } else {
#pragma unroll
      for (int ct = 0; ct < 4; ct++) {
        int col = c0 + ct * 16 + r16;
        float bv = bias ? bias[col] : 0.f;
#pragma unroll
        for (int i = 0; i < 4; i++) {
          int row = rbase + kg * 4 + i;
          if (row < M) {
            float v = acc[ct][i] + bv;
            if (relu) v = fmaxf(v, 0.f);
            if (out) out[(size_t)row * C + col] = v;
            if (out_bf) out_bf[(size_t)row * C + col] = f2bf(v);
          }
        }
      }
    }
  }

  if constexpr (GATE) {
#pragma unroll
    for (int i = 0; i < 4; i++) {
#pragma unroll
      for (int o = 1; o < 16; o <<= 1) greg[i] += __shfl_xor(greg[i], o);
    }
    if (r16 == 0) {
      float b0 = gb[0];
#pragma unroll
      for (int i = 0; i < 4; i++) {
        int row = rbase + kg * 4 + i;
        if (row < M) gate[row] = greg[i] + b0;
      }
    }
  }
#undef STAGE
#undef COMPUTE
}

// ---------------- GCN aggregation: wave/node, 32 lanes/row (16B loads), bf16 out ----------------
// lane owns 8 cols c0=(lane&31)*8; half 0 (lanes 0-31) edges 4g,4g+1; half 1 edges 4g+2,4g+3.
__global__ void k_gcn_agg(const ushort* __restrict__ xt, const float* __restrict__ dis,
                          const int* __restrict__ row_ptr, const int* __restrict__ col_src,
                          const float* __restrict__ b_gcn, ushort* __restrict__ outb) {
  int node = blockIdx.x * 4 + (threadIdx.x >> 6);
  if (node >= N_NODES) return;
  int lane = threadIdx.x & 63;
  int half = lane >> 5;
  int c0 = (lane & 31) * 8;
  float di = dis[node];
  float acc[8];
#pragma unroll
  for (int j = 0; j < 8; j++) acc[j] = 0.f;
  int b = row_ptr[node], e = row_ptr[node + 1];
  int g0 = b;
  for (; g0 + 4 <= e; g0 += 4) {
    int i0 = g0 + half * 2;
    int s0 = col_src[i0], s1 = col_src[i0 + 1];
    float w0 = di * dis[s0], w1 = di * dis[s1];
    u16x8 u0 = *reinterpret_cast<const u16x8*>(xt + (size_t)s0 * HID + c0);
    u16x8 u1 = *reinterpret_cast<const u16x8*>(xt + (size_t)s1 * HID + c0);
#pragma unroll
    for (int j = 0; j < 8; j++) {
      acc[j] = fmaf(bfu(u0[j]), w0, acc[j]);
      acc[j] = fmaf(bfu(u1[j]), w1, acc[j]);
    }
  }
  {  // tail (0..3 edges), guarded
    int i0 = g0 + half * 2;
    int s0 = 0, s1 = 0;
    float w0 = 0.f, w1 = 0.f;
    if (i0 < e) { s0 = col_src[i0]; w0 = di * dis[s0]; }
    if (i0 + 1 < e) { s1 = col_src[i0 + 1]; w1 = di * dis[s1]; }
    u16x8 u0 = *reinterpret_cast<const u16x8*>(xt + (size_t)s0 * HID + c0);
    u16x8 u1 = *reinterpret_cast<const u16x8*>(xt + (size_t)s1 * HID + c0);
#pragma unroll
    for (int j = 0; j < 8; j++) {
      acc[j] = fmaf(bfu(u0[j]), w0, acc[j]);
      acc[j] = fmaf(bfu(u1[j]), w1, acc[j]);
    }
  }
#pragma unroll
  for (int j = 0; j < 8; j++) acc[j] += __shfl_xor(acc[j], 32);
  // self loop + bias + write (half 0)
  if (!half) {
    u16x8 un = *reinterpret_cast<const u16x8*>(xt + (size_t)node * HID + c0);
    float w0 = di * di;
    u16x8 r;
#pragma unroll
    for (int j = 0; j < 8; j++) {
      float v = fmaf(bfu(un[j]), w0, acc[j]) + b_gcn[c0 + j];
      r[j] = f2bf(v);
    }
    *reinterpret_cast<u16x8*>(outb + (size_t)node * HID + c0) = r;
  }
}

// ---------------- GAT ----------------
__global__ void k_gat_al(const ushort* __restrict__ xt, const float* __restrict__ a_src,
                         const float* __restrict__ a_dst, float* __restrict__ alsrc,
                         float* __restrict__ aldst) {
  int node = blockIdx.x * 4 + (threadIdx.x >> 6);
  if (node >= N_NODES) return;
  int lane = threadIdx.x & 63;
  float4 v = bf4(*reinterpret_cast<const ushort4*>(xt + (size_t)node * HID + lane * 4));
  float4 as = *reinterpret_cast<const float4*>(a_src + lane * 4);
  float4 ad = *reinterpret_cast<const float4*>(a_dst + lane * 4);
  float ps = v.x * as.x + v.y * as.y + v.z * as.z + v.w * as.w;
  float pd = v.x * ad.x + v.y * ad.y + v.z * ad.z + v.w * ad.w;
  for (int o = 1; o < 8; o <<= 1) { ps += __shfl_xor(ps, o); pd += __shfl_xor(pd, o); }
  if ((lane & 7) == 0) {
    alsrc[node * 8 + (lane >> 3)] = ps;
    aldst[node * 8 + (lane >> 3)] = pd;
  }
}

__device__ __forceinline__ float leaky02(float x) { return x > 0.f ? x : 0.2f * x; }

// Single-pass GAT, 32 lanes/row. head hh = (lane&31)>>2 (8 cols per lane = 1 head slice... c0/32).
__global__ void k_gat_agg(const ushort* __restrict__ xt, const float* __restrict__ alsrc,
                          const float* __restrict__ aldst, const int* __restrict__ row_ptr,
                          const int* __restrict__ col_src, const float* __restrict__ b_gat,
                          ushort* __restrict__ outb) {
  int node = blockIdx.x * 4 + (threadIdx.x >> 6);
  if (node >= N_NODES) return;
  int lane = threadIdx.x & 63;
  int half = lane >> 5;
  int l32 = lane & 31;
  int c0 = l32 * 8;
  int hh = l32 >> 2;  // head of this lane's 8 cols
  float ad = aldst[node * 8 + hh];
  float acc[8];
#pragma unroll
  for (int j = 0; j < 8; j++) acc[j] = 0.f;
  float s = 0.f;
  int b = row_ptr[node], e = row_ptr[node + 1];
  int g0 = b;
  for (; g0 + 4 <= e; g0 += 4) {
    int i0 = g0 + half * 2;
    int s0 = col_src[i0], s1 = col_src[i0 + 1];
    float a0 = __expf(leaky02(alsrc[s0 * 8 + hh] + ad));
    float a1 = __expf(leaky02(alsrc[s1 * 8 + hh] + ad));
    u16x8 u0 = *reinterpret_cast<const u16x8*>(xt + (size_t)s0 * HID + c0);
    u16x8 u1 = *reinterpret_cast<const u16x8*>(xt + (size_t)s1 * HID + c0);
    s += a0 + a1;
#pragma unroll
    for (int j = 0; j < 8; j++) {
      acc[j] = fmaf(bfu(u0[j]), a0, acc[j]);
      acc[j] = fmaf(bfu(u1[j]), a1, acc[j]);
    }
  }
  {  // tail, guarded
    int i0 = g0 + half * 2;
    int s0 = 0, s1 = 0;
    float a0 = 0.f, a1 = 0.f;
    if (i0 < e) { s0 = col_src[i0]; a0 = __expf(leaky02(alsrc[s0 * 8 + hh] + ad)); }
    if (i0 + 1 < e) { s1 = col_src[i0 + 1]; a1 = __expf(leaky02(alsrc[s1 * 8 + hh] + ad)); }
    u16x8 u0 = *reinterpret_cast<const u16x8*>(xt + (size_t)s0 * HID + c0);
    u16x8 u1 = *reinterpret_cast<const u16x8*>(xt + (size_t)s1 * HID + c0);
    s += a0 + a1;
#pragma unroll
    for (int j = 0; j < 8; j++) {
      acc[j] = fmaf(bfu(u0[j]), a0, acc[j]);
      acc[j] = fmaf(bfu(u1[j]), a1, acc[j]);
    }
  }
#pragma unroll
  for (int j = 0; j < 8; j++) acc[j] += __shfl_xor(acc[j], 32);
  s += __shfl_xor(s, 32);
  if (!half) {
    float e0 = __expf(leaky02(alsrc[node * 8 + hh] + ad));  // self loop
    u16x8 un = *reinterpret_cast<const u16x8*>(xt + (size_t)node * HID + c0);
    float inv_s = 1.0f / (s + e0);
    u16x8 r;
#pragma unroll
    for (int j = 0; j < 8; j++) {
      float v = fmaf(bfu(un[j]), e0, acc[j]) * inv_s + b_gat[c0 + j];
      r[j] = f2bf(v);
    }
    *reinterpret_cast<u16x8*>(outb + (size_t)node * HID + c0) = r;
  }
}

// ---------------- SAGE mean aggregation: 32 lanes/row, bf16 in/out ----------------
__global__ void k_sage_agg(const ushort* __restrict__ h, const int* __restrict__ row_ptr,
                           const int* __restrict__ col_src, ushort* __restrict__ outb) {
  int node = blockIdx.x * 4 + (threadIdx.x >> 6);
  if (node >= N_NODES) return;
  int lane = threadIdx.x & 63;
  int half = lane >> 5;
  int c0 = (lane & 31) * 8;
  float acc[8];
#pragma unroll
  for (int j = 0; j < 8; j++) acc[j] = 0.f;
  int b = row_ptr[node], e = row_ptr[node + 1];
  int g0 = b;
  for (; g0 + 4 <= e; g0 += 4) {
    int i0 = g0 + half * 2;
    int s0 = col_src[i0], s1 = col_src[i0 + 1];
    u16x8 u0 = *reinterpret_cast<const u16x8*>(h + (size_t)s0 * HID + c0);
    u16x8 u1 = *reinterpret_cast<const u16x8*>(h + (size_t)s1 * HID + c0);
#pragma unroll
    for (int j = 0; j < 8; j++) acc[j] += bfu(u0[j]) + bfu(u1[j]);
  }
  {
    int i0 = g0 + half * 2;
    int s0 = 0, s1 = 0;
    float w0 = 0.f, w1 = 0.f;
    if (i0 < e) { s0 = col_src[i0]; w0 = 1.f; }
    if (i0 + 1 < e) { s1 = col_src[i0 + 1]; w1 = 1.f; }
    u16x8 u0 = *reinterpret_cast<const u16x8*>(h + (size_t)s0 * HID + c0);
    u16x8 u1 = *reinterpret_cast<const u16x8*>(h + (size_t)s1 * HID + c0);
#pragma unroll
    for (int j = 0; j < 8; j++) {
      acc[j] = fmaf(bfu(u0[j]), w0, acc[j]);
      acc[j] = fmaf(bfu(u1[j]), w1, acc[j]);
    }
  }
#pragma unroll
  for (int j = 0; j < 8; j++) acc[j] += __shfl_xor(acc[j], 32);
  if (!half) {
    float inv = 1.0f / fmaxf((float)(e - b), 1.0f);
    u16x8 r;
#pragma unroll
    for (int j = 0; j < 8; j++) r[j] = f2bf(acc[j] * inv);
    *reinterpret_cast<u16x8*>(outb + (size_t)node * HID + c0) = r;
  }
}

// ---------------- BatchNorm (bf16 input) ----------------
__global__ void k_bn_stats(const ushort* __restrict__ x, float* __restrict__ stats) {
  int c = threadIdx.x;
  float s = 0.f, q = 0.f;
  for (int r = blockIdx.x; r < N_NODES; r += gridDim.x) {
    float v = bfu(x[(size_t)r * HID + c]);
    s += v;
    q = fmaf(v, v, q);
  }
  atomicAdd(&stats[c], s);
  atomicAdd(&stats[HID + c], q);
}

// h += relu(bn(x_bf16)); also emit h_bf
__global__ void k_bn_apply(const ushort* __restrict__ x, const float* __restrict__ stats,
                           const float* __restrict__ gamma, const float* __restrict__ beta,
                           float* __restrict__ h, ushort* __restrict__ h_bf) {
  const float invN = 1.0f / (float)N_NODES;
  int total = N_NODES * 64;
  for (int i = blockIdx.x * 256 + threadIdx.x; i < total; i += gridDim.x * 256) {
    int c4 = (i & 63) * 4;
    float4 xv = bf4(*reinterpret_cast<const ushort4*>(x + (size_t)i * 4));
    float4 sm = *reinterpret_cast<const float4*>(stats + c4);
    float4 sq = *reinterpret_cast<const float4*>(stats + HID + c4);
    float4 gm = *reinterpret_cast<const float4*>(gamma + c4);
    float4 bt = *reinterpret_cast<const float4*>(beta + c4);
    float4 hv = *reinterpret_cast<const float4*>(h + (size_t)i * 4);
#define BN1(f)                                                    \
  {                                                               \
    float mu = sm.f * invN;                                       \
    float var = sq.f * invN - mu * mu;                            \
    float sc = gm.f * rsqrtf(var + EPS);                          \
    float v = (xv.f - mu) * sc + bt.f;                            \
    hv.f += fmaxf(v, 0.f);                                        \
  }
    BN1(x) BN1(y) BN1(z) BN1(w)
#undef BN1
    *reinterpret_cast<float4*>(h + (size_t)i * 4) = hv;
    *reinterpret_cast<ushort4*>(h_bf + (size_t)i * 4) =
        make_ushort4(f2bf(hv.x), f2bf(hv.y), f2bf(hv.z), f2bf(hv.w));
  }
}

// ---------------- graph segment starts ----------------
__global__ void k_gstart(const int* __restrict__ batch, int* __restrict__ gstart) {
  int g = blockIdx.x * 256 + threadIdx.x;
  if (g > NG) return;
  int lo = 0, hi = N_NODES;
  while (lo < hi) {
    int mid = (lo + hi) >> 1;
    if (batch[mid] < g) lo = mid + 1; else hi = mid;
  }
  gstart[g] = lo;
}

// ---------------- global attention pooling (bf16 h) ----------------
__global__ void k_pool(const ushort* __restrict__ hb, const float* __restrict__ gate,
                       const int* __restrict__ gstart, float* __restrict__ hg) {
  __shared__ float red[256];
  __shared__ float wbuf[256];
  int g = blockIdx.x, tid = threadIdx.x;
  int b = gstart[g], e = gstart[g + 1];
  float m = -1e30f;
  for (int r = b + tid; r < e; r += 256) m = fmaxf(m, gate[r]);
  red[tid] = m;
  __syncthreads();
  for (int o = 128; o > 0; o >>= 1) {
    if (tid < o) red[tid] = fmaxf(red[tid], red[tid + o]);
    __syncthreads();
  }
  m = red[0];
  __syncthreads();
  float s = 0.f;
  for (int r = b + tid; r < e; r += 256) s += __expf(gate[r] - m);
  red[tid] = s;
  __syncthreads();
  for (int o = 128; o > 0; o >>= 1) {
    if (tid < o) red[tid] += red[tid + o];
    __syncthreads();
  }
  float inv = 1.0f / fmaxf(red[0], 1e-16f);
  __syncthreads();
  float acc = 0.f;
  for (int cb = b; cb < e; cb += 256) {
    int r = cb + tid;
    wbuf[tid] = (r < e) ? __expf(gate[r] - m) : 0.f;
    __syncthreads();
    int n = min(256, e - cb);
    for (int j = 0; j < n; j++)
      acc = fmaf(bfu(hb[(size_t)(cb + j) * HID + tid]), wbuf[j], acc);
    __syncthreads();
  }
  hg[(size_t)g * HID + tid] = acc * inv;
}

// ---------------- MLP head ----------------
__global__ void k_mlp(const float* __restrict__ hg, const float* __restrict__ W1,
                      const float* __restrict__ b1, const float* __restrict__ lng,
                      const float* __restrict__ lnb, const float* __restrict__ W2,
                      const float* __restrict__ b2, float* __restrict__ out) {
  __shared__ float row[HID];
  __shared__ float z[HID];
  __shared__ float red[HID];
  int g = blockIdx.x, tid = threadIdx.x;
  row[tid] = hg[(size_t)g * HID + tid];
  __syncthreads();
  float acc = b1[tid];
  for (int k = 0; k < HID; k++) acc = fmaf(row[k], W1[(size_t)k * HID + tid], acc);
  red[tid] = acc;
  __syncthreads();
  for (int o = 128; o > 0; o >>= 1) {
    if (tid < o) red[tid] += red[tid + o];
    __syncthreads();
  }
  float mu = red[0] * (1.0f / HID);
  __syncthreads();
  red[tid] = acc * acc;
  __syncthreads();
  for (int o = 128; o > 0; o >>= 1) {
    if (tid < o) red[tid] += red[tid + o];
    __syncthreads();
  }
  float var = red[0] * (1.0f / HID) - mu * mu;
  float zz = (acc - mu) * rsqrtf(var + EPS) * lng[tid] + lnb[tid];
  z[tid] = fmaxf(zz, 0.f);
  __syncthreads();
  if (tid < 64) {
    float o = b2[tid];
    for (int k = 0; k < HID; k++) o = fmaf(z[k], W2[(size_t)k * 64 + tid], o);
    out[(size_t)g * 64 + tid] = o;
  }
}

// ---------------- launch ----------------
extern "C" void kernel_launch(void* const* d_in, const int* in_sizes, int n_in,
                              void* d_out, int out_size, void* d_ws, size_t ws_size,
                              hipStream_t stream) {
  const float* x     = (const float*)d_in[0];
  const float* W_emb = (const float*)d_in[1];
  const float* b_emb = (const float*)d_in[2];
  const float* W_gcn = (const float*)d_in[3];
  const float* b_gcn = (const float*)d_in[4];
  const float* W_gat = (const float*)d_in[5];
  const float* a_src = (const float*)d_in[6];
  const float* a_dst = (const float*)d_in[7];
  const float* b_gat = (const float*)d_in[8];
  const float* W_l   = (const float*)d_in[9];
  const float* b_l   = (const float*)d_in[10];
  const float* W_r   = (const float*)d_in[11];
  const float* bn_g  = (const float*)d_in[12];
  const float* bn_b  = (const float*)d_in[13];
  const float* Wg1   = (const float*)d_in[14];
  const float* bg1   = (const float*)d_in[15];
  const float* Wg2   = (const float*)d_in[16];
  const float* bg2   = (const float*)d_in[17];
  const float* Wm1   = (const float*)d_in[18];
  const float* bm1   = (const float*)d_in[19];
  const float* lnmg  = (const float*)d_in[20];
  const float* lnmb  = (const float*)d_in[21];
  const float* Wm2   = (const float*)d_in[22];
  const float* bm2   = (const float*)d_in[23];
  const float* Wv1   = (const float*)d_in[24];
  const float* bv1   = (const float*)d_in[25];
  const float* lnvg  = (const float*)d_in[26];
  const float* lnvb  = (const float*)d_in[27];
  const float* Wv2   = (const float*)d_in[28];
  const float* bv2   = (const float*)d_in[29];
  const int* ei      = (const int*)d_in[30];
  const int* batch   = (const int*)d_in[31];
  float* out = (float*)d_out;

  float* ws = (float*)d_ws;
  float* h     = ws;
  float* t1    = h + (size_t)N_NODES * HID;   // region reused as bf16 t1b
  float* alsrc = t1 + (size_t)N_NODES * HID;
  float* aldst = alsrc + N_NODES * 8;
  float* dis   = aldst + N_NODES * 8;
  float* gate  = dis + N_NODES;
  float* hg    = gate + N_NODES;
  float* zbase = hg + NG * HID;
  float* bnst  = zbase;                // 3 * 512
  int* row_cnt = (int*)(zbase + 3 * 512);
  int* fill    = row_cnt + N_NODES;
  int* row_ptr = fill + N_NODES;
  int* col_src = row_ptr + N_NODES + 1;
  int* gstart  = col_src + N_EDGES;
  int* psum    = gstart + NG + 1;
  int* boff    = psum + 64;

  ushort* t1b = (ushort*)t1;

  size_t off = (size_t)((char*)(boff + 64) - (char*)d_ws);
  off = (off + 15) & ~(size_t)15;
  ushort* h_bf   = (ushort*)((char*)d_ws + off);
  ushort* t0_bf  = h_bf + (size_t)N_NODES * HID;
  ushort* wemb_t = t0_bf + (size_t)N_NODES * HID;
  ushort* wgcn_t = wemb_t + 128 * 256;
  ushort* wgat_t = wgcn_t + 256 * 256;
  ushort* wr_t   = wgat_t + 256 * 256;
  ushort* wl_t   = wr_t + 256 * 256;
  ushort* wg1_t  = wl_t + 256 * 256;   // 256*128

  size_t zbytes = (size_t)3 * 512 * 4 + 2 * (size_t)N_NODES * 4;
  hipMemsetAsync(zbase, 0, zbytes, stream);

  // CSR by dst (hierarchical scan + fused dis)
  k_csr_count<<<(N_EDGES + 255) / 256, 256, 0, stream>>>(ei, row_cnt);
  k_scan_part<<<SCB, 256, 0, stream>>>(row_cnt, psum);
  k_scan_top<<<1, 64, 0, stream>>>(psum, boff, row_ptr);
  k_scan_out<<<SCB, 256, 0, stream>>>(row_cnt, boff, row_ptr, dis);
  k_csr_fill<<<(N_EDGES + 255) / 256, 256, 0, stream>>>(ei, row_ptr, fill, col_src);

  // all weight transposes in one launch
  WtArgs wa;
  wa.src[0] = W_emb; wa.dst[0] = wemb_t; wa.K[0] = 128; wa.C[0] = 256; wa.off[0] = 0;
  wa.src[1] = W_gcn; wa.dst[1] = wgcn_t; wa.K[1] = 256; wa.C[1] = 256; wa.off[1] = 128;
  wa.src[2] = W_gat; wa.dst[2] = wgat_t; wa.K[2] = 256; wa.C[2] = 256; wa.off[2] = 384;
  wa.src[3] = W_r;   wa.dst[3] = wr_t;   wa.K[3] = 256; wa.C[3] = 256; wa.off[3] = 640;
  wa.src[4] = W_l;   wa.dst[4] = wl_t;   wa.K[4] = 256; wa.C[4] = 256; wa.off[4] = 896;
  wa.src[5] = Wg1;   wa.dst[5] = wg1_t;  wa.K[5] = 256; wa.C[5] = 128; wa.off[5] = 1152;
  k_wt_all<<<1280, 256, 0, stream>>>(wa);

  const int RB = (N_NODES + 63) / 64;   // 782 gemm blocks
  const int AB = (N_NODES + 3) / 4;     // 12500 agg blocks

  // embedding: h = x @ W_emb + b_emb  (fp32 A converted on load; fp32 + bf16 out)
  k_mgemm<128, 256, false, true, false><<<RB, 256, 0, stream>>>(
      x, wemb_t, nullptr, nullptr, b_emb, h, h_bf, nullptr, nullptr, nullptr, N_NODES, 0);

  // --- GCN ---
  k_mgemm<256, 256, false, false, false><<<RB, 256, 0, stream>>>(
      h_bf, wgcn_t, nullptr, nullptr, nullptr, nullptr, t0_bf, nullptr, nullptr, nullptr, N_NODES, 0);
  k_gcn_agg<<<AB, 256, 0, stream>>>(t0_bf, dis, row_ptr, col_src, b_gcn, t1b);
  k_bn_stats<<<256, 256, 0, stream>>>(t1b, bnst);
  k_bn_apply<<<1024, 256, 0, stream>>>(t1b, bnst, bn_g, bn_b, h, h_bf);

  // --- GAT (single-pass softmax fused into agg) ---
  k_mgemm<256, 256, false, false, false><<<RB, 256, 0, stream>>>(
      h_bf, wgat_t, nullptr, nullptr, nullptr, nullptr, t0_bf, nullptr, nullptr, nullptr, N_NODES, 0);
  k_gat_al<<<AB, 256, 0, stream>>>(t0_bf, a_src, a_dst, alsrc, aldst);
  k_gat_agg<<<AB, 256, 0, stream>>>(t0_bf, alsrc, aldst, row_ptr, col_src, b_gat, t1b);
  k_bn_stats<<<256, 256, 0, stream>>>(t1b, bnst + 512);
  k_bn_apply<<<1024, 256, 0, stream>>>(t1b, bnst + 512, bn_g + HID, bn_b + HID, h, h_bf);

  // --- SAGE: t1b = h@W_r + b_l + mean@W_l (dual, both A-frag sets in regs) ---
  k_sage_agg<<<AB, 256, 0, stream>>>(h_bf, row_ptr, col_src, t0_bf);
  k_mgemm<256, 256, true, false, false><<<RB, 256, 0, stream>>>(
      h_bf, wr_t, t0_bf, wl_t, b_l, nullptr, t1b, nullptr, nullptr, nullptr, N_NODES, 0);
  k_bn_stats<<<256, 256, 0, stream>>>(t1b, bnst + 1024);
  k_bn_apply<<<1024, 256, 0, stream>>>(t1b, bnst + 1024, bn_g + 2 * HID, bn_b + 2 * HID, h, h_bf);

  // --- gate (fully fused GEMM epilogue) + pooling ---
  k_mgemm<256, 128, false, false, true><<<RB, 256, 0, stream>>>(
      h_bf, wg1_t, nullptr, nullptr, bg1, nullptr, nullptr, Wg2, bg2, gate, N_NODES, 1);
  k_gstart<<<3, 256, 0, stream>>>(batch, gstart);
  k_pool<<<NG, 256, 0, stream>>>(h_bf, gate, gstart, hg);

  // --- heads ---
  k_mlp<<<NG, 256, 0, stream>>>(hg, Wm1, bm1, lnmg, lnmb, Wm2, bm2, out);
  k_mlp<<<NG, 256, 0, stream>>>(hg, Wv1, bv1, lnvg, lnvb, Wv2, bv2, out + (size_t)NG * 64);
}